// Round 7
// baseline (1518.785 us; speedup 1.0000x reference)
//
#include <hip/hip_runtime.h>
#include <hip/hip_bf16.h>
#include <cmath>

#define BATCH 8
#define CIN 64
#define COUT 128
#define NPTS 16384
#define RES 32
#define R3 32768
#define NGROUP 8
#define GSIZE 16

typedef __hip_bfloat16 bf16;
typedef __attribute__((ext_vector_type(8))) short short8;
typedef __attribute__((ext_vector_type(4))) float f32x4;

__device__ inline float b2f(ushort u) { union { float f; uint v; } x; x.v = ((uint)u) << 16; return x.f; }
__device__ inline ushort f2bu(float f) { __hip_bfloat16 h = __float2bfloat16(f); return *reinterpret_cast<ushort*>(&h); }

// ---------------- coord stats ----------------
__global__ __launch_bounds__(256) void coord_stats_k(const float* __restrict__ coords,
                                                     float* __restrict__ bstats) {
    int b = blockIdx.x;
    int t = threadIdx.x;
    __shared__ float red[256];
    __shared__ float means[3];
    for (int c = 0; c < 3; ++c) {
        float acc = 0.f;
        const float* p = coords + ((size_t)b * 3 + c) * NPTS;
        for (int n = t; n < NPTS; n += 256) acc += p[n];
        red[t] = acc; __syncthreads();
        for (int s = 128; s > 0; s >>= 1) { if (t < s) red[t] += red[t + s]; __syncthreads(); }
        if (t == 0) means[c] = red[0] * (1.f / NPTS);
        __syncthreads();
    }
    float m0 = means[0], m1 = means[1], m2 = means[2];
    const float* px = coords + ((size_t)b * 3 + 0) * NPTS;
    const float* py = coords + ((size_t)b * 3 + 1) * NPTS;
    const float* pz = coords + ((size_t)b * 3 + 2) * NPTS;
    float mx = 0.f;
    for (int n = t; n < NPTS; n += 256) {
        float dx = px[n] - m0, dy = py[n] - m1, dz = pz[n] - m2;
        mx = fmaxf(mx, sqrtf(dx * dx + dy * dy + dz * dz));
    }
    red[t] = mx; __syncthreads();
    for (int s = 128; s > 0; s >>= 1) { if (t < s) red[t] = fmaxf(red[t], red[t + s]); __syncthreads(); }
    if (t == 0) {
        bstats[b * 4 + 0] = m0; bstats[b * 4 + 1] = m1; bstats[b * 4 + 2] = m2;
        bstats[b * 4 + 3] = 1.f / (2.f * red[0]);
    }
}

// ---------------- per-point voxel index + nc4 + count ----------------
__global__ __launch_bounds__(256) void vox_idx_k(const float* __restrict__ coords,
                                                 const float* __restrict__ bstats,
                                                 float4* __restrict__ nc4,   // [g]
                                                 int* __restrict__ vidx,
                                                 int* __restrict__ slot,
                                                 unsigned int* __restrict__ cnts) {
    int g = blockIdx.x * 256 + threadIdx.x;
    int b = g >> 14, n = g & (NPTS - 1);
    float m0 = bstats[b * 4 + 0], m1 = bstats[b * 4 + 1], m2 = bstats[b * 4 + 2];
    float sc = bstats[b * 4 + 3];
    float x = coords[((size_t)b * 3 + 0) * NPTS + n];
    float y = coords[((size_t)b * 3 + 1) * NPTS + n];
    float z = coords[((size_t)b * 3 + 2) * NPTS + n];
    float ncx = fminf(fmaxf(((x - m0) * sc + 0.5f) * (float)RES, 0.f), RES - 1.f);
    float ncy = fminf(fmaxf(((y - m1) * sc + 0.5f) * (float)RES, 0.f), RES - 1.f);
    float ncz = fminf(fmaxf(((z - m2) * sc + 0.5f) * (float)RES, 0.f), RES - 1.f);
    nc4[g] = make_float4(ncx, ncy, ncz, 0.f);
    int ix = min(max((int)rintf(ncx), 0), RES - 1);  // rintf = half-even = jnp.round
    int iy = min(max((int)rintf(ncy), 0), RES - 1);
    int iz = min(max((int)rintf(ncz), 0), RES - 1);
    int v = b * R3 + (ix * RES + iy) * RES + iz;
    vidx[g] = v;
    slot[g] = (int)atomicAdd(&cnts[v], 1u);
}

// ---------------- feature transpose: [b][64][N] fp32 -> [b][n][64] fp32 ----------------
__global__ __launch_bounds__(256) void transpose_feats_k(const float* __restrict__ feats,
                                                         float* __restrict__ featT) {
    int blk = blockIdx.x;
    int b = blk >> 8, ntile = blk & 255;
    int t = threadIdx.x;
    __shared__ float lds[64][65];
    for (int e = t; e < 64 * 64; e += 256) {
        int c = e >> 6, n = e & 63;
        lds[c][n] = feats[((size_t)b * CIN + c) * NPTS + ntile * 64 + n];
    }
    __syncthreads();
    for (int e = t; e < 64 * 64; e += 256) {
        int n = e >> 6, c = e & 63;
        featT[(((size_t)b << 14) + ntile * 64 + n) * CIN + c] = lds[c][n];
    }
}

// ---------------- scan ----------------
__global__ __launch_bounds__(256) void scan1_k(const unsigned int* __restrict__ cnts,
                                               unsigned int* __restrict__ offs,
                                               unsigned int* __restrict__ part) {
    int t = threadIdx.x;
    int g = blockIdx.x * 256 + t;
    unsigned int v = cnts[g];
    __shared__ unsigned int s[256];
    s[t] = v; __syncthreads();
    for (int d = 1; d < 256; d <<= 1) {
        unsigned int x = (t >= d) ? s[t - d] : 0u;
        __syncthreads();
        s[t] += x;
        __syncthreads();
    }
    offs[g] = s[t] - v;
    if (t == 255) part[blockIdx.x] = s[255];
}

__global__ __launch_bounds__(1024) void scan2_k(unsigned int* __restrict__ part) {
    int t = threadIdx.x;
    unsigned int v = part[t];
    __shared__ unsigned int s[1024];
    s[t] = v; __syncthreads();
    for (int d = 1; d < 1024; d <<= 1) {
        unsigned int x = (t >= d) ? s[t - d] : 0u;
        __syncthreads();
        s[t] += x;
        __syncthreads();
    }
    part[t] = s[t] - v;
}

__global__ __launch_bounds__(256) void scan3_k(unsigned int* __restrict__ offs,
                                               const unsigned int* __restrict__ part) {
    int g = blockIdx.x * 256 + threadIdx.x;
    offs[g] += part[blockIdx.x];
}

// ---------------- scatter point ids into CSR (per-batch n AND global g) ----------------
__global__ __launch_bounds__(256) void scatter_pts_k(const int* __restrict__ vidx,
                                                     const int* __restrict__ slot,
                                                     const unsigned int* __restrict__ offs,
                                                     unsigned int* __restrict__ pidx,
                                                     unsigned int* __restrict__ pidx2) {
    int g = blockIdx.x * 256 + threadIdx.x;
    int n = g & (NPTS - 1);
    int v = vidx[g];
    unsigned int dst = offs[v] + slot[g];
    pidx[dst] = (unsigned int)n;
    pidx2[dst] = (unsigned int)g;
}

// ---------------- gather: CSR mean -> bf16 channel-last vox ----------------
__global__ __launch_bounds__(256) void gather_k(const float* __restrict__ featT,
                                                const unsigned int* __restrict__ cnts,
                                                const unsigned int* __restrict__ offs,
                                                const unsigned int* __restrict__ pidx,
                                                bf16* __restrict__ voxCL) {
    int u = blockIdx.x * 256 + threadIdx.x;
    int v = u >> 3;
    int l8 = u & 7;
    int b = v >> 15;
    unsigned int cnt = cnts[v];
    unsigned int off = offs[v];
    float acc[8] = {0.f, 0.f, 0.f, 0.f, 0.f, 0.f, 0.f, 0.f};
    for (unsigned int i = 0; i < cnt; ++i) {
        unsigned int n = pidx[off + i];
        const float4* fp = (const float4*)(featT + (((size_t)b << 14) + n) * CIN + l8 * 8);
        float4 f0 = fp[0], f1 = fp[1];
        acc[0] += f0.x; acc[1] += f0.y; acc[2] += f0.z; acc[3] += f0.w;
        acc[4] += f1.x; acc[5] += f1.y; acc[6] += f1.z; acc[7] += f1.w;
    }
    float inv = 1.f / fmaxf((float)cnt, 1.f);
    ushort o[8];
#pragma unroll
    for (int j = 0; j < 8; ++j) o[j] = f2bu(acc[j] * inv);
    *(short8*)(voxCL + (size_t)v * CIN + l8 * 8) = *(short8*)o;
}

// ---------------- weight reorder: [co][ci][27] fp32 -> [t][c32][co][kb][8] bf16 ----------------
template <int CIN_T>
__global__ __launch_bounds__(256) void wreorder_k(const float* __restrict__ w,
                                                  bf16* __restrict__ wf) {
    const int NC = CIN_T / 32;
    int u = blockIdx.x * 256 + threadIdx.x;
    if (u >= 27 * NC * 128 * 4) return;
    int kb = u & 3;
    int co = (u >> 2) & 127;
    int c32 = (u >> 9) % NC;
    int t = u / (512 * NC);
    int cibase = c32 * 32 + kb * 8;
    ushort o[8];
#pragma unroll
    for (int j = 0; j < 8; ++j)
        o[j] = f2bu(w[((size_t)co * CIN_T + cibase + j) * 27 + t]);
    *(short8*)(wf + (size_t)u * 8) = *(short8*)o;
}

// ---------------- implicit-GEMM conv3d 3x3x3 via MFMA bf16 ----------------
// block 512 = 8 waves (2 cog x 4 sg); wave: 64 co x 32 sp (4 A x 2 B = 8 MFMA/tap)
// LDS layout + launch bounds IDENTICAL to R4/R6-proven (80B pos stride, (512,2)).
// Halved B-side LDS reads vs R6 (was the binding constraint at MfmaUtil 38%).
template <int CIN_T>
__global__ __launch_bounds__(512, 2) void conv3d_mfma_k(const bf16* __restrict__ x,  // [b][p][CIN_T]
                                                        const bf16* __restrict__ wf, // [27][NC][128][4][8]
                                                        const float* __restrict__ bias,
                                                        bf16* __restrict__ y,        // [b][p][128]
                                                        float* __restrict__ gnacc) { // [64][2]
    constexpr int NC = CIN_T / 32;
    int blk = blockIdx.x;
    int hq = blk & 7;
    int d = (blk >> 3) & 31;
    int b = blk >> 8;
    int t = threadIdx.x;
    int lane = t & 63;
    int wid = t >> 6;
    int cog = wid >> 2;  // 0..1
    int sg = wid & 3;    // 0..3
    int lr = lane & 15;
    int kb = lane >> 4;

    __shared__ __align__(16) char xs[3 * 6 * 34 * 80];  // 48960 B
    __shared__ float gred[8][2];
    if (t < 16) gred[t >> 1][t & 1] = 0.f;

    f32x4 acc[4][2];
#pragma unroll
    for (int r = 0; r < 4; ++r)
#pragma unroll
        for (int j = 0; j < 2; ++j) acc[r][j] = (f32x4){0.f, 0.f, 0.f, 0.f};

    int bbase[2];
#pragma unroll
    for (int j = 0; j < 2; ++j)
        bbase[j] = ((sg * 34) + (j * 16 + lr)) * 80 + kb * 16;  // hl = sg, wl = j*16+lr

    for (int cc = 0; cc < NC; ++cc) {
        __syncthreads();
        for (int e = t; e < 612 * 4; e += 512) {
            int ekb = e & 3;
            int pos = e >> 2;
            int ww = pos % 34;
            int hh = (pos / 34) % 6;
            int dd = pos / 204;
            int dz = d + dd - 1;
            int hz = hq * 4 + hh - 1;
            int wz = ww - 1;
            short8 v = {0, 0, 0, 0, 0, 0, 0, 0};
            if (dz >= 0 && dz < RES && hz >= 0 && hz < RES && wz >= 0 && wz < RES)
                v = *(const short8*)(x + ((size_t)b * R3 + dz * 1024 + hz * 32 + wz) * CIN_T + cc * 32 + ekb * 8);
            *(short8*)(xs + pos * 80 + ekb * 16) = v;
        }
        __syncthreads();

        const short8* wfp = (const short8*)wf;
        size_t abase = ((size_t)cc * 128 + cog * 64 + lr) * 4 + kb;
#pragma unroll
        for (int dd = 0; dd < 3; ++dd)
#pragma unroll
            for (int dh = 0; dh < 3; ++dh)
#pragma unroll
                for (int dw = 0; dw < 3; ++dw) {
                    int tap = (dd * 3 + dh) * 3 + dw;
                    size_t ab = abase + (size_t)tap * NC * 512;
                    short8 a0 = wfp[ab];
                    short8 a1 = wfp[ab + 64];
                    short8 a2 = wfp[ab + 128];
                    short8 a3 = wfp[ab + 192];
                    int toff = ((dd * 6 + dh) * 34 + dw) * 80;
                    short8 b0 = *(const short8*)(xs + bbase[0] + toff);
                    short8 b1 = *(const short8*)(xs + bbase[1] + toff);
                    acc[0][0] = __builtin_amdgcn_mfma_f32_16x16x32_bf16(a0, b0, acc[0][0], 0, 0, 0);
                    acc[0][1] = __builtin_amdgcn_mfma_f32_16x16x32_bf16(a0, b1, acc[0][1], 0, 0, 0);
                    acc[1][0] = __builtin_amdgcn_mfma_f32_16x16x32_bf16(a1, b0, acc[1][0], 0, 0, 0);
                    acc[1][1] = __builtin_amdgcn_mfma_f32_16x16x32_bf16(a1, b1, acc[1][1], 0, 0, 0);
                    acc[2][0] = __builtin_amdgcn_mfma_f32_16x16x32_bf16(a2, b0, acc[2][0], 0, 0, 0);
                    acc[2][1] = __builtin_amdgcn_mfma_f32_16x16x32_bf16(a2, b1, acc[2][1], 0, 0, 0);
                    acc[3][0] = __builtin_amdgcn_mfma_f32_16x16x32_bf16(a3, b0, acc[3][0], 0, 0, 0);
                    acc[3][1] = __builtin_amdgcn_mfma_f32_16x16x32_bf16(a3, b1, acc[3][1], 0, 0, 0);
                }
    }

    // epilogue: store bf16 + GN partial stats (group = cog*4 + r)
    float sred[4], ssred[4];
#pragma unroll
    for (int r = 0; r < 4; ++r) {
        int co = cog * 64 + r * 16 + kb * 4;
        float4 bv = *(const float4*)(bias + co);
        float s = 0.f, ss = 0.f;
#pragma unroll
        for (int j = 0; j < 2; ++j) {
            int p = d * 1024 + (hq * 4 + sg) * 32 + (j * 16 + lr);
            float v0 = acc[r][j][0] + bv.x;
            float v1 = acc[r][j][1] + bv.y;
            float v2 = acc[r][j][2] + bv.z;
            float v3 = acc[r][j][3] + bv.w;
            ushort4 o;
            o.x = f2bu(v0); o.y = f2bu(v1); o.z = f2bu(v2); o.w = f2bu(v3);
            *(ushort4*)(y + ((size_t)b * R3 + p) * COUT + co) = o;
            s += v0 + v1 + v2 + v3;
            ss += v0 * v0 + v1 * v1 + v2 * v2 + v3 * v3;
        }
        sred[r] = s; ssred[r] = ss;
    }
#pragma unroll
    for (int m = 1; m < 64; m <<= 1) {
#pragma unroll
        for (int r = 0; r < 4; ++r) {
            sred[r] += __shfl_xor(sred[r], m, 64);
            ssred[r] += __shfl_xor(ssred[r], m, 64);
        }
    }
    if (lane == 0) {
#pragma unroll
        for (int r = 0; r < 4; ++r) {
            atomicAdd(&gred[cog * 4 + r][0], sred[r]);
            atomicAdd(&gred[cog * 4 + r][1], ssred[r]);
        }
    }
    __syncthreads();
    if (t < 16) atomicAdd(&gnacc[(b * 8 + (t >> 1)) * 2 + (t & 1)], gred[t >> 1][t & 1]);
}

// ---------------- GN apply + swish on channel-last bf16 (act1 only) ----------------
__global__ __launch_bounds__(256) void gn_apply_cl_k(bf16* __restrict__ x,
                                                     const float* __restrict__ gnacc,
                                                     const float* __restrict__ gamma,
                                                     const float* __restrict__ beta) {
    int u = blockIdx.x * 256 + threadIdx.x;
    int ci8 = u & 15;
    int p = (u >> 4) & (R3 - 1);
    int b = u >> 19;
    int ci = ci8 * 8;
    int bg = b * 8 + (ci8 >> 1);
    const float M = (float)(GSIZE * R3);
    float s = gnacc[bg * 2], ss = gnacc[bg * 2 + 1];
    float mean = s / M;
    float istd = rsqrtf(fmaxf(ss / M - mean * mean, 0.f) + 1e-5f);
    bf16* ptr = x + ((size_t)b * R3 + p) * COUT + ci;
    short8 v = *(const short8*)ptr;
    ushort o[8];
#pragma unroll
    for (int j = 0; j < 8; ++j) {
        float f = b2f((ushort)v[j]);
        float yv = fmaf((f - mean) * istd, gamma[ci + j], beta[ci + j]);
        o[j] = f2bu(yv / (1.f + expf(-yv)));
    }
    *(short8*)ptr = *(short8*)o;
}

// ---------------- point branch GEMM: channel-last pfT [g][128] + fused GN stats ----------------
__global__ __launch_bounds__(256) void point_gemm_cl_k(const float* __restrict__ feats,
                                                       const float* __restrict__ wp,
                                                       const float* __restrict__ bp,
                                                       float* __restrict__ pfT,
                                                       float* __restrict__ gnacc) {
    int g = blockIdx.x * 256 + threadIdx.x;  // 131072
    int b = g >> 14, n = g & (NPTS - 1);
    int lane = threadIdx.x & 63;
    float f[CIN];
    const float* fp = feats + ((size_t)b * CIN) * NPTS + n;
#pragma unroll
    for (int ci = 0; ci < CIN; ++ci) f[ci] = fp[(size_t)ci * NPTS];
    float* pout = pfT + (size_t)g * COUT;
    float gs[8], gss[8];
#pragma unroll
    for (int grp = 0; grp < 8; ++grp) {
        float a[16];
#pragma unroll
        for (int k = 0; k < 16; ++k) a[k] = bp[grp * 16 + k];
#pragma unroll
        for (int ci = 0; ci < CIN; ++ci) {
            float fv = f[ci];
#pragma unroll
            for (int k = 0; k < 16; ++k)
                a[k] = fmaf(wp[(size_t)(grp * 16 + k) * CIN + ci], fv, a[k]);
        }
        float s = 0.f, ss = 0.f;
#pragma unroll
        for (int k = 0; k < 16; ++k) { s += a[k]; ss = fmaf(a[k], a[k], ss); }
        gs[grp] = s; gss[grp] = ss;
#pragma unroll
        for (int k = 0; k < 4; ++k)
            *(float4*)(pout + grp * 16 + k * 4) = make_float4(a[k*4], a[k*4+1], a[k*4+2], a[k*4+3]);
    }
#pragma unroll
    for (int m = 1; m < 64; m <<= 1) {
#pragma unroll
        for (int grp = 0; grp < 8; ++grp) {
            gs[grp] += __shfl_xor(gs[grp], m, 64);
            gss[grp] += __shfl_xor(gss[grp], m, 64);
        }
    }
    if (lane == 0) {
#pragma unroll
        for (int grp = 0; grp < 8; ++grp) {
            atomicAdd(&gnacc[(b * 8 + grp) * 2 + 0], gs[grp]);
            atomicAdd(&gnacc[(b * 8 + grp) * 2 + 1], gss[grp]);
        }
    }
}

// ---------------- fuse2: CSR-ordered devox + GN2/GNp + swish + add, in place on pfT ----------------
__global__ __launch_bounds__(256) void fuse2_k(const bf16* __restrict__ vox,  // act2 [b][p][128]
                                               const float4* __restrict__ nc4,
                                               const unsigned int* __restrict__ pidx2,
                                               const float* __restrict__ gn2acc,
                                               const float* __restrict__ gnpacc,
                                               const float* __restrict__ g2g,
                                               const float* __restrict__ g2b,
                                               const float* __restrict__ gpg,
                                               const float* __restrict__ gpb,
                                               float* __restrict__ pfT) {
    int s = blockIdx.x * 256 + threadIdx.x;        // CSR slot: voxel-sorted order
    unsigned int g = pidx2[s];
    int b = (int)(g >> 14);
    float4 c4 = nc4[g];
    const float CMAX = (float)(RES - 1) - 1e-6f;
    float cx = fminf(c4.x, CMAX), cy = fminf(c4.y, CMAX), cz = fminf(c4.z, CMAX);
    int ix0 = (int)cx, iy0 = (int)cy, iz0 = (int)cz;
    float fx = cx - ix0, fy = cy - iy0, fz = cz - iz0;
    int ix1 = min(ix0 + 1, RES - 1), iy1 = min(iy0 + 1, RES - 1), iz1 = min(iz0 + 1, RES - 1);
    float gx0 = 1.f - fx, gy0 = 1.f - fy, gz0 = 1.f - fz;
    float wc[8] = {gx0 * gy0 * gz0, gx0 * gy0 * fz, gx0 * fy * gz0, gx0 * fy * fz,
                   fx * gy0 * gz0,  fx * gy0 * fz,  fx * fy * gz0,  fx * fy * fz};
    int fi[8];
    fi[0] = (ix0 * RES + iy0) * RES + iz0; fi[1] = (ix0 * RES + iy0) * RES + iz1;
    fi[2] = (ix0 * RES + iy1) * RES + iz0; fi[3] = (ix0 * RES + iy1) * RES + iz1;
    fi[4] = (ix1 * RES + iy0) * RES + iz0; fi[5] = (ix1 * RES + iy0) * RES + iz1;
    fi[6] = (ix1 * RES + iy1) * RES + iz0; fi[7] = (ix1 * RES + iy1) * RES + iz1;
    const bf16* vb = vox + (size_t)b * R3 * COUT;
    float* pp = pfT + (size_t)g * COUT;
    const float M2 = (float)(GSIZE * R3);
    const float Mp = (float)(GSIZE * NPTS);
    for (int o = 0; o < COUT; o += 8) {
        int bg = b * 8 + (o >> 4);
        float s2 = gn2acc[bg * 2], ss2 = gn2acc[bg * 2 + 1];
        float mean2 = s2 / M2;
        float istd2 = rsqrtf(fmaxf(ss2 / M2 - mean2 * mean2, 0.f) + 1e-5f);
        float sp = gnpacc[bg * 2], ssp = gnpacc[bg * 2 + 1];
        float meanp = sp / Mp;
        float istdp = rsqrtf(fmaxf(ssp / Mp - meanp * meanp, 0.f) + 1e-5f);
        float ga[8], gb[8], pa[8], pb[8];
#pragma unroll
        for (int j = 0; j < 8; ++j) {
            float gmj = g2g[o + j];
            ga[j] = istd2 * gmj;
            gb[j] = g2b[o + j] - mean2 * istd2 * gmj;
            float pmj = gpg[o + j];
            pa[j] = istdp * pmj;
            pb[j] = gpb[o + j] - meanp * istdp * pmj;
        }
        float accv[8] = {0.f, 0.f, 0.f, 0.f, 0.f, 0.f, 0.f, 0.f};
#pragma unroll
        for (int f = 0; f < 8; ++f) {
            short8 v = *(const short8*)(vb + (size_t)fi[f] * COUT + o);
            float wgt = wc[f];
#pragma unroll
            for (int j = 0; j < 8; ++j) {
                float yv = fmaf(b2f((ushort)v[j]), ga[j], gb[j]);
                float sw = yv / (1.f + expf(-yv));
                accv[j] = fmaf(wgt, sw, accv[j]);
            }
        }
        float4 p0 = *(float4*)(pp + o);
        float4 p1 = *(float4*)(pp + o + 4);
        float pv[8] = {p0.x, p0.y, p0.z, p0.w, p1.x, p1.y, p1.z, p1.w};
#pragma unroll
        for (int j = 0; j < 8; ++j) {
            float yv = fmaf(pv[j], pa[j], pb[j]);
            float sw = yv / (1.f + expf(-yv));
            pv[j] = sw + accv[j];
        }
        *(float4*)(pp + o) = make_float4(pv[0], pv[1], pv[2], pv[3]);
        *(float4*)(pp + o + 4) = make_float4(pv[4], pv[5], pv[6], pv[7]);
    }
}

// ---------------- transpose pfT [b][n][128] -> out [b][128][n] ----------------
__global__ __launch_bounds__(256) void transpose_out_k(const float* __restrict__ pfT,
                                                       float* __restrict__ out) {
    int blk = blockIdx.x;       // b*256 + ntile
    int b = blk >> 8, nt = blk & 255;
    int t = threadIdx.x;
    int n0 = nt * 64;
    __shared__ float lds[64][129];
#pragma unroll
    for (int k = 0; k < 8; ++k) {
        int e = t + k * 256;           // 2048 float4s: 64 rows x 32 c4
        int row = e >> 5, c4 = e & 31;
        float4 v = ((const float4*)pfT)[(((size_t)b << 14) + n0 + row) * 32 + c4];
        lds[row][c4 * 4 + 0] = v.x;
        lds[row][c4 * 4 + 1] = v.y;
        lds[row][c4 * 4 + 2] = v.z;
        lds[row][c4 * 4 + 3] = v.w;
    }
    __syncthreads();
#pragma unroll
    for (int k = 0; k < 32; ++k) {
        int e = t + k * 256;           // 8192 floats: 128 c x 64 n
        int c = e >> 6, n = e & 63;
        out[((size_t)b * COUT + c) * NPTS + n0 + n] = lds[n][c];
    }
}

extern "C" void kernel_launch(void* const* d_in, const int* in_sizes, int n_in,
                              void* d_out, int out_size, void* d_ws, size_t ws_size,
                              hipStream_t stream) {
    const float* features = (const float*)d_in[0];
    const float* coords   = (const float*)d_in[1];
    const float* w1  = (const float*)d_in[3];
    const float* b1  = (const float*)d_in[4];
    const float* g1g = (const float*)d_in[5];
    const float* g1b = (const float*)d_in[6];
    const float* w2  = (const float*)d_in[7];
    const float* b2  = (const float*)d_in[8];
    const float* g2g = (const float*)d_in[9];
    const float* g2b = (const float*)d_in[10];
    const float* wp  = (const float*)d_in[11];
    const float* bp  = (const float*)d_in[12];
    const float* gpg = (const float*)d_in[13];
    const float* gpb = (const float*)d_in[14];
    float* out = (float*)d_out;

    // ws (~137 MB):
    //   [0,64MB)    act1 bf16 [b][p][128]  -> after conv2: pfT fp32 [g][128] (overlay, 64MB)
    //   [64,128MB)  voxCL bf16 32MB | featT fp32 32MB -> act2 bf16 overlays all 64MB
    //   tail: w1f, w2f, nc4, cnts, offs, vidx, slot, pidx, pidx2, part, bstats, gn accs
    char* ws = (char*)d_ws;
    size_t off = 0;
    bf16* act1 = (bf16*)(ws + off);
    float* pfT = (float*)(ws + off);         off += (size_t)BATCH * R3 * COUT * 2;  // 64MB
    bf16* act2 = (bf16*)(ws + off);
    bf16* voxCL = (bf16*)(ws + off);         off += (size_t)BATCH * R3 * CIN * 2;   // 32MB
    float* featT = (float*)(ws + off);       off += (size_t)BATCH * NPTS * CIN * 4; // 32MB
    bf16* w1f = (bf16*)(ws + off);           off += (size_t)27 * 2 * 128 * 32 * 2;
    bf16* w2f = (bf16*)(ws + off);           off += (size_t)27 * 4 * 128 * 32 * 2;
    float4* nc4 = (float4*)(ws + off);       off += (size_t)BATCH * NPTS * 16;      // 2MB
    unsigned int* cnts = (unsigned int*)(ws + off);  off += (size_t)BATCH * R3 * 4;
    unsigned int* offs = (unsigned int*)(ws + off);  off += (size_t)BATCH * R3 * 4;
    int* vidx = (int*)(ws + off);            off += (size_t)BATCH * NPTS * 4;
    int* slot = (int*)(ws + off);            off += (size_t)BATCH * NPTS * 4;
    unsigned int* pidx = (unsigned int*)(ws + off);  off += (size_t)BATCH * NPTS * 4;
    unsigned int* pidx2 = (unsigned int*)(ws + off); off += (size_t)BATCH * NPTS * 4;
    unsigned int* part = (unsigned int*)(ws + off);  off += 4096;
    float* bstats = (float*)(ws + off);      off += 256;
    float* gn1acc = (float*)(ws + off);      off += 512;   // [64][2]
    float* gn2acc = (float*)(ws + off);      off += 512;
    float* gnpacc = (float*)(ws + off);      off += 512;

    hipMemsetAsync(cnts, 0, (size_t)BATCH * R3 * 4, stream);
    hipMemsetAsync(gn1acc, 0, 3 * 512, stream);

    coord_stats_k<<<BATCH, 256, 0, stream>>>(coords, bstats);
    vox_idx_k<<<BATCH * NPTS / 256, 256, 0, stream>>>(coords, bstats, nc4, vidx, slot, cnts);
    transpose_feats_k<<<BATCH * 256, 256, 0, stream>>>(features, featT);
    scan1_k<<<BATCH * R3 / 256, 256, 0, stream>>>(cnts, offs, part);
    scan2_k<<<1, 1024, 0, stream>>>(part);
    scan3_k<<<BATCH * R3 / 256, 256, 0, stream>>>(offs, part);
    scatter_pts_k<<<BATCH * NPTS / 256, 256, 0, stream>>>(vidx, slot, offs, pidx, pidx2);
    gather_k<<<BATCH * R3 * 8 / 256, 256, 0, stream>>>(featT, cnts, offs, pidx, voxCL);

    wreorder_k<CIN><<<(27 * 2 * 128 * 4 + 255) / 256, 256, 0, stream>>>(w1, w1f);
    wreorder_k<COUT><<<(27 * 4 * 128 * 4 + 255) / 256, 256, 0, stream>>>(w2, w2f);

    conv3d_mfma_k<CIN><<<BATCH * 32 * 8, 512, 0, stream>>>(voxCL, w1f, b1, act1, gn1acc);
    gn_apply_cl_k<<<BATCH * R3 * 16 / 256, 256, 0, stream>>>(act1, gn1acc, g1g, g1b);

    conv3d_mfma_k<COUT><<<BATCH * 32 * 8, 512, 0, stream>>>(act1, w2f, b2, act2, gn2acc);

    // pfT overlays act1 -> must launch after conv2 (stream-ordered)
    point_gemm_cl_k<<<BATCH * NPTS / 256, 256, 0, stream>>>(features, wp, bp, pfT, gnpacc);

    fuse2_k<<<BATCH * NPTS / 256, 256, 0, stream>>>(act2, nc4, pidx2, gn2acc, gnpacc,
                                                    g2g, g2b, gpg, gpb, pfT);

    transpose_out_k<<<BATCH * 256, 256, 0, stream>>>(pfT, out);
}

// Round 8
// 1331.971 us; speedup vs baseline: 1.1403x; 1.1403x over previous
//
#include <hip/hip_runtime.h>
#include <hip/hip_bf16.h>
#include <cmath>

#define BATCH 8
#define CIN 64
#define COUT 128
#define NPTS 16384
#define RES 32
#define R3 32768
#define NGROUP 8
#define GSIZE 16

typedef __hip_bfloat16 bf16;
typedef __attribute__((ext_vector_type(8))) short short8;
typedef __attribute__((ext_vector_type(4))) float f32x4;

__device__ inline float b2f(ushort u) { union { float f; uint v; } x; x.v = ((uint)u) << 16; return x.f; }
__device__ inline ushort f2bu(float f) { __hip_bfloat16 h = __float2bfloat16(f); return *reinterpret_cast<ushort*>(&h); }

// ---------------- coord stats ----------------
__global__ __launch_bounds__(256) void coord_stats_k(const float* __restrict__ coords,
                                                     float* __restrict__ bstats) {
    int b = blockIdx.x;
    int t = threadIdx.x;
    __shared__ float red[256];
    __shared__ float means[3];
    for (int c = 0; c < 3; ++c) {
        float acc = 0.f;
        const float* p = coords + ((size_t)b * 3 + c) * NPTS;
        for (int n = t; n < NPTS; n += 256) acc += p[n];
        red[t] = acc; __syncthreads();
        for (int s = 128; s > 0; s >>= 1) { if (t < s) red[t] += red[t + s]; __syncthreads(); }
        if (t == 0) means[c] = red[0] * (1.f / NPTS);
        __syncthreads();
    }
    float m0 = means[0], m1 = means[1], m2 = means[2];
    const float* px = coords + ((size_t)b * 3 + 0) * NPTS;
    const float* py = coords + ((size_t)b * 3 + 1) * NPTS;
    const float* pz = coords + ((size_t)b * 3 + 2) * NPTS;
    float mx = 0.f;
    for (int n = t; n < NPTS; n += 256) {
        float dx = px[n] - m0, dy = py[n] - m1, dz = pz[n] - m2;
        mx = fmaxf(mx, sqrtf(dx * dx + dy * dy + dz * dz));
    }
    red[t] = mx; __syncthreads();
    for (int s = 128; s > 0; s >>= 1) { if (t < s) red[t] = fmaxf(red[t], red[t + s]); __syncthreads(); }
    if (t == 0) {
        bstats[b * 4 + 0] = m0; bstats[b * 4 + 1] = m1; bstats[b * 4 + 2] = m2;
        bstats[b * 4 + 3] = 1.f / (2.f * red[0]);
    }
}

// ---------------- per-point voxel index + nc4 + count ----------------
__global__ __launch_bounds__(256) void vox_idx_k(const float* __restrict__ coords,
                                                 const float* __restrict__ bstats,
                                                 float4* __restrict__ nc4,
                                                 int* __restrict__ vidx,
                                                 int* __restrict__ slot,
                                                 unsigned int* __restrict__ cnts) {
    int g = blockIdx.x * 256 + threadIdx.x;
    int b = g >> 14, n = g & (NPTS - 1);
    float m0 = bstats[b * 4 + 0], m1 = bstats[b * 4 + 1], m2 = bstats[b * 4 + 2];
    float sc = bstats[b * 4 + 3];
    float x = coords[((size_t)b * 3 + 0) * NPTS + n];
    float y = coords[((size_t)b * 3 + 1) * NPTS + n];
    float z = coords[((size_t)b * 3 + 2) * NPTS + n];
    float ncx = fminf(fmaxf(((x - m0) * sc + 0.5f) * (float)RES, 0.f), RES - 1.f);
    float ncy = fminf(fmaxf(((y - m1) * sc + 0.5f) * (float)RES, 0.f), RES - 1.f);
    float ncz = fminf(fmaxf(((z - m2) * sc + 0.5f) * (float)RES, 0.f), RES - 1.f);
    nc4[g] = make_float4(ncx, ncy, ncz, 0.f);
    int ix = min(max((int)rintf(ncx), 0), RES - 1);  // rintf = half-even = jnp.round
    int iy = min(max((int)rintf(ncy), 0), RES - 1);
    int iz = min(max((int)rintf(ncz), 0), RES - 1);
    int v = b * R3 + (ix * RES + iy) * RES + iz;
    vidx[g] = v;
    slot[g] = (int)atomicAdd(&cnts[v], 1u);
}

// ---------------- feature transpose: [b][64][N] fp32 -> [g][64] fp32 ----------------
__global__ __launch_bounds__(256) void transpose_feats_k(const float* __restrict__ feats,
                                                         float* __restrict__ featT) {
    int blk = blockIdx.x;
    int b = blk >> 8, ntile = blk & 255;
    int t = threadIdx.x;
    __shared__ float lds[64][65];
    for (int e = t; e < 64 * 64; e += 256) {
        int c = e >> 6, n = e & 63;
        lds[c][n] = feats[((size_t)b * CIN + c) * NPTS + ntile * 64 + n];
    }
    __syncthreads();
    for (int e = t; e < 64 * 64; e += 256) {
        int n = e >> 6, c = e & 63;
        featT[(((size_t)b << 14) + ntile * 64 + n) * CIN + c] = lds[c][n];
    }
}

// ---------------- scan ----------------
__global__ __launch_bounds__(256) void scan1_k(const unsigned int* __restrict__ cnts,
                                               unsigned int* __restrict__ offs,
                                               unsigned int* __restrict__ part) {
    int t = threadIdx.x;
    int g = blockIdx.x * 256 + t;
    unsigned int v = cnts[g];
    __shared__ unsigned int s[256];
    s[t] = v; __syncthreads();
    for (int d = 1; d < 256; d <<= 1) {
        unsigned int x = (t >= d) ? s[t - d] : 0u;
        __syncthreads();
        s[t] += x;
        __syncthreads();
    }
    offs[g] = s[t] - v;
    if (t == 255) part[blockIdx.x] = s[255];
}

__global__ __launch_bounds__(1024) void scan2_k(unsigned int* __restrict__ part) {
    int t = threadIdx.x;
    unsigned int v = part[t];
    __shared__ unsigned int s[1024];
    s[t] = v; __syncthreads();
    for (int d = 1; d < 1024; d <<= 1) {
        unsigned int x = (t >= d) ? s[t - d] : 0u;
        __syncthreads();
        s[t] += x;
        __syncthreads();
    }
    part[t] = s[t] - v;
}

__global__ __launch_bounds__(256) void scan3_k(unsigned int* __restrict__ offs,
                                               const unsigned int* __restrict__ part) {
    int g = blockIdx.x * 256 + threadIdx.x;
    offs[g] += part[blockIdx.x];
}

// ---------------- scatter global point id into CSR ----------------
__global__ __launch_bounds__(256) void scatter_pts_k(const int* __restrict__ vidx,
                                                     const int* __restrict__ slot,
                                                     const unsigned int* __restrict__ offs,
                                                     unsigned int* __restrict__ pidx2) {
    int g = blockIdx.x * 256 + threadIdx.x;
    int v = vidx[g];
    pidx2[offs[v] + slot[g]] = (unsigned int)g;
}

// ---------------- gather: CSR mean -> bf16 channel-last vox ----------------
__global__ __launch_bounds__(256) void gather_k(const float* __restrict__ featT,
                                                const unsigned int* __restrict__ cnts,
                                                const unsigned int* __restrict__ offs,
                                                const unsigned int* __restrict__ pidx2,
                                                bf16* __restrict__ voxCL) {
    int u = blockIdx.x * 256 + threadIdx.x;
    int v = u >> 3;
    int l8 = u & 7;
    unsigned int cnt = cnts[v];
    unsigned int off = offs[v];
    float acc[8] = {0.f, 0.f, 0.f, 0.f, 0.f, 0.f, 0.f, 0.f};
    for (unsigned int i = 0; i < cnt; ++i) {
        unsigned int g = pidx2[off + i];
        const float4* fp = (const float4*)(featT + (size_t)g * CIN + l8 * 8);
        float4 f0 = fp[0], f1 = fp[1];
        acc[0] += f0.x; acc[1] += f0.y; acc[2] += f0.z; acc[3] += f0.w;
        acc[4] += f1.x; acc[5] += f1.y; acc[6] += f1.z; acc[7] += f1.w;
    }
    float inv = 1.f / fmaxf((float)cnt, 1.f);
    ushort o[8];
#pragma unroll
    for (int j = 0; j < 8; ++j) o[j] = f2bu(acc[j] * inv);
    *(short8*)(voxCL + (size_t)v * CIN + l8 * 8) = *(short8*)o;
}

// ---------------- weight reorder: [co][ci][27] fp32 -> [t][c32][co][kb][8] bf16 ----------------
template <int CIN_T>
__global__ __launch_bounds__(256) void wreorder_k(const float* __restrict__ w,
                                                  bf16* __restrict__ wf) {
    const int NC = CIN_T / 32;
    int u = blockIdx.x * 256 + threadIdx.x;
    if (u >= 27 * NC * 128 * 4) return;
    int kb = u & 3;
    int co = (u >> 2) & 127;
    int c32 = (u >> 9) % NC;
    int t = u / (512 * NC);
    int cibase = c32 * 32 + kb * 8;
    ushort o[8];
#pragma unroll
    for (int j = 0; j < 8; ++j)
        o[j] = f2bu(w[((size_t)co * CIN_T + cibase + j) * 27 + t]);
    *(short8*)(wf + (size_t)u * 8) = *(short8*)o;
}

// ---------------- wp transpose: [co][ci] -> [ci][co] fp32 ----------------
__global__ __launch_bounds__(256) void wpt_k(const float* __restrict__ wp,
                                             float* __restrict__ wpT) {
    int u = blockIdx.x * 256 + threadIdx.x;  // 8192
    int co = u & 127, ci = u >> 7;
    wpT[ci * 128 + co] = wp[co * 64 + ci];
}

// ---------------- implicit-GEMM conv3d 3x3x3 via MFMA bf16 (R7 mapping) ----------------
template <int CIN_T>
__global__ __launch_bounds__(512, 2) void conv3d_mfma_k(const bf16* __restrict__ x,
                                                        const bf16* __restrict__ wf,
                                                        const float* __restrict__ bias,
                                                        bf16* __restrict__ y,
                                                        float* __restrict__ gnacc) {
    constexpr int NC = CIN_T / 32;
    int blk = blockIdx.x;
    int hq = blk & 7;
    int d = (blk >> 3) & 31;
    int b = blk >> 8;
    int t = threadIdx.x;
    int lane = t & 63;
    int wid = t >> 6;
    int cog = wid >> 2;  // 0..1
    int sg = wid & 3;    // 0..3
    int lr = lane & 15;
    int kb = lane >> 4;

    __shared__ __align__(16) char xs[3 * 6 * 34 * 80];
    __shared__ float gred[8][2];
    if (t < 16) gred[t >> 1][t & 1] = 0.f;

    f32x4 acc[4][2];
#pragma unroll
    for (int r = 0; r < 4; ++r)
#pragma unroll
        for (int j = 0; j < 2; ++j) acc[r][j] = (f32x4){0.f, 0.f, 0.f, 0.f};

    int bbase[2];
#pragma unroll
    for (int j = 0; j < 2; ++j)
        bbase[j] = ((sg * 34) + (j * 16 + lr)) * 80 + kb * 16;

    for (int cc = 0; cc < NC; ++cc) {
        __syncthreads();
        for (int e = t; e < 612 * 4; e += 512) {
            int ekb = e & 3;
            int pos = e >> 2;
            int ww = pos % 34;
            int hh = (pos / 34) % 6;
            int dd = pos / 204;
            int dz = d + dd - 1;
            int hz = hq * 4 + hh - 1;
            int wz = ww - 1;
            short8 v = {0, 0, 0, 0, 0, 0, 0, 0};
            if (dz >= 0 && dz < RES && hz >= 0 && hz < RES && wz >= 0 && wz < RES)
                v = *(const short8*)(x + ((size_t)b * R3 + dz * 1024 + hz * 32 + wz) * CIN_T + cc * 32 + ekb * 8);
            *(short8*)(xs + pos * 80 + ekb * 16) = v;
        }
        __syncthreads();

        const short8* wfp = (const short8*)wf;
        size_t abase = ((size_t)cc * 128 + cog * 64 + lr) * 4 + kb;
#pragma unroll
        for (int dd = 0; dd < 3; ++dd)
#pragma unroll
            for (int dh = 0; dh < 3; ++dh)
#pragma unroll
                for (int dw = 0; dw < 3; ++dw) {
                    int tap = (dd * 3 + dh) * 3 + dw;
                    size_t ab = abase + (size_t)tap * NC * 512;
                    short8 a0 = wfp[ab];
                    short8 a1 = wfp[ab + 64];
                    short8 a2 = wfp[ab + 128];
                    short8 a3 = wfp[ab + 192];
                    int toff = ((dd * 6 + dh) * 34 + dw) * 80;
                    short8 b0 = *(const short8*)(xs + bbase[0] + toff);
                    short8 b1 = *(const short8*)(xs + bbase[1] + toff);
                    acc[0][0] = __builtin_amdgcn_mfma_f32_16x16x32_bf16(a0, b0, acc[0][0], 0, 0, 0);
                    acc[0][1] = __builtin_amdgcn_mfma_f32_16x16x32_bf16(a0, b1, acc[0][1], 0, 0, 0);
                    acc[1][0] = __builtin_amdgcn_mfma_f32_16x16x32_bf16(a1, b0, acc[1][0], 0, 0, 0);
                    acc[1][1] = __builtin_amdgcn_mfma_f32_16x16x32_bf16(a1, b1, acc[1][1], 0, 0, 0);
                    acc[2][0] = __builtin_amdgcn_mfma_f32_16x16x32_bf16(a2, b0, acc[2][0], 0, 0, 0);
                    acc[2][1] = __builtin_amdgcn_mfma_f32_16x16x32_bf16(a2, b1, acc[2][1], 0, 0, 0);
                    acc[3][0] = __builtin_amdgcn_mfma_f32_16x16x32_bf16(a3, b0, acc[3][0], 0, 0, 0);
                    acc[3][1] = __builtin_amdgcn_mfma_f32_16x16x32_bf16(a3, b1, acc[3][1], 0, 0, 0);
                }
    }

    float sred[4], ssred[4];
#pragma unroll
    for (int r = 0; r < 4; ++r) {
        int co = cog * 64 + r * 16 + kb * 4;
        float4 bv = *(const float4*)(bias + co);
        float s = 0.f, ss = 0.f;
#pragma unroll
        for (int j = 0; j < 2; ++j) {
            int p = d * 1024 + (hq * 4 + sg) * 32 + (j * 16 + lr);
            float v0 = acc[r][j][0] + bv.x;
            float v1 = acc[r][j][1] + bv.y;
            float v2 = acc[r][j][2] + bv.z;
            float v3 = acc[r][j][3] + bv.w;
            ushort4 o;
            o.x = f2bu(v0); o.y = f2bu(v1); o.z = f2bu(v2); o.w = f2bu(v3);
            *(ushort4*)(y + ((size_t)b * R3 + p) * COUT + co) = o;
            s += v0 + v1 + v2 + v3;
            ss += v0 * v0 + v1 * v1 + v2 * v2 + v3 * v3;
        }
        sred[r] = s; ssred[r] = ss;
    }
#pragma unroll
    for (int m = 1; m < 64; m <<= 1) {
#pragma unroll
        for (int r = 0; r < 4; ++r) {
            sred[r] += __shfl_xor(sred[r], m, 64);
            ssred[r] += __shfl_xor(ssred[r], m, 64);
        }
    }
    if (lane == 0) {
#pragma unroll
        for (int r = 0; r < 4; ++r) {
            atomicAdd(&gred[cog * 4 + r][0], sred[r]);
            atomicAdd(&gred[cog * 4 + r][1], ssred[r]);
        }
    }
    __syncthreads();
    if (t < 16) atomicAdd(&gnacc[(b * 8 + (t >> 1)) * 2 + (t & 1)], gred[t >> 1][t & 1]);
}

// ---------------- GN apply + swish (act1 only) ----------------
__global__ __launch_bounds__(256) void gn_apply_cl_k(bf16* __restrict__ x,
                                                     const float* __restrict__ gnacc,
                                                     const float* __restrict__ gamma,
                                                     const float* __restrict__ beta) {
    int u = blockIdx.x * 256 + threadIdx.x;
    int ci8 = u & 15;
    int p = (u >> 4) & (R3 - 1);
    int b = u >> 19;
    int ci = ci8 * 8;
    int bg = b * 8 + (ci8 >> 1);
    const float M = (float)(GSIZE * R3);
    float s = gnacc[bg * 2], ss = gnacc[bg * 2 + 1];
    float mean = s / M;
    float istd = rsqrtf(fmaxf(ss / M - mean * mean, 0.f) + 1e-5f);
    bf16* ptr = x + ((size_t)b * R3 + p) * COUT + ci;
    short8 v = *(const short8*)ptr;
    ushort o[8];
#pragma unroll
    for (int j = 0; j < 8; ++j) {
        float f = b2f((ushort)v[j]);
        float yv = fmaf((f - mean) * istd, gamma[ci + j], beta[ci + j]);
        o[j] = f2bu(yv / (1.f + expf(-yv)));
    }
    *(short8*)ptr = *(short8*)o;
}

// ---------------- point branch: GN stats ONLY (no pf store) ----------------
__global__ __launch_bounds__(256) void pgemm_stats_k(const float* __restrict__ feats,
                                                     const float* __restrict__ wp,
                                                     const float* __restrict__ bp,
                                                     float* __restrict__ gnacc) {
    int blk = blockIdx.x;
    int b = blk / (NPTS / 256);
    int n = (blk % (NPTS / 256)) * 256 + threadIdx.x;
    int lane = threadIdx.x & 63;
    float f[CIN];
    const float* fp = feats + ((size_t)b * CIN) * NPTS + n;
#pragma unroll
    for (int ci = 0; ci < CIN; ++ci) f[ci] = fp[(size_t)ci * NPTS];
    float gs[8], gss[8];
#pragma unroll
    for (int g = 0; g < 8; ++g) { gs[g] = 0.f; gss[g] = 0.f; }
#pragma unroll
    for (int g = 0; g < 8; ++g) {
#pragma unroll
        for (int h = 0; h < 2; ++h) {
            int c0 = g * 16 + h * 8;
            float a[8];
#pragma unroll
            for (int k = 0; k < 8; ++k) a[k] = bp[c0 + k];
#pragma unroll
            for (int ci = 0; ci < CIN; ++ci) {
                float fv = f[ci];
#pragma unroll
                for (int k = 0; k < 8; ++k) a[k] = fmaf(wp[(size_t)(c0 + k) * CIN + ci], fv, a[k]);
            }
#pragma unroll
            for (int k = 0; k < 8; ++k) { gs[g] += a[k]; gss[g] = fmaf(a[k], a[k], gss[g]); }
        }
    }
#pragma unroll
    for (int m = 1; m < 64; m <<= 1) {
#pragma unroll
        for (int g = 0; g < 8; ++g) {
            gs[g] += __shfl_xor(gs[g], m, 64);
            gss[g] += __shfl_xor(gss[g], m, 64);
        }
    }
    if (lane == 0) {
#pragma unroll
        for (int g = 0; g < 8; ++g) {
            atomicAdd(&gnacc[(b * 8 + g) * 2 + 0], gs[g]);
            atomicAdd(&gnacc[(b * 8 + g) * 2 + 1], gss[g]);
        }
    }
}

// ---------------- fuse2: 8 lanes/point; pf inline + GN + swish + devox + add ----------------
// thread (slot s, l8): owns channels c0=l8*16..+15 (= GN group l8) for point g=pidx2[s].
// All loads/stores contiguous per point (512B rows), corners 256B/corner/point.
__global__ __launch_bounds__(256) void fuse2_k(const bf16* __restrict__ vox,   // act2 [b][p][128]
                                               const float* __restrict__ featT,// [g][64]
                                               const float* __restrict__ wpT,  // [64][128]
                                               const float* __restrict__ bp,
                                               const float4* __restrict__ nc4,
                                               const unsigned int* __restrict__ pidx2,
                                               const float* __restrict__ gn2acc,
                                               const float* __restrict__ gnpacc,
                                               const float* __restrict__ g2g,
                                               const float* __restrict__ g2b,
                                               const float* __restrict__ gpg,
                                               const float* __restrict__ gpb,
                                               float* __restrict__ pfT) {      // [g][128]
    __shared__ float wls[64 * 128];  // 32 KB
    int t = threadIdx.x;
    for (int e = t; e < 64 * 128 / 4; e += 256)
        ((float4*)wls)[e] = ((const float4*)wpT)[e];
    __syncthreads();

    int u = blockIdx.x * 256 + t;
    int s = u >> 3;
    int l8 = u & 7;
    unsigned int g = pidx2[s];
    int b = (int)(g >> 14);
    int c0 = l8 * 16;

    // --- point-branch GEMM for 16 channels ---
    float a[16];
#pragma unroll
    for (int k = 0; k < 16; ++k) a[k] = bp[c0 + k];
    const float* fg = featT + (size_t)g * CIN;
    for (int ci = 0; ci < CIN; ++ci) {
        float fv = fg[ci];
        const float* wrow = wls + ci * 128 + c0;
#pragma unroll
        for (int k = 0; k < 16; ++k) a[k] = fmaf(wrow[k], fv, a[k]);
    }

    // --- GN coefficients (group = l8) ---
    int bg = b * 8 + l8;
    const float M2 = (float)(GSIZE * R3);
    const float Mp = (float)(GSIZE * NPTS);
    float s2 = gn2acc[bg * 2], ss2 = gn2acc[bg * 2 + 1];
    float mean2 = s2 / M2;
    float istd2 = rsqrtf(fmaxf(ss2 / M2 - mean2 * mean2, 0.f) + 1e-5f);
    float sp = gnpacc[bg * 2], ssp = gnpacc[bg * 2 + 1];
    float meanp = sp / Mp;
    float istdp = rsqrtf(fmaxf(ssp / Mp - meanp * meanp, 0.f) + 1e-5f);
    float ga[16], gb[16];
#pragma unroll
    for (int j = 0; j < 16; ++j) {
        float gm = g2g[c0 + j];
        ga[j] = istd2 * gm;
        gb[j] = g2b[c0 + j] - mean2 * istd2 * gm;
    }

    // --- trilinear setup ---
    float4 c4 = nc4[g];
    const float CMAX = (float)(RES - 1) - 1e-6f;
    float cx = fminf(c4.x, CMAX), cy = fminf(c4.y, CMAX), cz = fminf(c4.z, CMAX);
    int ix0 = (int)cx, iy0 = (int)cy, iz0 = (int)cz;
    float fx = cx - ix0, fy = cy - iy0, fz = cz - iz0;
    int ix1 = min(ix0 + 1, RES - 1), iy1 = min(iy0 + 1, RES - 1), iz1 = min(iz0 + 1, RES - 1);
    float gx0 = 1.f - fx, gy0 = 1.f - fy, gz0 = 1.f - fz;
    float wc[8] = {gx0 * gy0 * gz0, gx0 * gy0 * fz, gx0 * fy * gz0, gx0 * fy * fz,
                   fx * gy0 * gz0,  fx * gy0 * fz,  fx * fy * gz0,  fx * fy * fz};
    int fi[8];
    fi[0] = (ix0 * RES + iy0) * RES + iz0; fi[1] = (ix0 * RES + iy0) * RES + iz1;
    fi[2] = (ix0 * RES + iy1) * RES + iz0; fi[3] = (ix0 * RES + iy1) * RES + iz1;
    fi[4] = (ix1 * RES + iy0) * RES + iz0; fi[5] = (ix1 * RES + iy0) * RES + iz1;
    fi[6] = (ix1 * RES + iy1) * RES + iz0; fi[7] = (ix1 * RES + iy1) * RES + iz1;

    const bf16* vb = vox + (size_t)b * R3 * COUT + c0;
    float accv[16] = {0.f, 0.f, 0.f, 0.f, 0.f, 0.f, 0.f, 0.f,
                      0.f, 0.f, 0.f, 0.f, 0.f, 0.f, 0.f, 0.f};
#pragma unroll
    for (int f = 0; f < 8; ++f) {
        const short8* vp = (const short8*)(vb + (size_t)fi[f] * COUT);
        short8 v0 = vp[0], v1 = vp[1];
        float wgt = wc[f];
#pragma unroll
        for (int j = 0; j < 8; ++j) {
            float yv = fmaf(b2f((ushort)v0[j]), ga[j], gb[j]);
            accv[j] = fmaf(wgt, yv / (1.f + expf(-yv)), accv[j]);
        }
#pragma unroll
        for (int j = 0; j < 8; ++j) {
            float yv = fmaf(b2f((ushort)v1[j]), ga[8 + j], gb[8 + j]);
            accv[8 + j] = fmaf(wgt, yv / (1.f + expf(-yv)), accv[8 + j]);
        }
    }

    // --- combine: swish(GNp(pf)) + devox ---
    float outv[16];
#pragma unroll
    for (int j = 0; j < 16; ++j) {
        float pm = gpg[c0 + j];
        float yv = fmaf((a[j] - meanp) * istdp, pm, gpb[c0 + j]);
        outv[j] = yv / (1.f + expf(-yv)) + accv[j];
    }
    float* pp = pfT + (size_t)g * COUT + c0;
#pragma unroll
    for (int k = 0; k < 4; ++k)
        *(float4*)(pp + k * 4) = make_float4(outv[k*4], outv[k*4+1], outv[k*4+2], outv[k*4+3]);
}

// ---------------- transpose pfT [b][n][128] -> out [b][128][n] ----------------
__global__ __launch_bounds__(256) void transpose_out_k(const float* __restrict__ pfT,
                                                       float* __restrict__ out) {
    int blk = blockIdx.x;
    int b = blk >> 8, nt = blk & 255;
    int t = threadIdx.x;
    int n0 = nt * 64;
    __shared__ float lds[64][129];
#pragma unroll
    for (int k = 0; k < 8; ++k) {
        int e = t + k * 256;
        int row = e >> 5, c4 = e & 31;
        float4 v = ((const float4*)pfT)[(((size_t)b << 14) + n0 + row) * 32 + c4];
        lds[row][c4 * 4 + 0] = v.x;
        lds[row][c4 * 4 + 1] = v.y;
        lds[row][c4 * 4 + 2] = v.z;
        lds[row][c4 * 4 + 3] = v.w;
    }
    __syncthreads();
#pragma unroll
    for (int k = 0; k < 32; ++k) {
        int e = t + k * 256;
        int c = e >> 6, n = e & 63;
        out[((size_t)b * COUT + c) * NPTS + n0 + n] = lds[n][c];
    }
}

extern "C" void kernel_launch(void* const* d_in, const int* in_sizes, int n_in,
                              void* d_out, int out_size, void* d_ws, size_t ws_size,
                              hipStream_t stream) {
    const float* features = (const float*)d_in[0];
    const float* coords   = (const float*)d_in[1];
    const float* w1  = (const float*)d_in[3];
    const float* b1  = (const float*)d_in[4];
    const float* g1g = (const float*)d_in[5];
    const float* g1b = (const float*)d_in[6];
    const float* w2  = (const float*)d_in[7];
    const float* b2  = (const float*)d_in[8];
    const float* g2g = (const float*)d_in[9];
    const float* g2b = (const float*)d_in[10];
    const float* wp  = (const float*)d_in[11];
    const float* bp  = (const float*)d_in[12];
    const float* gpg = (const float*)d_in[13];
    const float* gpb = (const float*)d_in[14];
    float* out = (float*)d_out;

    // ws (~199 MB):
    //   [0,64MB)     act1 bf16 -> pfT fp32 (overlay; act1 dead after conv2)
    //   [64,128MB)   act2 bf16 (live until fuse2)
    //   [128,160MB)  voxCL bf16
    //   [160,192MB)  featT fp32 (live until fuse2)
    //   tail: w1f, w2f, wpT, nc4, cnts, offs, vidx, slot, pidx2, part, stats
    char* ws = (char*)d_ws;
    size_t off = 0;
    bf16* act1 = (bf16*)(ws + off);
    float* pfT = (float*)(ws + off);         off += (size_t)BATCH * R3 * COUT * 2;  // 64MB
    bf16* act2 = (bf16*)(ws + off);          off += (size_t)BATCH * R3 * COUT * 2;  // 64MB
    bf16* voxCL = (bf16*)(ws + off);         off += (size_t)BATCH * R3 * CIN * 2;   // 32MB
    float* featT = (float*)(ws + off);       off += (size_t)BATCH * NPTS * CIN * 4; // 32MB
    bf16* w1f = (bf16*)(ws + off);           off += (size_t)27 * 2 * 128 * 32 * 2;
    bf16* w2f = (bf16*)(ws + off);           off += (size_t)27 * 4 * 128 * 32 * 2;
    float* wpT = (float*)(ws + off);         off += 64 * 128 * 4;
    float4* nc4 = (float4*)(ws + off);       off += (size_t)BATCH * NPTS * 16;
    unsigned int* cnts = (unsigned int*)(ws + off);  off += (size_t)BATCH * R3 * 4;
    unsigned int* offs = (unsigned int*)(ws + off);  off += (size_t)BATCH * R3 * 4;
    int* vidx = (int*)(ws + off);            off += (size_t)BATCH * NPTS * 4;
    int* slot = (int*)(ws + off);            off += (size_t)BATCH * NPTS * 4;
    unsigned int* pidx2 = (unsigned int*)(ws + off); off += (size_t)BATCH * NPTS * 4;
    unsigned int* part = (unsigned int*)(ws + off);  off += 4096;
    float* bstats = (float*)(ws + off);      off += 256;
    float* gn1acc = (float*)(ws + off);      off += 512;
    float* gn2acc = (float*)(ws + off);      off += 512;
    float* gnpacc = (float*)(ws + off);      off += 512;

    hipMemsetAsync(cnts, 0, (size_t)BATCH * R3 * 4, stream);
    hipMemsetAsync(gn1acc, 0, 3 * 512, stream);

    coord_stats_k<<<BATCH, 256, 0, stream>>>(coords, bstats);
    vox_idx_k<<<BATCH * NPTS / 256, 256, 0, stream>>>(coords, bstats, nc4, vidx, slot, cnts);
    transpose_feats_k<<<BATCH * 256, 256, 0, stream>>>(features, featT);
    scan1_k<<<BATCH * R3 / 256, 256, 0, stream>>>(cnts, offs, part);
    scan2_k<<<1, 1024, 0, stream>>>(part);
    scan3_k<<<BATCH * R3 / 256, 256, 0, stream>>>(offs, part);
    scatter_pts_k<<<BATCH * NPTS / 256, 256, 0, stream>>>(vidx, slot, offs, pidx2);
    gather_k<<<BATCH * R3 * 8 / 256, 256, 0, stream>>>(featT, cnts, offs, pidx2, voxCL);

    wreorder_k<CIN><<<(27 * 2 * 128 * 4 + 255) / 256, 256, 0, stream>>>(w1, w1f);
    wreorder_k<COUT><<<(27 * 4 * 128 * 4 + 255) / 256, 256, 0, stream>>>(w2, w2f);
    wpt_k<<<32, 256, 0, stream>>>(wp, wpT);

    conv3d_mfma_k<CIN><<<BATCH * 32 * 8, 512, 0, stream>>>(voxCL, w1f, b1, act1, gn1acc);
    gn_apply_cl_k<<<BATCH * R3 * 16 / 256, 256, 0, stream>>>(act1, gn1acc, g1g, g1b);

    conv3d_mfma_k<COUT><<<BATCH * 32 * 8, 512, 0, stream>>>(act1, w2f, b2, act2, gn2acc);

    pgemm_stats_k<<<BATCH * NPTS / 256, 256, 0, stream>>>(features, wp, bp, gnpacc);

    fuse2_k<<<BATCH * NPTS * 8 / 256, 256, 0, stream>>>(act2, featT, wpT, bp, nc4, pidx2,
                                                        gn2acc, gnpacc, g2g, g2b, gpg, gpb, pfT);

    transpose_out_k<<<BATCH * 256, 256, 0, stream>>>(pfT, out);
}

// Round 9
// 1086.477 us; speedup vs baseline: 1.3979x; 1.2260x over previous
//
#include <hip/hip_runtime.h>
#include <hip/hip_bf16.h>
#include <cmath>

#define BATCH 8
#define CIN 64
#define COUT 128
#define NPTS 16384
#define RES 32
#define R3 32768
#define NGROUP 8
#define GSIZE 16

typedef __hip_bfloat16 bf16;
typedef __attribute__((ext_vector_type(8))) short short8;
typedef __attribute__((ext_vector_type(4))) float f32x4;

__device__ inline float b2f(ushort u) { union { float f; uint v; } x; x.v = ((uint)u) << 16; return x.f; }
__device__ inline ushort f2bu(float f) { __hip_bfloat16 h = __float2bfloat16(f); return *reinterpret_cast<ushort*>(&h); }

// ---------------- coord stats ----------------
__global__ __launch_bounds__(256) void coord_stats_k(const float* __restrict__ coords,
                                                     float* __restrict__ bstats) {
    int b = blockIdx.x;
    int t = threadIdx.x;
    __shared__ float red[256];
    __shared__ float means[3];
    for (int c = 0; c < 3; ++c) {
        float acc = 0.f;
        const float* p = coords + ((size_t)b * 3 + c) * NPTS;
        for (int n = t; n < NPTS; n += 256) acc += p[n];
        red[t] = acc; __syncthreads();
        for (int s = 128; s > 0; s >>= 1) { if (t < s) red[t] += red[t + s]; __syncthreads(); }
        if (t == 0) means[c] = red[0] * (1.f / NPTS);
        __syncthreads();
    }
    float m0 = means[0], m1 = means[1], m2 = means[2];
    const float* px = coords + ((size_t)b * 3 + 0) * NPTS;
    const float* py = coords + ((size_t)b * 3 + 1) * NPTS;
    const float* pz = coords + ((size_t)b * 3 + 2) * NPTS;
    float mx = 0.f;
    for (int n = t; n < NPTS; n += 256) {
        float dx = px[n] - m0, dy = py[n] - m1, dz = pz[n] - m2;
        mx = fmaxf(mx, sqrtf(dx * dx + dy * dy + dz * dz));
    }
    red[t] = mx; __syncthreads();
    for (int s = 128; s > 0; s >>= 1) { if (t < s) red[t] = fmaxf(red[t], red[t + s]); __syncthreads(); }
    if (t == 0) {
        bstats[b * 4 + 0] = m0; bstats[b * 4 + 1] = m1; bstats[b * 4 + 2] = m2;
        bstats[b * 4 + 3] = 1.f / (2.f * red[0]);
    }
}

// ---------------- per-point voxel index + nc4 + count ----------------
__global__ __launch_bounds__(256) void vox_idx_k(const float* __restrict__ coords,
                                                 const float* __restrict__ bstats,
                                                 float4* __restrict__ nc4,
                                                 int* __restrict__ vidx,
                                                 int* __restrict__ slot,
                                                 unsigned int* __restrict__ cnts) {
    int g = blockIdx.x * 256 + threadIdx.x;
    int b = g >> 14, n = g & (NPTS - 1);
    float m0 = bstats[b * 4 + 0], m1 = bstats[b * 4 + 1], m2 = bstats[b * 4 + 2];
    float sc = bstats[b * 4 + 3];
    float x = coords[((size_t)b * 3 + 0) * NPTS + n];
    float y = coords[((size_t)b * 3 + 1) * NPTS + n];
    float z = coords[((size_t)b * 3 + 2) * NPTS + n];
    float ncx = fminf(fmaxf(((x - m0) * sc + 0.5f) * (float)RES, 0.f), RES - 1.f);
    float ncy = fminf(fmaxf(((y - m1) * sc + 0.5f) * (float)RES, 0.f), RES - 1.f);
    float ncz = fminf(fmaxf(((z - m2) * sc + 0.5f) * (float)RES, 0.f), RES - 1.f);
    nc4[g] = make_float4(ncx, ncy, ncz, 0.f);
    int ix = min(max((int)rintf(ncx), 0), RES - 1);  // rintf = half-even = jnp.round
    int iy = min(max((int)rintf(ncy), 0), RES - 1);
    int iz = min(max((int)rintf(ncz), 0), RES - 1);
    int v = b * R3 + (ix * RES + iy) * RES + iz;
    vidx[g] = v;
    slot[g] = (int)atomicAdd(&cnts[v], 1u);
}

// ---------------- feature transpose: [b][64][N] fp32 -> [g][64] fp32 ----------------
__global__ __launch_bounds__(256) void transpose_feats_k(const float* __restrict__ feats,
                                                         float* __restrict__ featT) {
    int blk = blockIdx.x;
    int b = blk >> 8, ntile = blk & 255;
    int t = threadIdx.x;
    __shared__ float lds[64][65];
    for (int e = t; e < 64 * 64; e += 256) {
        int c = e >> 6, n = e & 63;
        lds[c][n] = feats[((size_t)b * CIN + c) * NPTS + ntile * 64 + n];
    }
    __syncthreads();
    for (int e = t; e < 64 * 64; e += 256) {
        int n = e >> 6, c = e & 63;
        featT[(((size_t)b << 14) + ntile * 64 + n) * CIN + c] = lds[c][n];
    }
}

// ---------------- scan ----------------
__global__ __launch_bounds__(256) void scan1_k(const unsigned int* __restrict__ cnts,
                                               unsigned int* __restrict__ offs,
                                               unsigned int* __restrict__ part) {
    int t = threadIdx.x;
    int g = blockIdx.x * 256 + t;
    unsigned int v = cnts[g];
    __shared__ unsigned int s[256];
    s[t] = v; __syncthreads();
    for (int d = 1; d < 256; d <<= 1) {
        unsigned int x = (t >= d) ? s[t - d] : 0u;
        __syncthreads();
        s[t] += x;
        __syncthreads();
    }
    offs[g] = s[t] - v;
    if (t == 255) part[blockIdx.x] = s[255];
}

__global__ __launch_bounds__(1024) void scan2_k(unsigned int* __restrict__ part) {
    int t = threadIdx.x;
    unsigned int v = part[t];
    __shared__ unsigned int s[1024];
    s[t] = v; __syncthreads();
    for (int d = 1; d < 1024; d <<= 1) {
        unsigned int x = (t >= d) ? s[t - d] : 0u;
        __syncthreads();
        s[t] += x;
        __syncthreads();
    }
    part[t] = s[t] - v;
}

__global__ __launch_bounds__(256) void scan3_k(unsigned int* __restrict__ offs,
                                               const unsigned int* __restrict__ part) {
    int g = blockIdx.x * 256 + threadIdx.x;
    offs[g] += part[blockIdx.x];
}

// ---------------- scatter global point id into CSR ----------------
__global__ __launch_bounds__(256) void scatter_pts_k(const int* __restrict__ vidx,
                                                     const int* __restrict__ slot,
                                                     const unsigned int* __restrict__ offs,
                                                     unsigned int* __restrict__ pidx2) {
    int g = blockIdx.x * 256 + threadIdx.x;
    int v = vidx[g];
    pidx2[offs[v] + slot[g]] = (unsigned int)g;
}

// ---------------- gather: CSR mean -> bf16 channel-last vox ----------------
__global__ __launch_bounds__(256) void gather_k(const float* __restrict__ featT,
                                                const unsigned int* __restrict__ cnts,
                                                const unsigned int* __restrict__ offs,
                                                const unsigned int* __restrict__ pidx2,
                                                bf16* __restrict__ voxCL) {
    int u = blockIdx.x * 256 + threadIdx.x;
    int v = u >> 3;
    int l8 = u & 7;
    unsigned int cnt = cnts[v];
    unsigned int off = offs[v];
    float acc[8] = {0.f, 0.f, 0.f, 0.f, 0.f, 0.f, 0.f, 0.f};
    for (unsigned int i = 0; i < cnt; ++i) {
        unsigned int g = pidx2[off + i];
        const float4* fp = (const float4*)(featT + (size_t)g * CIN + l8 * 8);
        float4 f0 = fp[0], f1 = fp[1];
        acc[0] += f0.x; acc[1] += f0.y; acc[2] += f0.z; acc[3] += f0.w;
        acc[4] += f1.x; acc[5] += f1.y; acc[6] += f1.z; acc[7] += f1.w;
    }
    float inv = 1.f / fmaxf((float)cnt, 1.f);
    ushort o[8];
#pragma unroll
    for (int j = 0; j < 8; ++j) o[j] = f2bu(acc[j] * inv);
    *(short8*)(voxCL + (size_t)v * CIN + l8 * 8) = *(short8*)o;
}

// ---------------- weight reorder: [co][ci][27] fp32 -> [t][c32][co][kb][8] bf16 ----------------
template <int CIN_T>
__global__ __launch_bounds__(256) void wreorder_k(const float* __restrict__ w,
                                                  bf16* __restrict__ wf) {
    const int NC = CIN_T / 32;
    int u = blockIdx.x * 256 + threadIdx.x;
    if (u >= 27 * NC * 128 * 4) return;
    int kb = u & 3;
    int co = (u >> 2) & 127;
    int c32 = (u >> 9) % NC;
    int t = u / (512 * NC);
    int cibase = c32 * 32 + kb * 8;
    ushort o[8];
#pragma unroll
    for (int j = 0; j < 8; ++j)
        o[j] = f2bu(w[((size_t)co * CIN_T + cibase + j) * 27 + t]);
    *(short8*)(wf + (size_t)u * 8) = *(short8*)o;
}

// ---------------- wp transpose: [co][ci] -> [ci][co] fp32 ----------------
__global__ __launch_bounds__(256) void wpt_k(const float* __restrict__ wp,
                                             float* __restrict__ wpT) {
    int u = blockIdx.x * 256 + threadIdx.x;  // 8192
    int co = u & 127, ci = u >> 7;
    wpT[ci * 128 + co] = wp[co * 64 + ci];
}

// ---------------- implicit-GEMM conv3d 3x3x3 via MFMA bf16 ----------------
// R6-proven mapping (4 cog x 2 sg, 80B pos stride, (512,2)) + d-PAIR tile:
// each block computes 2 consecutive d-slices -> each A-load feeds 16 MFMAs
// (was 8), halving the L2 weight-load traffic per output (the R8-measured
// binding constraint: both mappings pinned at ~13.5 TB/s A-read rate).
template <int CIN_T>
__global__ __launch_bounds__(512, 2) void conv3d_mfma_k(const bf16* __restrict__ x,  // [b][p][CIN_T]
                                                        const bf16* __restrict__ wf, // [27][NC][128][4][8]
                                                        const float* __restrict__ bias,
                                                        bf16* __restrict__ y,        // [b][p][128]
                                                        float* __restrict__ gnacc) { // [64][2]
    constexpr int NC = CIN_T / 32;
    int blk = blockIdx.x;
    int hq = blk & 7;
    int dp = (blk >> 3) & 15;
    int b = blk >> 7;
    int d0 = dp * 2;
    int t = threadIdx.x;
    int lane = t & 63;
    int wid = t >> 6;
    int cog = wid >> 1;  // 0..3
    int sg = wid & 1;    // 0..1
    int lr = lane & 15;
    int kb = lane >> 4;

    __shared__ __align__(16) char xs[4 * 6 * 34 * 80];  // 65280 B (4 dd-planes)
    __shared__ float gred[8][2];
    if (t < 16) gred[t >> 1][t & 1] = 0.f;

    f32x4 acc[2][4][2];  // [r][j][dl]
#pragma unroll
    for (int r = 0; r < 2; ++r)
#pragma unroll
        for (int j = 0; j < 4; ++j)
#pragma unroll
            for (int dl = 0; dl < 2; ++dl) acc[r][j][dl] = (f32x4){0.f, 0.f, 0.f, 0.f};

    int bbase[4];
#pragma unroll
    for (int j = 0; j < 4; ++j) {
        int sp = sg * 64 + j * 16 + lr;
        int hl = sp >> 5, wl = sp & 31;
        bbase[j] = (hl * 34 + wl) * 80 + kb * 16;
    }

    for (int cc = 0; cc < NC; ++cc) {
        __syncthreads();
        for (int e = t; e < 816 * 4; e += 512) {
            int ekb = e & 3;
            int pos = e >> 2;
            int ww = pos % 34;
            int hh = (pos / 34) % 6;
            int dd = pos / 204;            // 0..3
            int dz = d0 + dd - 1;
            int hz = hq * 4 + hh - 1;
            int wz = ww - 1;
            short8 v = {0, 0, 0, 0, 0, 0, 0, 0};
            if (dz >= 0 && dz < RES && hz >= 0 && hz < RES && wz >= 0 && wz < RES)
                v = *(const short8*)(x + ((size_t)b * R3 + dz * 1024 + hz * 32 + wz) * CIN_T + cc * 32 + ekb * 8);
            *(short8*)(xs + pos * 80 + ekb * 16) = v;
        }
        __syncthreads();

        const short8* wfp = (const short8*)wf;
        size_t abase = ((size_t)cc * 128 + cog * 32 + lr) * 4 + kb;
#pragma unroll
        for (int dd = 0; dd < 3; ++dd)
#pragma unroll
            for (int dh = 0; dh < 3; ++dh)
#pragma unroll
                for (int dw = 0; dw < 3; ++dw) {
                    int tap = (dd * 3 + dh) * 3 + dw;
                    short8 a0 = wfp[abase + (size_t)tap * NC * 512];
                    short8 a1 = wfp[abase + (size_t)tap * NC * 512 + 64];
                    int toff = ((dd * 6 + dh) * 34 + dw) * 80;   // dl=0 plane; dl=1 at +204*80
                    short8 bb[4], bb2[4];
#pragma unroll
                    for (int j = 0; j < 4; ++j) {
                        bb[j]  = *(const short8*)(xs + bbase[j] + toff);
                        bb2[j] = *(const short8*)(xs + bbase[j] + toff + 16320);
                    }
#pragma unroll
                    for (int j = 0; j < 4; ++j) {
                        acc[0][j][0] = __builtin_amdgcn_mfma_f32_16x16x32_bf16(a0, bb[j],  acc[0][j][0], 0, 0, 0);
                        acc[1][j][0] = __builtin_amdgcn_mfma_f32_16x16x32_bf16(a1, bb[j],  acc[1][j][0], 0, 0, 0);
                        acc[0][j][1] = __builtin_amdgcn_mfma_f32_16x16x32_bf16(a0, bb2[j], acc[0][j][1], 0, 0, 0);
                        acc[1][j][1] = __builtin_amdgcn_mfma_f32_16x16x32_bf16(a1, bb2[j], acc[1][j][1], 0, 0, 0);
                    }
                }
    }

    // epilogue: store bf16 (2 d-slices) + GN partial stats (group = cog*2 + r)
    float sred[2], ssred[2];
#pragma unroll
    for (int r = 0; r < 2; ++r) {
        int co = cog * 32 + r * 16 + kb * 4;
        float4 bv = *(const float4*)(bias + co);
        float s = 0.f, ss = 0.f;
#pragma unroll
        for (int j = 0; j < 4; ++j) {
            int sp = sg * 64 + j * 16 + lr;
#pragma unroll
            for (int dl = 0; dl < 2; ++dl) {
                int p = (d0 + dl) * 1024 + (hq * 4 + (sp >> 5)) * 32 + (sp & 31);
                float v0 = acc[r][j][dl][0] + bv.x;
                float v1 = acc[r][j][dl][1] + bv.y;
                float v2 = acc[r][j][dl][2] + bv.z;
                float v3 = acc[r][j][dl][3] + bv.w;
                ushort4 o;
                o.x = f2bu(v0); o.y = f2bu(v1); o.z = f2bu(v2); o.w = f2bu(v3);
                *(ushort4*)(y + ((size_t)b * R3 + p) * COUT + co) = o;
                s += v0 + v1 + v2 + v3;
                ss += v0 * v0 + v1 * v1 + v2 * v2 + v3 * v3;
            }
        }
        sred[r] = s; ssred[r] = ss;
    }
#pragma unroll
    for (int m = 1; m < 64; m <<= 1) {
#pragma unroll
        for (int r = 0; r < 2; ++r) {
            sred[r] += __shfl_xor(sred[r], m, 64);
            ssred[r] += __shfl_xor(ssred[r], m, 64);
        }
    }
    if (lane == 0) {
#pragma unroll
        for (int r = 0; r < 2; ++r) {
            atomicAdd(&gred[cog * 2 + r][0], sred[r]);
            atomicAdd(&gred[cog * 2 + r][1], ssred[r]);
        }
    }
    __syncthreads();
    if (t < 16) atomicAdd(&gnacc[(b * 8 + (t >> 1)) * 2 + (t & 1)], gred[t >> 1][t & 1]);
}

// ---------------- GN apply + swish (act1 only) ----------------
__global__ __launch_bounds__(256) void gn_apply_cl_k(bf16* __restrict__ x,
                                                     const float* __restrict__ gnacc,
                                                     const float* __restrict__ gamma,
                                                     const float* __restrict__ beta) {
    int u = blockIdx.x * 256 + threadIdx.x;
    int ci8 = u & 15;
    int p = (u >> 4) & (R3 - 1);
    int b = u >> 19;
    int ci = ci8 * 8;
    int bg = b * 8 + (ci8 >> 1);
    const float M = (float)(GSIZE * R3);
    float s = gnacc[bg * 2], ss = gnacc[bg * 2 + 1];
    float mean = s / M;
    float istd = rsqrtf(fmaxf(ss / M - mean * mean, 0.f) + 1e-5f);
    bf16* ptr = x + ((size_t)b * R3 + p) * COUT + ci;
    short8 v = *(const short8*)ptr;
    ushort o[8];
#pragma unroll
    for (int j = 0; j < 8; ++j) {
        float f = b2f((ushort)v[j]);
        float yv = fmaf((f - mean) * istd, gamma[ci + j], beta[ci + j]);
        o[j] = f2bu(yv / (1.f + expf(-yv)));
    }
    *(short8*)ptr = *(short8*)o;
}

// ---------------- point branch: GN stats ONLY ----------------
__global__ __launch_bounds__(256) void pgemm_stats_k(const float* __restrict__ feats,
                                                     const float* __restrict__ wp,
                                                     const float* __restrict__ bp,
                                                     float* __restrict__ gnacc) {
    int blk = blockIdx.x;
    int b = blk / (NPTS / 256);
    int n = (blk % (NPTS / 256)) * 256 + threadIdx.x;
    int lane = threadIdx.x & 63;
    float f[CIN];
    const float* fp = feats + ((size_t)b * CIN) * NPTS + n;
#pragma unroll
    for (int ci = 0; ci < CIN; ++ci) f[ci] = fp[(size_t)ci * NPTS];
    float gs[8], gss[8];
#pragma unroll
    for (int g = 0; g < 8; ++g) { gs[g] = 0.f; gss[g] = 0.f; }
#pragma unroll
    for (int g = 0; g < 8; ++g) {
#pragma unroll
        for (int h = 0; h < 2; ++h) {
            int c0 = g * 16 + h * 8;
            float a[8];
#pragma unroll
            for (int k = 0; k < 8; ++k) a[k] = bp[c0 + k];
#pragma unroll
            for (int ci = 0; ci < CIN; ++ci) {
                float fv = f[ci];
#pragma unroll
                for (int k = 0; k < 8; ++k) a[k] = fmaf(wp[(size_t)(c0 + k) * CIN + ci], fv, a[k]);
            }
#pragma unroll
            for (int k = 0; k < 8; ++k) { gs[g] += a[k]; gss[g] = fmaf(a[k], a[k], gss[g]); }
        }
    }
#pragma unroll
    for (int m = 1; m < 64; m <<= 1) {
#pragma unroll
        for (int g = 0; g < 8; ++g) {
            gs[g] += __shfl_xor(gs[g], m, 64);
            gss[g] += __shfl_xor(gss[g], m, 64);
        }
    }
    if (lane == 0) {
#pragma unroll
        for (int g = 0; g < 8; ++g) {
            atomicAdd(&gnacc[(b * 8 + g) * 2 + 0], gs[g]);
            atomicAdd(&gnacc[(b * 8 + g) * 2 + 1], gss[g]);
        }
    }
}

// ---------------- fuse2: 8 lanes/point; pf inline + GN + swish + devox + add ----------------
__global__ __launch_bounds__(256) void fuse2_k(const bf16* __restrict__ vox,   // act2 [b][p][128]
                                               const float* __restrict__ featT,// [g][64]
                                               const float* __restrict__ wpT,  // [64][128]
                                               const float* __restrict__ bp,
                                               const float4* __restrict__ nc4,
                                               const unsigned int* __restrict__ pidx2,
                                               const float* __restrict__ gn2acc,
                                               const float* __restrict__ gnpacc,
                                               const float* __restrict__ g2g,
                                               const float* __restrict__ g2b,
                                               const float* __restrict__ gpg,
                                               const float* __restrict__ gpb,
                                               float* __restrict__ pfT) {      // [g][128]
    __shared__ float wls[64 * 128];  // 32 KB
    int t = threadIdx.x;
    for (int e = t; e < 64 * 128 / 4; e += 256)
        ((float4*)wls)[e] = ((const float4*)wpT)[e];
    __syncthreads();

    int u = blockIdx.x * 256 + t;
    int s = u >> 3;
    int l8 = u & 7;
    unsigned int g = pidx2[s];
    int b = (int)(g >> 14);
    int c0 = l8 * 16;

    float a[16];
#pragma unroll
    for (int k = 0; k < 16; ++k) a[k] = bp[c0 + k];
    const float* fg = featT + (size_t)g * CIN;
    for (int ci = 0; ci < CIN; ++ci) {
        float fv = fg[ci];
        const float* wrow = wls + ci * 128 + c0;
#pragma unroll
        for (int k = 0; k < 16; ++k) a[k] = fmaf(wrow[k], fv, a[k]);
    }

    int bg = b * 8 + l8;
    const float M2 = (float)(GSIZE * R3);
    const float Mp = (float)(GSIZE * NPTS);
    float s2 = gn2acc[bg * 2], ss2 = gn2acc[bg * 2 + 1];
    float mean2 = s2 / M2;
    float istd2 = rsqrtf(fmaxf(ss2 / M2 - mean2 * mean2, 0.f) + 1e-5f);
    float sp = gnpacc[bg * 2], ssp = gnpacc[bg * 2 + 1];
    float meanp = sp / Mp;
    float istdp = rsqrtf(fmaxf(ssp / Mp - meanp * meanp, 0.f) + 1e-5f);
    float ga[16], gb[16];
#pragma unroll
    for (int j = 0; j < 16; ++j) {
        float gm = g2g[c0 + j];
        ga[j] = istd2 * gm;
        gb[j] = g2b[c0 + j] - mean2 * istd2 * gm;
    }

    float4 c4 = nc4[g];
    const float CMAX = (float)(RES - 1) - 1e-6f;
    float cx = fminf(c4.x, CMAX), cy = fminf(c4.y, CMAX), cz = fminf(c4.z, CMAX);
    int ix0 = (int)cx, iy0 = (int)cy, iz0 = (int)cz;
    float fx = cx - ix0, fy = cy - iy0, fz = cz - iz0;
    int ix1 = min(ix0 + 1, RES - 1), iy1 = min(iy0 + 1, RES - 1), iz1 = min(iz0 + 1, RES - 1);
    float gx0 = 1.f - fx, gy0 = 1.f - fy, gz0 = 1.f - fz;
    float wc[8] = {gx0 * gy0 * gz0, gx0 * gy0 * fz, gx0 * fy * gz0, gx0 * fy * fz,
                   fx * gy0 * gz0,  fx * gy0 * fz,  fx * fy * gz0,  fx * fy * fz};
    int fi[8];
    fi[0] = (ix0 * RES + iy0) * RES + iz0; fi[1] = (ix0 * RES + iy0) * RES + iz1;
    fi[2] = (ix0 * RES + iy1) * RES + iz0; fi[3] = (ix0 * RES + iy1) * RES + iz1;
    fi[4] = (ix1 * RES + iy0) * RES + iz0; fi[5] = (ix1 * RES + iy0) * RES + iz1;
    fi[6] = (ix1 * RES + iy1) * RES + iz0; fi[7] = (ix1 * RES + iy1) * RES + iz1;

    const bf16* vb = vox + (size_t)b * R3 * COUT + c0;
    float accv[16] = {0.f, 0.f, 0.f, 0.f, 0.f, 0.f, 0.f, 0.f,
                      0.f, 0.f, 0.f, 0.f, 0.f, 0.f, 0.f, 0.f};
#pragma unroll
    for (int f = 0; f < 8; ++f) {
        const short8* vp = (const short8*)(vb + (size_t)fi[f] * COUT);
        short8 v0 = vp[0], v1 = vp[1];
        float wgt = wc[f];
#pragma unroll
        for (int j = 0; j < 8; ++j) {
            float yv = fmaf(b2f((ushort)v0[j]), ga[j], gb[j]);
            accv[j] = fmaf(wgt, yv / (1.f + expf(-yv)), accv[j]);
        }
#pragma unroll
        for (int j = 0; j < 8; ++j) {
            float yv = fmaf(b2f((ushort)v1[j]), ga[8 + j], gb[8 + j]);
            accv[8 + j] = fmaf(wgt, yv / (1.f + expf(-yv)), accv[8 + j]);
        }
    }

    float outv[16];
#pragma unroll
    for (int j = 0; j < 16; ++j) {
        float pm = gpg[c0 + j];
        float yv = fmaf((a[j] - meanp) * istdp, pm, gpb[c0 + j]);
        outv[j] = yv / (1.f + expf(-yv)) + accv[j];
    }
    float* pp = pfT + (size_t)g * COUT + c0;
#pragma unroll
    for (int k = 0; k < 4; ++k)
        *(float4*)(pp + k * 4) = make_float4(outv[k*4], outv[k*4+1], outv[k*4+2], outv[k*4+3]);
}

// ---------------- transpose pfT [b][n][128] -> out [b][128][n] ----------------
__global__ __launch_bounds__(256) void transpose_out_k(const float* __restrict__ pfT,
                                                       float* __restrict__ out) {
    int blk = blockIdx.x;
    int b = blk >> 8, nt = blk & 255;
    int t = threadIdx.x;
    int n0 = nt * 64;
    __shared__ float lds[64][129];
#pragma unroll
    for (int k = 0; k < 8; ++k) {
        int e = t + k * 256;
        int row = e >> 5, c4 = e & 31;
        float4 v = ((const float4*)pfT)[(((size_t)b << 14) + n0 + row) * 32 + c4];
        lds[row][c4 * 4 + 0] = v.x;
        lds[row][c4 * 4 + 1] = v.y;
        lds[row][c4 * 4 + 2] = v.z;
        lds[row][c4 * 4 + 3] = v.w;
    }
    __syncthreads();
#pragma unroll
    for (int k = 0; k < 32; ++k) {
        int e = t + k * 256;
        int c = e >> 6, n = e & 63;
        out[((size_t)b * COUT + c) * NPTS + n0 + n] = lds[n][c];
    }
}

extern "C" void kernel_launch(void* const* d_in, const int* in_sizes, int n_in,
                              void* d_out, int out_size, void* d_ws, size_t ws_size,
                              hipStream_t stream) {
    const float* features = (const float*)d_in[0];
    const float* coords   = (const float*)d_in[1];
    const float* w1  = (const float*)d_in[3];
    const float* b1  = (const float*)d_in[4];
    const float* g1g = (const float*)d_in[5];
    const float* g1b = (const float*)d_in[6];
    const float* w2  = (const float*)d_in[7];
    const float* b2  = (const float*)d_in[8];
    const float* g2g = (const float*)d_in[9];
    const float* g2b = (const float*)d_in[10];
    const float* wp  = (const float*)d_in[11];
    const float* bp  = (const float*)d_in[12];
    const float* gpg = (const float*)d_in[13];
    const float* gpb = (const float*)d_in[14];
    float* out = (float*)d_out;

    char* ws = (char*)d_ws;
    size_t off = 0;
    bf16* act1 = (bf16*)(ws + off);
    float* pfT = (float*)(ws + off);         off += (size_t)BATCH * R3 * COUT * 2;  // 64MB
    bf16* act2 = (bf16*)(ws + off);          off += (size_t)BATCH * R3 * COUT * 2;  // 64MB
    bf16* voxCL = (bf16*)(ws + off);         off += (size_t)BATCH * R3 * CIN * 2;   // 32MB
    float* featT = (float*)(ws + off);       off += (size_t)BATCH * NPTS * CIN * 4; // 32MB
    bf16* w1f = (bf16*)(ws + off);           off += (size_t)27 * 2 * 128 * 32 * 2;
    bf16* w2f = (bf16*)(ws + off);           off += (size_t)27 * 4 * 128 * 32 * 2;
    float* wpT = (float*)(ws + off);         off += 64 * 128 * 4;
    float4* nc4 = (float4*)(ws + off);       off += (size_t)BATCH * NPTS * 16;
    unsigned int* cnts = (unsigned int*)(ws + off);  off += (size_t)BATCH * R3 * 4;
    unsigned int* offs = (unsigned int*)(ws + off);  off += (size_t)BATCH * R3 * 4;
    int* vidx = (int*)(ws + off);            off += (size_t)BATCH * NPTS * 4;
    int* slot = (int*)(ws + off);            off += (size_t)BATCH * NPTS * 4;
    unsigned int* pidx2 = (unsigned int*)(ws + off); off += (size_t)BATCH * NPTS * 4;
    unsigned int* part = (unsigned int*)(ws + off);  off += 4096;
    float* bstats = (float*)(ws + off);      off += 256;
    float* gn1acc = (float*)(ws + off);      off += 512;
    float* gn2acc = (float*)(ws + off);      off += 512;
    float* gnpacc = (float*)(ws + off);      off += 512;

    hipMemsetAsync(cnts, 0, (size_t)BATCH * R3 * 4, stream);
    hipMemsetAsync(gn1acc, 0, 3 * 512, stream);

    coord_stats_k<<<BATCH, 256, 0, stream>>>(coords, bstats);
    vox_idx_k<<<BATCH * NPTS / 256, 256, 0, stream>>>(coords, bstats, nc4, vidx, slot, cnts);
    transpose_feats_k<<<BATCH * 256, 256, 0, stream>>>(features, featT);
    scan1_k<<<BATCH * R3 / 256, 256, 0, stream>>>(cnts, offs, part);
    scan2_k<<<1, 1024, 0, stream>>>(part);
    scan3_k<<<BATCH * R3 / 256, 256, 0, stream>>>(offs, part);
    scatter_pts_k<<<BATCH * NPTS / 256, 256, 0, stream>>>(vidx, slot, offs, pidx2);
    gather_k<<<BATCH * R3 * 8 / 256, 256, 0, stream>>>(featT, cnts, offs, pidx2, voxCL);

    wreorder_k<CIN><<<(27 * 2 * 128 * 4 + 255) / 256, 256, 0, stream>>>(w1, w1f);
    wreorder_k<COUT><<<(27 * 4 * 128 * 4 + 255) / 256, 256, 0, stream>>>(w2, w2f);
    wpt_k<<<32, 256, 0, stream>>>(wp, wpT);

    conv3d_mfma_k<CIN><<<BATCH * 16 * 8, 512, 0, stream>>>(voxCL, w1f, b1, act1, gn1acc);
    gn_apply_cl_k<<<BATCH * R3 * 16 / 256, 256, 0, stream>>>(act1, gn1acc, g1g, g1b);

    conv3d_mfma_k<COUT><<<BATCH * 16 * 8, 512, 0, stream>>>(act1, w2f, b2, act2, gn2acc);

    pgemm_stats_k<<<BATCH * NPTS / 256, 256, 0, stream>>>(features, wp, bp, gnpacc);

    fuse2_k<<<BATCH * NPTS * 8 / 256, 256, 0, stream>>>(act2, featT, wpT, bp, nc4, pidx2,
                                                        gn2acc, gnpacc, g2g, g2b, gpg, gpb, pfT);

    transpose_out_k<<<BATCH * 256, 256, 0, stream>>>(pfT, out);
}

// Round 10
// 806.368 us; speedup vs baseline: 1.8835x; 1.3474x over previous
//
#include <hip/hip_runtime.h>
#include <hip/hip_bf16.h>
#include <cmath>

#define BATCH 8
#define CIN 64
#define COUT 128
#define NPTS 16384
#define RES 32
#define R3 32768
#define NGROUP 8
#define GSIZE 16

typedef __hip_bfloat16 bf16;
typedef __attribute__((ext_vector_type(8))) short short8;
typedef __attribute__((ext_vector_type(4))) float f32x4;

__device__ inline float b2f(ushort u) { union { float f; uint v; } x; x.v = ((uint)u) << 16; return x.f; }
__device__ inline ushort f2bu(float f) { __hip_bfloat16 h = __float2bfloat16(f); return *reinterpret_cast<ushort*>(&h); }

// ---------------- coord stats ----------------
__global__ __launch_bounds__(256) void coord_stats_k(const float* __restrict__ coords,
                                                     float* __restrict__ bstats) {
    int b = blockIdx.x;
    int t = threadIdx.x;
    __shared__ float red[256];
    __shared__ float means[3];
    for (int c = 0; c < 3; ++c) {
        float acc = 0.f;
        const float* p = coords + ((size_t)b * 3 + c) * NPTS;
        for (int n = t; n < NPTS; n += 256) acc += p[n];
        red[t] = acc; __syncthreads();
        for (int s = 128; s > 0; s >>= 1) { if (t < s) red[t] += red[t + s]; __syncthreads(); }
        if (t == 0) means[c] = red[0] * (1.f / NPTS);
        __syncthreads();
    }
    float m0 = means[0], m1 = means[1], m2 = means[2];
    const float* px = coords + ((size_t)b * 3 + 0) * NPTS;
    const float* py = coords + ((size_t)b * 3 + 1) * NPTS;
    const float* pz = coords + ((size_t)b * 3 + 2) * NPTS;
    float mx = 0.f;
    for (int n = t; n < NPTS; n += 256) {
        float dx = px[n] - m0, dy = py[n] - m1, dz = pz[n] - m2;
        mx = fmaxf(mx, sqrtf(dx * dx + dy * dy + dz * dz));
    }
    red[t] = mx; __syncthreads();
    for (int s = 128; s > 0; s >>= 1) { if (t < s) red[t] = fmaxf(red[t], red[t + s]); __syncthreads(); }
    if (t == 0) {
        bstats[b * 4 + 0] = m0; bstats[b * 4 + 1] = m1; bstats[b * 4 + 2] = m2;
        bstats[b * 4 + 3] = 1.f / (2.f * red[0]);
    }
}

// ---------------- per-point voxel index + nc4 + count ----------------
__global__ __launch_bounds__(256) void vox_idx_k(const float* __restrict__ coords,
                                                 const float* __restrict__ bstats,
                                                 float4* __restrict__ nc4,
                                                 int* __restrict__ vidx,
                                                 int* __restrict__ slot,
                                                 unsigned int* __restrict__ cnts) {
    int g = blockIdx.x * 256 + threadIdx.x;
    int b = g >> 14, n = g & (NPTS - 1);
    float m0 = bstats[b * 4 + 0], m1 = bstats[b * 4 + 1], m2 = bstats[b * 4 + 2];
    float sc = bstats[b * 4 + 3];
    float x = coords[((size_t)b * 3 + 0) * NPTS + n];
    float y = coords[((size_t)b * 3 + 1) * NPTS + n];
    float z = coords[((size_t)b * 3 + 2) * NPTS + n];
    float ncx = fminf(fmaxf(((x - m0) * sc + 0.5f) * (float)RES, 0.f), RES - 1.f);
    float ncy = fminf(fmaxf(((y - m1) * sc + 0.5f) * (float)RES, 0.f), RES - 1.f);
    float ncz = fminf(fmaxf(((z - m2) * sc + 0.5f) * (float)RES, 0.f), RES - 1.f);
    nc4[g] = make_float4(ncx, ncy, ncz, 0.f);
    int ix = min(max((int)rintf(ncx), 0), RES - 1);  // rintf = half-even = jnp.round
    int iy = min(max((int)rintf(ncy), 0), RES - 1);
    int iz = min(max((int)rintf(ncz), 0), RES - 1);
    int v = b * R3 + (ix * RES + iy) * RES + iz;
    vidx[g] = v;
    slot[g] = (int)atomicAdd(&cnts[v], 1u);
}

// ---------------- feature transpose: [b][64][N] fp32 -> [g][64] fp32 ----------------
__global__ __launch_bounds__(256) void transpose_feats_k(const float* __restrict__ feats,
                                                         float* __restrict__ featT) {
    int blk = blockIdx.x;
    int b = blk >> 8, ntile = blk & 255;
    int t = threadIdx.x;
    __shared__ float lds[64][65];
    for (int e = t; e < 64 * 64; e += 256) {
        int c = e >> 6, n = e & 63;
        lds[c][n] = feats[((size_t)b * CIN + c) * NPTS + ntile * 64 + n];
    }
    __syncthreads();
    for (int e = t; e < 64 * 64; e += 256) {
        int n = e >> 6, c = e & 63;
        featT[(((size_t)b << 14) + ntile * 64 + n) * CIN + c] = lds[c][n];
    }
}

// ---------------- scan ----------------
__global__ __launch_bounds__(256) void scan1_k(const unsigned int* __restrict__ cnts,
                                               unsigned int* __restrict__ offs,
                                               unsigned int* __restrict__ part) {
    int t = threadIdx.x;
    int g = blockIdx.x * 256 + t;
    unsigned int v = cnts[g];
    __shared__ unsigned int s[256];
    s[t] = v; __syncthreads();
    for (int d = 1; d < 256; d <<= 1) {
        unsigned int x = (t >= d) ? s[t - d] : 0u;
        __syncthreads();
        s[t] += x;
        __syncthreads();
    }
    offs[g] = s[t] - v;
    if (t == 255) part[blockIdx.x] = s[255];
}

__global__ __launch_bounds__(1024) void scan2_k(unsigned int* __restrict__ part) {
    int t = threadIdx.x;
    unsigned int v = part[t];
    __shared__ unsigned int s[1024];
    s[t] = v; __syncthreads();
    for (int d = 1; d < 1024; d <<= 1) {
        unsigned int x = (t >= d) ? s[t - d] : 0u;
        __syncthreads();
        s[t] += x;
        __syncthreads();
    }
    part[t] = s[t] - v;
}

__global__ __launch_bounds__(256) void scan3_k(unsigned int* __restrict__ offs,
                                               const unsigned int* __restrict__ part) {
    int g = blockIdx.x * 256 + threadIdx.x;
    offs[g] += part[blockIdx.x];
}

// ---------------- scatter global point id into CSR ----------------
__global__ __launch_bounds__(256) void scatter_pts_k(const int* __restrict__ vidx,
                                                     const int* __restrict__ slot,
                                                     const unsigned int* __restrict__ offs,
                                                     unsigned int* __restrict__ pidx2) {
    int g = blockIdx.x * 256 + threadIdx.x;
    int v = vidx[g];
    pidx2[offs[v] + slot[g]] = (unsigned int)g;
}

// ---------------- gather: CSR mean -> bf16 channel-last vox ----------------
__global__ __launch_bounds__(256) void gather_k(const float* __restrict__ featT,
                                                const unsigned int* __restrict__ cnts,
                                                const unsigned int* __restrict__ offs,
                                                const unsigned int* __restrict__ pidx2,
                                                bf16* __restrict__ voxCL) {
    int u = blockIdx.x * 256 + threadIdx.x;
    int v = u >> 3;
    int l8 = u & 7;
    unsigned int cnt = cnts[v];
    unsigned int off = offs[v];
    float acc[8] = {0.f, 0.f, 0.f, 0.f, 0.f, 0.f, 0.f, 0.f};
    for (unsigned int i = 0; i < cnt; ++i) {
        unsigned int g = pidx2[off + i];
        const float4* fp = (const float4*)(featT + (size_t)g * CIN + l8 * 8);
        float4 f0 = fp[0], f1 = fp[1];
        acc[0] += f0.x; acc[1] += f0.y; acc[2] += f0.z; acc[3] += f0.w;
        acc[4] += f1.x; acc[5] += f1.y; acc[6] += f1.z; acc[7] += f1.w;
    }
    float inv = 1.f / fmaxf((float)cnt, 1.f);
    ushort o[8];
#pragma unroll
    for (int j = 0; j < 8; ++j) o[j] = f2bu(acc[j] * inv);
    *(short8*)(voxCL + (size_t)v * CIN + l8 * 8) = *(short8*)o;
}

// ---------------- weight reorder: [co][ci][27] fp32 -> [t][c32][co][kb][8] bf16 ----------------
template <int CIN_T>
__global__ __launch_bounds__(256) void wreorder_k(const float* __restrict__ w,
                                                  bf16* __restrict__ wf) {
    const int NC = CIN_T / 32;
    int u = blockIdx.x * 256 + threadIdx.x;
    if (u >= 27 * NC * 128 * 4) return;
    int kb = u & 3;
    int co = (u >> 2) & 127;
    int c32 = (u >> 9) % NC;
    int t = u / (512 * NC);
    int cibase = c32 * 32 + kb * 8;
    ushort o[8];
#pragma unroll
    for (int j = 0; j < 8; ++j)
        o[j] = f2bu(w[((size_t)co * CIN_T + cibase + j) * 27 + t]);
    *(short8*)(wf + (size_t)u * 8) = *(short8*)o;
}

// ---------------- wp transpose: [co][ci] -> [ci][co] fp32 ----------------
__global__ __launch_bounds__(256) void wpt_k(const float* __restrict__ wp,
                                             float* __restrict__ wpT) {
    int u = blockIdx.x * 256 + threadIdx.x;  // 8192
    int co = u & 127, ci = u >> 7;
    wpT[ci * 128 + co] = wp[co * 64 + ci];
}

// ---------------- implicit-GEMM conv3d 3x3x3 via MFMA bf16 (R6-proven, EXACT) ----------------
// block 512 = 8 waves (4 cog x 2 sg); 80B pos stride; 49KB LDS -> 3 blocks/CU.
// Measured: conv2 272us, MfmaUtil 38%, occupancy 60%. Do not touch mapping/bounds.
template <int CIN_T>
__global__ __launch_bounds__(512, 2) void conv3d_mfma_k(const bf16* __restrict__ x,  // [b][p][CIN_T]
                                                        const bf16* __restrict__ wf, // [27][NC][128][4][8]
                                                        const float* __restrict__ bias,
                                                        bf16* __restrict__ y,        // [b][p][128]
                                                        float* __restrict__ gnacc) { // [64][2]
    constexpr int NC = CIN_T / 32;
    int blk = blockIdx.x;
    int hq = blk & 7;
    int d = (blk >> 3) & 31;
    int b = blk >> 8;
    int t = threadIdx.x;
    int lane = t & 63;
    int wid = t >> 6;
    int cog = wid >> 1;  // 0..3
    int sg = wid & 1;    // 0..1
    int lr = lane & 15;
    int kb = lane >> 4;

    __shared__ __align__(16) char xs[3 * 6 * 34 * 80];  // 48960 B
    __shared__ float gred[8][2];
    if (t < 16) gred[t >> 1][t & 1] = 0.f;

    f32x4 acc[2][4];
#pragma unroll
    for (int r = 0; r < 2; ++r)
#pragma unroll
        for (int j = 0; j < 4; ++j) acc[r][j] = (f32x4){0.f, 0.f, 0.f, 0.f};

    int bbase[4];
#pragma unroll
    for (int j = 0; j < 4; ++j) {
        int sp = sg * 64 + j * 16 + lr;
        int hl = sp >> 5, wl = sp & 31;
        bbase[j] = (hl * 34 + wl) * 80 + kb * 16;
    }

    for (int cc = 0; cc < NC; ++cc) {
        __syncthreads();
        for (int e = t; e < 612 * 4; e += 512) {
            int ekb = e & 3;
            int pos = e >> 2;
            int ww = pos % 34;
            int hh = (pos / 34) % 6;
            int dd = pos / 204;
            int dz = d + dd - 1;
            int hz = hq * 4 + hh - 1;
            int wz = ww - 1;
            short8 v = {0, 0, 0, 0, 0, 0, 0, 0};
            if (dz >= 0 && dz < RES && hz >= 0 && hz < RES && wz >= 0 && wz < RES)
                v = *(const short8*)(x + ((size_t)b * R3 + dz * 1024 + hz * 32 + wz) * CIN_T + cc * 32 + ekb * 8);
            *(short8*)(xs + pos * 80 + ekb * 16) = v;
        }
        __syncthreads();

        const short8* wfp = (const short8*)wf;
        size_t abase = ((size_t)cc * 128 + cog * 32 + lr) * 4 + kb;
#pragma unroll
        for (int dd = 0; dd < 3; ++dd)
#pragma unroll
            for (int dh = 0; dh < 3; ++dh)
#pragma unroll
                for (int dw = 0; dw < 3; ++dw) {
                    int tap = (dd * 3 + dh) * 3 + dw;
                    short8 a0 = wfp[abase + (size_t)tap * NC * 512];
                    short8 a1 = wfp[abase + (size_t)tap * NC * 512 + 64];
                    int toff = ((dd * 6 + dh) * 34 + dw) * 80;
                    short8 bb[4];
#pragma unroll
                    for (int j = 0; j < 4; ++j)
                        bb[j] = *(const short8*)(xs + bbase[j] + toff);
#pragma unroll
                    for (int j = 0; j < 4; ++j) {
                        acc[0][j] = __builtin_amdgcn_mfma_f32_16x16x32_bf16(a0, bb[j], acc[0][j], 0, 0, 0);
                        acc[1][j] = __builtin_amdgcn_mfma_f32_16x16x32_bf16(a1, bb[j], acc[1][j], 0, 0, 0);
                    }
                }
    }

    // epilogue: store bf16 + GN partial stats (group = cog*2 + r)
    float sred[2], ssred[2];
#pragma unroll
    for (int r = 0; r < 2; ++r) {
        int co = cog * 32 + r * 16 + kb * 4;
        float4 bv = *(const float4*)(bias + co);
        float s = 0.f, ss = 0.f;
#pragma unroll
        for (int j = 0; j < 4; ++j) {
            int sp = sg * 64 + j * 16 + lr;
            int p = d * 1024 + (hq * 4 + (sp >> 5)) * 32 + (sp & 31);
            float v0 = acc[r][j][0] + bv.x;
            float v1 = acc[r][j][1] + bv.y;
            float v2 = acc[r][j][2] + bv.z;
            float v3 = acc[r][j][3] + bv.w;
            ushort4 o;
            o.x = f2bu(v0); o.y = f2bu(v1); o.z = f2bu(v2); o.w = f2bu(v3);
            *(ushort4*)(y + ((size_t)b * R3 + p) * COUT + co) = o;
            s += v0 + v1 + v2 + v3;
            ss += v0 * v0 + v1 * v1 + v2 * v2 + v3 * v3;
        }
        sred[r] = s; ssred[r] = ss;
    }
#pragma unroll
    for (int m = 1; m < 64; m <<= 1) {
#pragma unroll
        for (int r = 0; r < 2; ++r) {
            sred[r] += __shfl_xor(sred[r], m, 64);
            ssred[r] += __shfl_xor(ssred[r], m, 64);
        }
    }
    if (lane == 0) {
#pragma unroll
        for (int r = 0; r < 2; ++r) {
            atomicAdd(&gred[cog * 2 + r][0], sred[r]);
            atomicAdd(&gred[cog * 2 + r][1], ssred[r]);
        }
    }
    __syncthreads();
    if (t < 16) atomicAdd(&gnacc[(b * 8 + (t >> 1)) * 2 + (t & 1)], gred[t >> 1][t & 1]);
}

// ---------------- GN apply + swish (act1 only) ----------------
__global__ __launch_bounds__(256) void gn_apply_cl_k(bf16* __restrict__ x,
                                                     const float* __restrict__ gnacc,
                                                     const float* __restrict__ gamma,
                                                     const float* __restrict__ beta) {
    int u = blockIdx.x * 256 + threadIdx.x;
    int ci8 = u & 15;
    int p = (u >> 4) & (R3 - 1);
    int b = u >> 19;
    int ci = ci8 * 8;
    int bg = b * 8 + (ci8 >> 1);
    const float M = (float)(GSIZE * R3);
    float s = gnacc[bg * 2], ss = gnacc[bg * 2 + 1];
    float mean = s / M;
    float istd = rsqrtf(fmaxf(ss / M - mean * mean, 0.f) + 1e-5f);
    bf16* ptr = x + ((size_t)b * R3 + p) * COUT + ci;
    short8 v = *(const short8*)ptr;
    ushort o[8];
#pragma unroll
    for (int j = 0; j < 8; ++j) {
        float f = b2f((ushort)v[j]);
        float yv = fmaf((f - mean) * istd, gamma[ci + j], beta[ci + j]);
        o[j] = f2bu(yv / (1.f + expf(-yv)));
    }
    *(short8*)ptr = *(short8*)o;
}

// ---------------- point-branch GN stats, fuse2-style ----------------
// thread (point g, l8) computes its 16 channels (= GN group l8) from LDS-staged wpT
// -> lane-local group sums -> xor-shuffle over point lanes -> 16 LDS + 16 global atomics.
// Replaces the old version whose 8192 per-thread VMEM weight loads were the hidden hog.
__global__ __launch_bounds__(256) void pstats_cl_k(const float* __restrict__ featT, // [g][64]
                                                   const float* __restrict__ wpT,   // [64][128]
                                                   const float* __restrict__ bp,
                                                   float* __restrict__ gnacc) {     // [64][2]
    __shared__ float wls[64 * 128];  // 32 KB
    __shared__ float gred[8][2];
    int t = threadIdx.x;
    for (int e = t; e < 64 * 128 / 4; e += 256)
        ((float4*)wls)[e] = ((const float4*)wpT)[e];
    if (t < 16) gred[t >> 1][t & 1] = 0.f;
    __syncthreads();

    int u = blockIdx.x * 256 + t;
    int g = u >> 3;
    int l8 = u & 7;
    int b = g >> 14;
    int c0 = l8 * 16;

    float a[16];
#pragma unroll
    for (int k = 0; k < 16; ++k) a[k] = bp[c0 + k];
    const float* fg = featT + (size_t)g * CIN;
    for (int ci = 0; ci < CIN; ++ci) {
        float fv = fg[ci];
        const float* wrow = wls + ci * 128 + c0;
#pragma unroll
        for (int k = 0; k < 16; ++k) a[k] = fmaf(wrow[k], fv, a[k]);
    }
    float s = 0.f, ss = 0.f;
#pragma unroll
    for (int k = 0; k < 16; ++k) { s += a[k]; ss = fmaf(a[k], a[k], ss); }
    // reduce over the 8 points of this wave (xor bits 3..5 keep l8 = lane&7 aligned)
    s += __shfl_xor(s, 8, 64);  ss += __shfl_xor(ss, 8, 64);
    s += __shfl_xor(s, 16, 64); ss += __shfl_xor(ss, 16, 64);
    s += __shfl_xor(s, 32, 64); ss += __shfl_xor(ss, 32, 64);
    int lane = t & 63;
    if (lane < 8) {
        atomicAdd(&gred[lane][0], s);
        atomicAdd(&gred[lane][1], ss);
    }
    __syncthreads();
    if (t < 16) atomicAdd(&gnacc[(b * 8 + (t >> 1)) * 2 + (t & 1)], gred[t >> 1][t & 1]);
}

// ---------------- fuse2: 8 lanes/point; pf inline + GN + swish + devox + add ----------------
__global__ __launch_bounds__(256) void fuse2_k(const bf16* __restrict__ vox,   // act2 [b][p][128]
                                               const float* __restrict__ featT,// [g][64]
                                               const float* __restrict__ wpT,  // [64][128]
                                               const float* __restrict__ bp,
                                               const float4* __restrict__ nc4,
                                               const unsigned int* __restrict__ pidx2,
                                               const float* __restrict__ gn2acc,
                                               const float* __restrict__ gnpacc,
                                               const float* __restrict__ g2g,
                                               const float* __restrict__ g2b,
                                               const float* __restrict__ gpg,
                                               const float* __restrict__ gpb,
                                               float* __restrict__ pfT) {      // [g][128]
    __shared__ float wls[64 * 128];  // 32 KB
    int t = threadIdx.x;
    for (int e = t; e < 64 * 128 / 4; e += 256)
        ((float4*)wls)[e] = ((const float4*)wpT)[e];
    __syncthreads();

    int u = blockIdx.x * 256 + t;
    int s = u >> 3;
    int l8 = u & 7;
    unsigned int g = pidx2[s];
    int b = (int)(g >> 14);
    int c0 = l8 * 16;

    float a[16];
#pragma unroll
    for (int k = 0; k < 16; ++k) a[k] = bp[c0 + k];
    const float* fg = featT + (size_t)g * CIN;
    for (int ci = 0; ci < CIN; ++ci) {
        float fv = fg[ci];
        const float* wrow = wls + ci * 128 + c0;
#pragma unroll
        for (int k = 0; k < 16; ++k) a[k] = fmaf(wrow[k], fv, a[k]);
    }

    int bg = b * 8 + l8;
    const float M2 = (float)(GSIZE * R3);
    const float Mp = (float)(GSIZE * NPTS);
    float s2 = gn2acc[bg * 2], ss2 = gn2acc[bg * 2 + 1];
    float mean2 = s2 / M2;
    float istd2 = rsqrtf(fmaxf(ss2 / M2 - mean2 * mean2, 0.f) + 1e-5f);
    float sp = gnpacc[bg * 2], ssp = gnpacc[bg * 2 + 1];
    float meanp = sp / Mp;
    float istdp = rsqrtf(fmaxf(ssp / Mp - meanp * meanp, 0.f) + 1e-5f);
    float ga[16], gb[16];
#pragma unroll
    for (int j = 0; j < 16; ++j) {
        float gm = g2g[c0 + j];
        ga[j] = istd2 * gm;
        gb[j] = g2b[c0 + j] - mean2 * istd2 * gm;
    }

    float4 c4 = nc4[g];
    const float CMAX = (float)(RES - 1) - 1e-6f;
    float cx = fminf(c4.x, CMAX), cy = fminf(c4.y, CMAX), cz = fminf(c4.z, CMAX);
    int ix0 = (int)cx, iy0 = (int)cy, iz0 = (int)cz;
    float fx = cx - ix0, fy = cy - iy0, fz = cz - iz0;
    int ix1 = min(ix0 + 1, RES - 1), iy1 = min(iy0 + 1, RES - 1), iz1 = min(iz0 + 1, RES - 1);
    float gx0 = 1.f - fx, gy0 = 1.f - fy, gz0 = 1.f - fz;
    float wc[8] = {gx0 * gy0 * gz0, gx0 * gy0 * fz, gx0 * fy * gz0, gx0 * fy * fz,
                   fx * gy0 * gz0,  fx * gy0 * fz,  fx * fy * gz0,  fx * fy * fz};
    int fi[8];
    fi[0] = (ix0 * RES + iy0) * RES + iz0; fi[1] = (ix0 * RES + iy0) * RES + iz1;
    fi[2] = (ix0 * RES + iy1) * RES + iz0; fi[3] = (ix0 * RES + iy1) * RES + iz1;
    fi[4] = (ix1 * RES + iy0) * RES + iz0; fi[5] = (ix1 * RES + iy0) * RES + iz1;
    fi[6] = (ix1 * RES + iy1) * RES + iz0; fi[7] = (ix1 * RES + iy1) * RES + iz1;

    const bf16* vb = vox + (size_t)b * R3 * COUT + c0;
    float accv[16] = {0.f, 0.f, 0.f, 0.f, 0.f, 0.f, 0.f, 0.f,
                      0.f, 0.f, 0.f, 0.f, 0.f, 0.f, 0.f, 0.f};
#pragma unroll
    for (int f = 0; f < 8; ++f) {
        const short8* vp = (const short8*)(vb + (size_t)fi[f] * COUT);
        short8 v0 = vp[0], v1 = vp[1];
        float wgt = wc[f];
#pragma unroll
        for (int j = 0; j < 8; ++j) {
            float yv = fmaf(b2f((ushort)v0[j]), ga[j], gb[j]);
            accv[j] = fmaf(wgt, yv / (1.f + expf(-yv)), accv[j]);
        }
#pragma unroll
        for (int j = 0; j < 8; ++j) {
            float yv = fmaf(b2f((ushort)v1[j]), ga[8 + j], gb[8 + j]);
            accv[8 + j] = fmaf(wgt, yv / (1.f + expf(-yv)), accv[8 + j]);
        }
    }

    float outv[16];
#pragma unroll
    for (int j = 0; j < 16; ++j) {
        float pm = gpg[c0 + j];
        float yv = fmaf((a[j] - meanp) * istdp, pm, gpb[c0 + j]);
        outv[j] = yv / (1.f + expf(-yv)) + accv[j];
    }
    float* pp = pfT + (size_t)g * COUT + c0;
#pragma unroll
    for (int k = 0; k < 4; ++k)
        *(float4*)(pp + k * 4) = make_float4(outv[k*4], outv[k*4+1], outv[k*4+2], outv[k*4+3]);
}

// ---------------- transpose pfT [b][n][128] -> out [b][128][n] ----------------
__global__ __launch_bounds__(256) void transpose_out_k(const float* __restrict__ pfT,
                                                       float* __restrict__ out) {
    int blk = blockIdx.x;
    int b = blk >> 8, nt = blk & 255;
    int t = threadIdx.x;
    int n0 = nt * 64;
    __shared__ float lds[64][129];
#pragma unroll
    for (int k = 0; k < 8; ++k) {
        int e = t + k * 256;
        int row = e >> 5, c4 = e & 31;
        float4 v = ((const float4*)pfT)[(((size_t)b << 14) + n0 + row) * 32 + c4];
        lds[row][c4 * 4 + 0] = v.x;
        lds[row][c4 * 4 + 1] = v.y;
        lds[row][c4 * 4 + 2] = v.z;
        lds[row][c4 * 4 + 3] = v.w;
    }
    __syncthreads();
#pragma unroll
    for (int k = 0; k < 32; ++k) {
        int e = t + k * 256;
        int c = e >> 6, n = e & 63;
        out[((size_t)b * COUT + c) * NPTS + n0 + n] = lds[n][c];
    }
}

extern "C" void kernel_launch(void* const* d_in, const int* in_sizes, int n_in,
                              void* d_out, int out_size, void* d_ws, size_t ws_size,
                              hipStream_t stream) {
    const float* features = (const float*)d_in[0];
    const float* coords   = (const float*)d_in[1];
    const float* w1  = (const float*)d_in[3];
    const float* b1  = (const float*)d_in[4];
    const float* g1g = (const float*)d_in[5];
    const float* g1b = (const float*)d_in[6];
    const float* w2  = (const float*)d_in[7];
    const float* b2  = (const float*)d_in[8];
    const float* g2g = (const float*)d_in[9];
    const float* g2b = (const float*)d_in[10];
    const float* wp  = (const float*)d_in[11];
    const float* bp  = (const float*)d_in[12];
    const float* gpg = (const float*)d_in[13];
    const float* gpb = (const float*)d_in[14];
    float* out = (float*)d_out;

    char* ws = (char*)d_ws;
    size_t off = 0;
    bf16* act1 = (bf16*)(ws + off);
    float* pfT = (float*)(ws + off);         off += (size_t)BATCH * R3 * COUT * 2;  // 64MB
    bf16* act2 = (bf16*)(ws + off);          off += (size_t)BATCH * R3 * COUT * 2;  // 64MB
    bf16* voxCL = (bf16*)(ws + off);         off += (size_t)BATCH * R3 * CIN * 2;   // 32MB
    float* featT = (float*)(ws + off);       off += (size_t)BATCH * NPTS * CIN * 4; // 32MB
    bf16* w1f = (bf16*)(ws + off);           off += (size_t)27 * 2 * 128 * 32 * 2;
    bf16* w2f = (bf16*)(ws + off);           off += (size_t)27 * 4 * 128 * 32 * 2;
    float* wpT = (float*)(ws + off);         off += 64 * 128 * 4;
    float4* nc4 = (float4*)(ws + off);       off += (size_t)BATCH * NPTS * 16;
    unsigned int* cnts = (unsigned int*)(ws + off);  off += (size_t)BATCH * R3 * 4;
    unsigned int* offs = (unsigned int*)(ws + off);  off += (size_t)BATCH * R3 * 4;
    int* vidx = (int*)(ws + off);            off += (size_t)BATCH * NPTS * 4;
    int* slot = (int*)(ws + off);            off += (size_t)BATCH * NPTS * 4;
    unsigned int* pidx2 = (unsigned int*)(ws + off); off += (size_t)BATCH * NPTS * 4;
    unsigned int* part = (unsigned int*)(ws + off);  off += 4096;
    float* bstats = (float*)(ws + off);      off += 256;
    float* gn1acc = (float*)(ws + off);      off += 512;
    float* gn2acc = (float*)(ws + off);      off += 512;
    float* gnpacc = (float*)(ws + off);      off += 512;

    hipMemsetAsync(cnts, 0, (size_t)BATCH * R3 * 4, stream);
    hipMemsetAsync(gn1acc, 0, 3 * 512, stream);

    coord_stats_k<<<BATCH, 256, 0, stream>>>(coords, bstats);
    vox_idx_k<<<BATCH * NPTS / 256, 256, 0, stream>>>(coords, bstats, nc4, vidx, slot, cnts);
    transpose_feats_k<<<BATCH * 256, 256, 0, stream>>>(features, featT);
    scan1_k<<<BATCH * R3 / 256, 256, 0, stream>>>(cnts, offs, part);
    scan2_k<<<1, 1024, 0, stream>>>(part);
    scan3_k<<<BATCH * R3 / 256, 256, 0, stream>>>(offs, part);
    scatter_pts_k<<<BATCH * NPTS / 256, 256, 0, stream>>>(vidx, slot, offs, pidx2);
    gather_k<<<BATCH * R3 * 8 / 256, 256, 0, stream>>>(featT, cnts, offs, pidx2, voxCL);

    wreorder_k<CIN><<<(27 * 2 * 128 * 4 + 255) / 256, 256, 0, stream>>>(w1, w1f);
    wreorder_k<COUT><<<(27 * 4 * 128 * 4 + 255) / 256, 256, 0, stream>>>(w2, w2f);
    wpt_k<<<32, 256, 0, stream>>>(wp, wpT);

    conv3d_mfma_k<CIN><<<BATCH * 32 * 8, 512, 0, stream>>>(voxCL, w1f, b1, act1, gn1acc);
    gn_apply_cl_k<<<BATCH * R3 * 16 / 256, 256, 0, stream>>>(act1, gn1acc, g1g, g1b);

    conv3d_mfma_k<COUT><<<BATCH * 32 * 8, 512, 0, stream>>>(act1, w2f, b2, act2, gn2acc);

    pstats_cl_k<<<BATCH * NPTS * 8 / 256, 256, 0, stream>>>(featT, wpT, bp, gnpacc);

    fuse2_k<<<BATCH * NPTS * 8 / 256, 256, 0, stream>>>(act2, featT, wpT, bp, nc4, pidx2,
                                                        gn2acc, gnpacc, g2g, g2b, gpg, gpb, pfT);

    transpose_out_k<<<BATCH * 256, 256, 0, stream>>>(pfT, out);
}

// Round 11
// 706.333 us; speedup vs baseline: 2.1502x; 1.1416x over previous
//
#include <hip/hip_runtime.h>
#include <hip/hip_bf16.h>
#include <cmath>

#define BATCH 8
#define CIN 64
#define COUT 128
#define NPTS 16384
#define RES 32
#define R3 32768
#define NGROUP 8
#define GSIZE 16

typedef __hip_bfloat16 bf16;
typedef __attribute__((ext_vector_type(8))) short short8;
typedef __attribute__((ext_vector_type(4))) float f32x4;

__device__ inline float b2f(ushort u) { union { float f; uint v; } x; x.v = ((uint)u) << 16; return x.f; }
__device__ inline ushort f2bu(float f) { __hip_bfloat16 h = __float2bfloat16(f); return *reinterpret_cast<ushort*>(&h); }

// ---------------- coord stats ----------------
__global__ __launch_bounds__(256) void coord_stats_k(const float* __restrict__ coords,
                                                     float* __restrict__ bstats) {
    int b = blockIdx.x;
    int t = threadIdx.x;
    __shared__ float red[256];
    __shared__ float means[3];
    for (int c = 0; c < 3; ++c) {
        float acc = 0.f;
        const float* p = coords + ((size_t)b * 3 + c) * NPTS;
        for (int n = t; n < NPTS; n += 256) acc += p[n];
        red[t] = acc; __syncthreads();
        for (int s = 128; s > 0; s >>= 1) { if (t < s) red[t] += red[t + s]; __syncthreads(); }
        if (t == 0) means[c] = red[0] * (1.f / NPTS);
        __syncthreads();
    }
    float m0 = means[0], m1 = means[1], m2 = means[2];
    const float* px = coords + ((size_t)b * 3 + 0) * NPTS;
    const float* py = coords + ((size_t)b * 3 + 1) * NPTS;
    const float* pz = coords + ((size_t)b * 3 + 2) * NPTS;
    float mx = 0.f;
    for (int n = t; n < NPTS; n += 256) {
        float dx = px[n] - m0, dy = py[n] - m1, dz = pz[n] - m2;
        mx = fmaxf(mx, sqrtf(dx * dx + dy * dy + dz * dz));
    }
    red[t] = mx; __syncthreads();
    for (int s = 128; s > 0; s >>= 1) { if (t < s) red[t] = fmaxf(red[t], red[t + s]); __syncthreads(); }
    if (t == 0) {
        bstats[b * 4 + 0] = m0; bstats[b * 4 + 1] = m1; bstats[b * 4 + 2] = m2;
        bstats[b * 4 + 3] = 1.f / (2.f * red[0]);
    }
}

// ---------------- per-point voxel index + nc4 + count ----------------
__global__ __launch_bounds__(256) void vox_idx_k(const float* __restrict__ coords,
                                                 const float* __restrict__ bstats,
                                                 float4* __restrict__ nc4,
                                                 int* __restrict__ vidx,
                                                 int* __restrict__ slot,
                                                 unsigned int* __restrict__ cnts) {
    int g = blockIdx.x * 256 + threadIdx.x;
    int b = g >> 14, n = g & (NPTS - 1);
    float m0 = bstats[b * 4 + 0], m1 = bstats[b * 4 + 1], m2 = bstats[b * 4 + 2];
    float sc = bstats[b * 4 + 3];
    float x = coords[((size_t)b * 3 + 0) * NPTS + n];
    float y = coords[((size_t)b * 3 + 1) * NPTS + n];
    float z = coords[((size_t)b * 3 + 2) * NPTS + n];
    float ncx = fminf(fmaxf(((x - m0) * sc + 0.5f) * (float)RES, 0.f), RES - 1.f);
    float ncy = fminf(fmaxf(((y - m1) * sc + 0.5f) * (float)RES, 0.f), RES - 1.f);
    float ncz = fminf(fmaxf(((z - m2) * sc + 0.5f) * (float)RES, 0.f), RES - 1.f);
    nc4[g] = make_float4(ncx, ncy, ncz, 0.f);
    int ix = min(max((int)rintf(ncx), 0), RES - 1);  // rintf = half-even = jnp.round
    int iy = min(max((int)rintf(ncy), 0), RES - 1);
    int iz = min(max((int)rintf(ncz), 0), RES - 1);
    int v = b * R3 + (ix * RES + iy) * RES + iz;
    vidx[g] = v;
    slot[g] = (int)atomicAdd(&cnts[v], 1u);
}

// ---------------- feature transpose: [b][64][N] fp32 -> [g][64] fp32 ----------------
__global__ __launch_bounds__(256) void transpose_feats_k(const float* __restrict__ feats,
                                                         float* __restrict__ featT) {
    int blk = blockIdx.x;
    int b = blk >> 8, ntile = blk & 255;
    int t = threadIdx.x;
    __shared__ float lds[64][65];
    for (int e = t; e < 64 * 64; e += 256) {
        int c = e >> 6, n = e & 63;
        lds[c][n] = feats[((size_t)b * CIN + c) * NPTS + ntile * 64 + n];
    }
    __syncthreads();
    for (int e = t; e < 64 * 64; e += 256) {
        int n = e >> 6, c = e & 63;
        featT[(((size_t)b << 14) + ntile * 64 + n) * CIN + c] = lds[c][n];
    }
}

// ---------------- scan ----------------
__global__ __launch_bounds__(256) void scan1_k(const unsigned int* __restrict__ cnts,
                                               unsigned int* __restrict__ offs,
                                               unsigned int* __restrict__ part) {
    int t = threadIdx.x;
    int g = blockIdx.x * 256 + t;
    unsigned int v = cnts[g];
    __shared__ unsigned int s[256];
    s[t] = v; __syncthreads();
    for (int d = 1; d < 256; d <<= 1) {
        unsigned int x = (t >= d) ? s[t - d] : 0u;
        __syncthreads();
        s[t] += x;
        __syncthreads();
    }
    offs[g] = s[t] - v;
    if (t == 255) part[blockIdx.x] = s[255];
}

__global__ __launch_bounds__(1024) void scan2_k(unsigned int* __restrict__ part) {
    int t = threadIdx.x;
    unsigned int v = part[t];
    __shared__ unsigned int s[1024];
    s[t] = v; __syncthreads();
    for (int d = 1; d < 1024; d <<= 1) {
        unsigned int x = (t >= d) ? s[t - d] : 0u;
        __syncthreads();
        s[t] += x;
        __syncthreads();
    }
    part[t] = s[t] - v;
}

__global__ __launch_bounds__(256) void scan3_k(unsigned int* __restrict__ offs,
                                               const unsigned int* __restrict__ part) {
    int g = blockIdx.x * 256 + threadIdx.x;
    offs[g] += part[blockIdx.x];
}

// ---------------- scatter global point id into CSR ----------------
__global__ __launch_bounds__(256) void scatter_pts_k(const int* __restrict__ vidx,
                                                     const int* __restrict__ slot,
                                                     const unsigned int* __restrict__ offs,
                                                     unsigned int* __restrict__ pidx2) {
    int g = blockIdx.x * 256 + threadIdx.x;
    int v = vidx[g];
    pidx2[offs[v] + slot[g]] = (unsigned int)g;
}

// ---------------- gather: CSR mean -> bf16 channel-last vox ----------------
__global__ __launch_bounds__(256) void gather_k(const float* __restrict__ featT,
                                                const unsigned int* __restrict__ cnts,
                                                const unsigned int* __restrict__ offs,
                                                const unsigned int* __restrict__ pidx2,
                                                bf16* __restrict__ voxCL) {
    int u = blockIdx.x * 256 + threadIdx.x;
    int v = u >> 3;
    int l8 = u & 7;
    unsigned int cnt = cnts[v];
    unsigned int off = offs[v];
    float acc[8] = {0.f, 0.f, 0.f, 0.f, 0.f, 0.f, 0.f, 0.f};
    for (unsigned int i = 0; i < cnt; ++i) {
        unsigned int g = pidx2[off + i];
        const float4* fp = (const float4*)(featT + (size_t)g * CIN + l8 * 8);
        float4 f0 = fp[0], f1 = fp[1];
        acc[0] += f0.x; acc[1] += f0.y; acc[2] += f0.z; acc[3] += f0.w;
        acc[4] += f1.x; acc[5] += f1.y; acc[6] += f1.z; acc[7] += f1.w;
    }
    float inv = 1.f / fmaxf((float)cnt, 1.f);
    ushort o[8];
#pragma unroll
    for (int j = 0; j < 8; ++j) o[j] = f2bu(acc[j] * inv);
    *(short8*)(voxCL + (size_t)v * CIN + l8 * 8) = *(short8*)o;
}

// ---------------- weight reorder: [co][ci][27] fp32 -> [t][c32][co][kb][8] bf16 ----------------
template <int CIN_T>
__global__ __launch_bounds__(256) void wreorder_k(const float* __restrict__ w,
                                                  bf16* __restrict__ wf) {
    const int NC = CIN_T / 32;
    int u = blockIdx.x * 256 + threadIdx.x;
    if (u >= 27 * NC * 128 * 4) return;
    int kb = u & 3;
    int co = (u >> 2) & 127;
    int c32 = (u >> 9) % NC;
    int t = u / (512 * NC);
    int cibase = c32 * 32 + kb * 8;
    ushort o[8];
#pragma unroll
    for (int j = 0; j < 8; ++j)
        o[j] = f2bu(w[((size_t)co * CIN_T + cibase + j) * 27 + t]);
    *(short8*)(wf + (size_t)u * 8) = *(short8*)o;
}

// ---------------- wp transpose: [co][ci] -> [ci][co] fp32 ----------------
__global__ __launch_bounds__(256) void wpt_k(const float* __restrict__ wp,
                                             float* __restrict__ wpT) {
    int u = blockIdx.x * 256 + threadIdx.x;  // 8192
    int co = u & 127, ci = u >> 7;
    wpT[ci * 128 + co] = wp[co * 64 + ci];
}

// ---------------- implicit-GEMM conv3d 3x3x3 via MFMA bf16 (R6-proven, EXACT) ----------------
// block 512 = 8 waves (4 cog x 2 sg); 80B pos stride; 49KB LDS -> 3 blocks/CU.
// Measured: conv2 272us, MfmaUtil 38%, occupancy 60%. Mapping/bounds untouched.
// GNIN: apply GN1+swish (affine folded via 1KB LDS table) to in-bounds staged
// elements -> eliminates the separate 128MB gn_apply pass.
template <int CIN_T, bool GNIN>
__global__ __launch_bounds__(512, 2) void conv3d_mfma_k(const bf16* __restrict__ x,  // [b][p][CIN_T]
                                                        const bf16* __restrict__ wf, // [27][NC][128][4][8]
                                                        const float* __restrict__ bias,
                                                        bf16* __restrict__ y,        // [b][p][128]
                                                        float* __restrict__ gnacc,   // out stats [64][2]
                                                        const float* __restrict__ gnaccIn,
                                                        const float* __restrict__ gammaIn,
                                                        const float* __restrict__ betaIn) {
    constexpr int NC = CIN_T / 32;
    int blk = blockIdx.x;
    int hq = blk & 7;
    int d = (blk >> 3) & 31;
    int b = blk >> 8;
    int t = threadIdx.x;
    int lane = t & 63;
    int wid = t >> 6;
    int cog = wid >> 1;  // 0..3
    int sg = wid & 1;    // 0..1
    int lr = lane & 15;
    int kb = lane >> 4;

    __shared__ __align__(16) char xs[3 * 6 * 34 * 80];  // 48960 B
    __shared__ float gred[8][2];
    __shared__ float gna[128], gnb[128];
    if (t < 16) gred[t >> 1][t & 1] = 0.f;
    if (GNIN) {
        if (t < 128) {
            int bgi = b * 8 + (t >> 4);
            const float M = (float)(GSIZE * R3);
            float s_ = gnaccIn[bgi * 2], ss_ = gnaccIn[bgi * 2 + 1];
            float mean_ = s_ / M;
            float istd_ = rsqrtf(fmaxf(ss_ / M - mean_ * mean_, 0.f) + 1e-5f);
            float gm = gammaIn[t];
            gna[t] = istd_ * gm;
            gnb[t] = betaIn[t] - mean_ * istd_ * gm;
        }
    }

    f32x4 acc[2][4];
#pragma unroll
    for (int r = 0; r < 2; ++r)
#pragma unroll
        for (int j = 0; j < 4; ++j) acc[r][j] = (f32x4){0.f, 0.f, 0.f, 0.f};

    int bbase[4];
#pragma unroll
    for (int j = 0; j < 4; ++j) {
        int sp = sg * 64 + j * 16 + lr;
        int hl = sp >> 5, wl = sp & 31;
        bbase[j] = (hl * 34 + wl) * 80 + kb * 16;
    }

    for (int cc = 0; cc < NC; ++cc) {
        __syncthreads();
        for (int e = t; e < 612 * 4; e += 512) {
            int ekb = e & 3;
            int pos = e >> 2;
            int ww = pos % 34;
            int hh = (pos / 34) % 6;
            int dd = pos / 204;
            int dz = d + dd - 1;
            int hz = hq * 4 + hh - 1;
            int wz = ww - 1;
            short8 v = {0, 0, 0, 0, 0, 0, 0, 0};
            if (dz >= 0 && dz < RES && hz >= 0 && hz < RES && wz >= 0 && wz < RES) {
                v = *(const short8*)(x + ((size_t)b * R3 + dz * 1024 + hz * 32 + wz) * CIN_T + cc * 32 + ekb * 8);
                if (GNIN) {
                    int ch = cc * 32 + ekb * 8;
                    ushort o_[8];
#pragma unroll
                    for (int j = 0; j < 8; ++j) {
                        float f = b2f((ushort)v[j]);
                        float yv = fmaf(f, gna[ch + j], gnb[ch + j]);
                        o_[j] = f2bu(yv / (1.f + __expf(-yv)));
                    }
                    v = *(short8*)o_;
                }
            }
            *(short8*)(xs + pos * 80 + ekb * 16) = v;
        }
        __syncthreads();

        const short8* wfp = (const short8*)wf;
        size_t abase = ((size_t)cc * 128 + cog * 32 + lr) * 4 + kb;
#pragma unroll
        for (int dd = 0; dd < 3; ++dd)
#pragma unroll
            for (int dh = 0; dh < 3; ++dh)
#pragma unroll
                for (int dw = 0; dw < 3; ++dw) {
                    int tap = (dd * 3 + dh) * 3 + dw;
                    short8 a0 = wfp[abase + (size_t)tap * NC * 512];
                    short8 a1 = wfp[abase + (size_t)tap * NC * 512 + 64];
                    int toff = ((dd * 6 + dh) * 34 + dw) * 80;
                    short8 bb[4];
#pragma unroll
                    for (int j = 0; j < 4; ++j)
                        bb[j] = *(const short8*)(xs + bbase[j] + toff);
#pragma unroll
                    for (int j = 0; j < 4; ++j) {
                        acc[0][j] = __builtin_amdgcn_mfma_f32_16x16x32_bf16(a0, bb[j], acc[0][j], 0, 0, 0);
                        acc[1][j] = __builtin_amdgcn_mfma_f32_16x16x32_bf16(a1, bb[j], acc[1][j], 0, 0, 0);
                    }
                }
    }

    // epilogue: store bf16 + GN partial stats (group = cog*2 + r)
    float sred[2], ssred[2];
#pragma unroll
    for (int r = 0; r < 2; ++r) {
        int co = cog * 32 + r * 16 + kb * 4;
        float4 bv = *(const float4*)(bias + co);
        float s = 0.f, ss = 0.f;
#pragma unroll
        for (int j = 0; j < 4; ++j) {
            int sp = sg * 64 + j * 16 + lr;
            int p = d * 1024 + (hq * 4 + (sp >> 5)) * 32 + (sp & 31);
            float v0 = acc[r][j][0] + bv.x;
            float v1 = acc[r][j][1] + bv.y;
            float v2 = acc[r][j][2] + bv.z;
            float v3 = acc[r][j][3] + bv.w;
            ushort4 o;
            o.x = f2bu(v0); o.y = f2bu(v1); o.z = f2bu(v2); o.w = f2bu(v3);
            *(ushort4*)(y + ((size_t)b * R3 + p) * COUT + co) = o;
            s += v0 + v1 + v2 + v3;
            ss += v0 * v0 + v1 * v1 + v2 * v2 + v3 * v3;
        }
        sred[r] = s; ssred[r] = ss;
    }
#pragma unroll
    for (int m = 1; m < 64; m <<= 1) {
#pragma unroll
        for (int r = 0; r < 2; ++r) {
            sred[r] += __shfl_xor(sred[r], m, 64);
            ssred[r] += __shfl_xor(ssred[r], m, 64);
        }
    }
    if (lane == 0) {
#pragma unroll
        for (int r = 0; r < 2; ++r) {
            atomicAdd(&gred[cog * 2 + r][0], sred[r]);
            atomicAdd(&gred[cog * 2 + r][1], ssred[r]);
        }
    }
    __syncthreads();
    if (t < 16) atomicAdd(&gnacc[(b * 8 + (t >> 1)) * 2 + (t & 1)], gred[t >> 1][t & 1]);
}

// ---------------- point-branch: GEMM -> pf bf16 store + GN stats ----------------
// thread (point g, l8) computes its 16 channels (= GN group l8) from LDS-staged wpT.
// pf stored channel-last bf16 (256B/point, coalesced) for fuse2 to reuse.
__global__ __launch_bounds__(256) void pstats_cl_k(const float* __restrict__ featT, // [g][64]
                                                   const float* __restrict__ wpT,   // [64][128]
                                                   const float* __restrict__ bp,
                                                   bf16* __restrict__ pfb,          // [g][128]
                                                   float* __restrict__ gnacc) {     // [64][2]
    __shared__ float wls[64 * 128];  // 32 KB
    __shared__ float gred[8][2];
    int t = threadIdx.x;
    for (int e = t; e < 64 * 128 / 4; e += 256)
        ((float4*)wls)[e] = ((const float4*)wpT)[e];
    if (t < 16) gred[t >> 1][t & 1] = 0.f;
    __syncthreads();

    int u = blockIdx.x * 256 + t;
    int g = u >> 3;
    int l8 = u & 7;
    int b = g >> 14;
    int c0 = l8 * 16;

    float a[16];
#pragma unroll
    for (int k = 0; k < 16; ++k) a[k] = bp[c0 + k];
    const float* fg = featT + (size_t)g * CIN;
    for (int ci = 0; ci < CIN; ++ci) {
        float fv = fg[ci];
        const float* wrow = wls + ci * 128 + c0;
#pragma unroll
        for (int k = 0; k < 16; ++k) a[k] = fmaf(wrow[k], fv, a[k]);
    }
    // store pf bf16 (stats below use fp32 'a' — quantization only affects fuse2's input)
    ushort o_[16];
#pragma unroll
    for (int k = 0; k < 16; ++k) o_[k] = f2bu(a[k]);
    *(short8*)(pfb + (size_t)g * COUT + c0) = *(short8*)(o_);
    *(short8*)(pfb + (size_t)g * COUT + c0 + 8) = *(short8*)(o_ + 8);

    float s = 0.f, ss = 0.f;
#pragma unroll
    for (int k = 0; k < 16; ++k) { s += a[k]; ss = fmaf(a[k], a[k], ss); }
    s += __shfl_xor(s, 8, 64);  ss += __shfl_xor(ss, 8, 64);
    s += __shfl_xor(s, 16, 64); ss += __shfl_xor(ss, 16, 64);
    s += __shfl_xor(s, 32, 64); ss += __shfl_xor(ss, 32, 64);
    int lane = t & 63;
    if (lane < 8) {
        atomicAdd(&gred[lane][0], s);
        atomicAdd(&gred[lane][1], ss);
    }
    __syncthreads();
    if (t < 16) atomicAdd(&gnacc[(b * 8 + (t >> 1)) * 2 + (t & 1)], gred[t >> 1][t & 1]);
}

// ---------------- fuse2: 8 lanes/point; load pf + GN + swish + devox + add ----------------
__global__ __launch_bounds__(256) void fuse2_k(const bf16* __restrict__ vox,   // act2 [b][p][128]
                                               const bf16* __restrict__ pfb,   // [g][128]
                                               const float4* __restrict__ nc4,
                                               const unsigned int* __restrict__ pidx2,
                                               const float* __restrict__ gn2acc,
                                               const float* __restrict__ gnpacc,
                                               const float* __restrict__ g2g,
                                               const float* __restrict__ g2b,
                                               const float* __restrict__ gpg,
                                               const float* __restrict__ gpb,
                                               float* __restrict__ pfT) {      // [g][128]
    int t = threadIdx.x;
    int u = blockIdx.x * 256 + t;
    int s = u >> 3;
    int l8 = u & 7;
    unsigned int g = pidx2[s];
    int b = (int)(g >> 14);
    int c0 = l8 * 16;

    // pf load (bf16, coalesced 32B/lane)
    const short8* pfp = (const short8*)(pfb + (size_t)g * COUT + c0);
    short8 p0 = pfp[0], p1 = pfp[1];
    float a[16];
#pragma unroll
    for (int j = 0; j < 8; ++j) { a[j] = b2f((ushort)p0[j]); a[8 + j] = b2f((ushort)p1[j]); }

    int bg = b * 8 + l8;
    const float M2 = (float)(GSIZE * R3);
    const float Mp = (float)(GSIZE * NPTS);
    float s2 = gn2acc[bg * 2], ss2 = gn2acc[bg * 2 + 1];
    float mean2 = s2 / M2;
    float istd2 = rsqrtf(fmaxf(ss2 / M2 - mean2 * mean2, 0.f) + 1e-5f);
    float sp = gnpacc[bg * 2], ssp = gnpacc[bg * 2 + 1];
    float meanp = sp / Mp;
    float istdp = rsqrtf(fmaxf(ssp / Mp - meanp * meanp, 0.f) + 1e-5f);
    float ga[16], gb[16];
#pragma unroll
    for (int j = 0; j < 16; ++j) {
        float gm = g2g[c0 + j];
        ga[j] = istd2 * gm;
        gb[j] = g2b[c0 + j] - mean2 * istd2 * gm;
    }

    float4 c4 = nc4[g];
    const float CMAX = (float)(RES - 1) - 1e-6f;
    float cx = fminf(c4.x, CMAX), cy = fminf(c4.y, CMAX), cz = fminf(c4.z, CMAX);
    int ix0 = (int)cx, iy0 = (int)cy, iz0 = (int)cz;
    float fx = cx - ix0, fy = cy - iy0, fz = cz - iz0;
    int ix1 = min(ix0 + 1, RES - 1), iy1 = min(iy0 + 1, RES - 1), iz1 = min(iz0 + 1, RES - 1);
    float gx0 = 1.f - fx, gy0 = 1.f - fy, gz0 = 1.f - fz;
    float wc[8] = {gx0 * gy0 * gz0, gx0 * gy0 * fz, gx0 * fy * gz0, gx0 * fy * fz,
                   fx * gy0 * gz0,  fx * gy0 * fz,  fx * fy * gz0,  fx * fy * fz};
    int fi[8];
    fi[0] = (ix0 * RES + iy0) * RES + iz0; fi[1] = (ix0 * RES + iy0) * RES + iz1;
    fi[2] = (ix0 * RES + iy1) * RES + iz0; fi[3] = (ix0 * RES + iy1) * RES + iz1;
    fi[4] = (ix1 * RES + iy0) * RES + iz0; fi[5] = (ix1 * RES + iy0) * RES + iz1;
    fi[6] = (ix1 * RES + iy1) * RES + iz0; fi[7] = (ix1 * RES + iy1) * RES + iz1;

    const bf16* vb = vox + (size_t)b * R3 * COUT + c0;
    float accv[16] = {0.f, 0.f, 0.f, 0.f, 0.f, 0.f, 0.f, 0.f,
                      0.f, 0.f, 0.f, 0.f, 0.f, 0.f, 0.f, 0.f};
#pragma unroll
    for (int f = 0; f < 8; ++f) {
        const short8* vp = (const short8*)(vb + (size_t)fi[f] * COUT);
        short8 v0 = vp[0], v1 = vp[1];
        float wgt = wc[f];
#pragma unroll
        for (int j = 0; j < 8; ++j) {
            float yv = fmaf(b2f((ushort)v0[j]), ga[j], gb[j]);
            accv[j] = fmaf(wgt, yv / (1.f + __expf(-yv)), accv[j]);
        }
#pragma unroll
        for (int j = 0; j < 8; ++j) {
            float yv = fmaf(b2f((ushort)v1[j]), ga[8 + j], gb[8 + j]);
            accv[8 + j] = fmaf(wgt, yv / (1.f + __expf(-yv)), accv[8 + j]);
        }
    }

    float outv[16];
#pragma unroll
    for (int j = 0; j < 16; ++j) {
        float pm = gpg[c0 + j];
        float yv = fmaf((a[j] - meanp) * istdp, pm, gpb[c0 + j]);
        outv[j] = yv / (1.f + __expf(-yv)) + accv[j];
    }
    float* pp = pfT + (size_t)g * COUT + c0;
#pragma unroll
    for (int k = 0; k < 4; ++k)
        *(float4*)(pp + k * 4) = make_float4(outv[k*4], outv[k*4+1], outv[k*4+2], outv[k*4+3]);
}

// ---------------- transpose pfT [b][n][128] -> out [b][128][n] ----------------
__global__ __launch_bounds__(256) void transpose_out_k(const float* __restrict__ pfT,
                                                       float* __restrict__ out) {
    int blk = blockIdx.x;
    int b = blk >> 8, nt = blk & 255;
    int t = threadIdx.x;
    int n0 = nt * 64;
    __shared__ float lds[64][129];
#pragma unroll
    for (int k = 0; k < 8; ++k) {
        int e = t + k * 256;
        int row = e >> 5, c4 = e & 31;
        float4 v = ((const float4*)pfT)[(((size_t)b << 14) + n0 + row) * 32 + c4];
        lds[row][c4 * 4 + 0] = v.x;
        lds[row][c4 * 4 + 1] = v.y;
        lds[row][c4 * 4 + 2] = v.z;
        lds[row][c4 * 4 + 3] = v.w;
    }
    __syncthreads();
#pragma unroll
    for (int k = 0; k < 32; ++k) {
        int e = t + k * 256;
        int c = e >> 6, n = e & 63;
        out[((size_t)b * COUT + c) * NPTS + n0 + n] = lds[n][c];
    }
}

extern "C" void kernel_launch(void* const* d_in, const int* in_sizes, int n_in,
                              void* d_out, int out_size, void* d_ws, size_t ws_size,
                              hipStream_t stream) {
    const float* features = (const float*)d_in[0];
    const float* coords   = (const float*)d_in[1];
    const float* w1  = (const float*)d_in[3];
    const float* b1  = (const float*)d_in[4];
    const float* g1g = (const float*)d_in[5];
    const float* g1b = (const float*)d_in[6];
    const float* w2  = (const float*)d_in[7];
    const float* b2  = (const float*)d_in[8];
    const float* g2g = (const float*)d_in[9];
    const float* g2b = (const float*)d_in[10];
    const float* wp  = (const float*)d_in[11];
    const float* bp  = (const float*)d_in[12];
    const float* gpg = (const float*)d_in[13];
    const float* gpb = (const float*)d_in[14];
    float* out = (float*)d_out;

    // ws (~199 MB):
    //   [0,64MB)     act1 bf16 -> pfT fp32 (overlay; act1 dead after conv2)
    //   [64,128MB)   act2 bf16 (live until fuse2)
    //   [128,160MB)  voxCL bf16 -> pfb bf16 (overlay; voxCL dead after conv1)
    //   [160,192MB)  featT fp32
    //   tail: w1f, w2f, wpT, nc4, cnts, offs, vidx, slot, pidx2, part, stats
    char* ws = (char*)d_ws;
    size_t off = 0;
    bf16* act1 = (bf16*)(ws + off);
    float* pfT = (float*)(ws + off);         off += (size_t)BATCH * R3 * COUT * 2;  // 64MB
    bf16* act2 = (bf16*)(ws + off);          off += (size_t)BATCH * R3 * COUT * 2;  // 64MB
    bf16* voxCL = (bf16*)(ws + off);
    bf16* pfb = (bf16*)(ws + off);           off += (size_t)BATCH * R3 * CIN * 2;   // 32MB
    float* featT = (float*)(ws + off);       off += (size_t)BATCH * NPTS * CIN * 4; // 32MB
    bf16* w1f = (bf16*)(ws + off);           off += (size_t)27 * 2 * 128 * 32 * 2;
    bf16* w2f = (bf16*)(ws + off);           off += (size_t)27 * 4 * 128 * 32 * 2;
    float* wpT = (float*)(ws + off);         off += 64 * 128 * 4;
    float4* nc4 = (float4*)(ws + off);       off += (size_t)BATCH * NPTS * 16;
    unsigned int* cnts = (unsigned int*)(ws + off);  off += (size_t)BATCH * R3 * 4;
    unsigned int* offs = (unsigned int*)(ws + off);  off += (size_t)BATCH * R3 * 4;
    int* vidx = (int*)(ws + off);            off += (size_t)BATCH * NPTS * 4;
    int* slot = (int*)(ws + off);            off += (size_t)BATCH * NPTS * 4;
    unsigned int* pidx2 = (unsigned int*)(ws + off); off += (size_t)BATCH * NPTS * 4;
    unsigned int* part = (unsigned int*)(ws + off);  off += 4096;
    float* bstats = (float*)(ws + off);      off += 256;
    float* gn1acc = (float*)(ws + off);      off += 512;
    float* gn2acc = (float*)(ws + off);      off += 512;
    float* gnpacc = (float*)(ws + off);      off += 512;

    hipMemsetAsync(cnts, 0, (size_t)BATCH * R3 * 4, stream);
    hipMemsetAsync(gn1acc, 0, 3 * 512, stream);

    coord_stats_k<<<BATCH, 256, 0, stream>>>(coords, bstats);
    vox_idx_k<<<BATCH * NPTS / 256, 256, 0, stream>>>(coords, bstats, nc4, vidx, slot, cnts);
    transpose_feats_k<<<BATCH * 256, 256, 0, stream>>>(features, featT);
    scan1_k<<<BATCH * R3 / 256, 256, 0, stream>>>(cnts, offs, part);
    scan2_k<<<1, 1024, 0, stream>>>(part);
    scan3_k<<<BATCH * R3 / 256, 256, 0, stream>>>(offs, part);
    scatter_pts_k<<<BATCH * NPTS / 256, 256, 0, stream>>>(vidx, slot, offs, pidx2);
    gather_k<<<BATCH * R3 * 8 / 256, 256, 0, stream>>>(featT, cnts, offs, pidx2, voxCL);

    wreorder_k<CIN><<<(27 * 2 * 128 * 4 + 255) / 256, 256, 0, stream>>>(w1, w1f);
    wreorder_k<COUT><<<(27 * 4 * 128 * 4 + 255) / 256, 256, 0, stream>>>(w2, w2f);
    wpt_k<<<32, 256, 0, stream>>>(wp, wpT);

    conv3d_mfma_k<CIN, false><<<BATCH * 32 * 8, 512, 0, stream>>>(
        voxCL, w1f, b1, act1, gn1acc, nullptr, nullptr, nullptr);

    conv3d_mfma_k<COUT, true><<<BATCH * 32 * 8, 512, 0, stream>>>(
        act1, w2f, b2, act2, gn2acc, gn1acc, g1g, g1b);

    // pfb overlays voxCL (dead after conv1); launched after conv2 for safety
    pstats_cl_k<<<BATCH * NPTS * 8 / 256, 256, 0, stream>>>(featT, wpT, bp, pfb, gnpacc);

    fuse2_k<<<BATCH * NPTS * 8 / 256, 256, 0, stream>>>(act2, pfb, nc4, pidx2,
                                                        gn2acc, gnpacc, g2g, g2b, gpg, gpb, pfT);

    transpose_out_k<<<BATCH * 256, 256, 0, stream>>>(pfT, out);
}

// Round 12
// 693.654 us; speedup vs baseline: 2.1895x; 1.0183x over previous
//
#include <hip/hip_runtime.h>
#include <hip/hip_bf16.h>
#include <cmath>

#define BATCH 8
#define CIN 64
#define COUT 128
#define NPTS 16384
#define RES 32
#define R3 32768
#define NGROUP 8
#define GSIZE 16

typedef __hip_bfloat16 bf16;
typedef __attribute__((ext_vector_type(8))) short short8;
typedef __attribute__((ext_vector_type(4))) float f32x4;

__device__ inline float b2f(ushort u) { union { float f; uint v; } x; x.v = ((uint)u) << 16; return x.f; }
__device__ inline ushort f2bu(float f) { __hip_bfloat16 h = __float2bfloat16(f); return *reinterpret_cast<ushort*>(&h); }

// ---------------- coord stats ----------------
__global__ __launch_bounds__(256) void coord_stats_k(const float* __restrict__ coords,
                                                     float* __restrict__ bstats) {
    int b = blockIdx.x;
    int t = threadIdx.x;
    __shared__ float red[256];
    __shared__ float means[3];
    for (int c = 0; c < 3; ++c) {
        float acc = 0.f;
        const float* p = coords + ((size_t)b * 3 + c) * NPTS;
        for (int n = t; n < NPTS; n += 256) acc += p[n];
        red[t] = acc; __syncthreads();
        for (int s = 128; s > 0; s >>= 1) { if (t < s) red[t] += red[t + s]; __syncthreads(); }
        if (t == 0) means[c] = red[0] * (1.f / NPTS);
        __syncthreads();
    }
    float m0 = means[0], m1 = means[1], m2 = means[2];
    const float* px = coords + ((size_t)b * 3 + 0) * NPTS;
    const float* py = coords + ((size_t)b * 3 + 1) * NPTS;
    const float* pz = coords + ((size_t)b * 3 + 2) * NPTS;
    float mx = 0.f;
    for (int n = t; n < NPTS; n += 256) {
        float dx = px[n] - m0, dy = py[n] - m1, dz = pz[n] - m2;
        mx = fmaxf(mx, sqrtf(dx * dx + dy * dy + dz * dz));
    }
    red[t] = mx; __syncthreads();
    for (int s = 128; s > 0; s >>= 1) { if (t < s) red[t] = fmaxf(red[t], red[t + s]); __syncthreads(); }
    if (t == 0) {
        bstats[b * 4 + 0] = m0; bstats[b * 4 + 1] = m1; bstats[b * 4 + 2] = m2;
        bstats[b * 4 + 3] = 1.f / (2.f * red[0]);
    }
}

// ---------------- per-point voxel index + nc4 + count ----------------
__global__ __launch_bounds__(256) void vox_idx_k(const float* __restrict__ coords,
                                                 const float* __restrict__ bstats,
                                                 float4* __restrict__ nc4,
                                                 int* __restrict__ vidx,
                                                 int* __restrict__ slot,
                                                 unsigned int* __restrict__ cnts) {
    int g = blockIdx.x * 256 + threadIdx.x;
    int b = g >> 14, n = g & (NPTS - 1);
    float m0 = bstats[b * 4 + 0], m1 = bstats[b * 4 + 1], m2 = bstats[b * 4 + 2];
    float sc = bstats[b * 4 + 3];
    float x = coords[((size_t)b * 3 + 0) * NPTS + n];
    float y = coords[((size_t)b * 3 + 1) * NPTS + n];
    float z = coords[((size_t)b * 3 + 2) * NPTS + n];
    float ncx = fminf(fmaxf(((x - m0) * sc + 0.5f) * (float)RES, 0.f), RES - 1.f);
    float ncy = fminf(fmaxf(((y - m1) * sc + 0.5f) * (float)RES, 0.f), RES - 1.f);
    float ncz = fminf(fmaxf(((z - m2) * sc + 0.5f) * (float)RES, 0.f), RES - 1.f);
    nc4[g] = make_float4(ncx, ncy, ncz, 0.f);
    int ix = min(max((int)rintf(ncx), 0), RES - 1);  // rintf = half-even = jnp.round
    int iy = min(max((int)rintf(ncy), 0), RES - 1);
    int iz = min(max((int)rintf(ncz), 0), RES - 1);
    int v = b * R3 + (ix * RES + iy) * RES + iz;
    vidx[g] = v;
    slot[g] = (int)atomicAdd(&cnts[v], 1u);
}

// ---------------- feature transpose: [b][64][N] fp32 -> [g][64] fp32 ----------------
__global__ __launch_bounds__(256) void transpose_feats_k(const float* __restrict__ feats,
                                                         float* __restrict__ featT) {
    int blk = blockIdx.x;
    int b = blk >> 8, ntile = blk & 255;
    int t = threadIdx.x;
    __shared__ float lds[64][65];
    for (int e = t; e < 64 * 64; e += 256) {
        int c = e >> 6, n = e & 63;
        lds[c][n] = feats[((size_t)b * CIN + c) * NPTS + ntile * 64 + n];
    }
    __syncthreads();
    for (int e = t; e < 64 * 64; e += 256) {
        int n = e >> 6, c = e & 63;
        featT[(((size_t)b << 14) + ntile * 64 + n) * CIN + c] = lds[c][n];
    }
}

// ---------------- scan ----------------
__global__ __launch_bounds__(256) void scan1_k(const unsigned int* __restrict__ cnts,
                                               unsigned int* __restrict__ offs,
                                               unsigned int* __restrict__ part) {
    int t = threadIdx.x;
    int g = blockIdx.x * 256 + t;
    unsigned int v = cnts[g];
    __shared__ unsigned int s[256];
    s[t] = v; __syncthreads();
    for (int d = 1; d < 256; d <<= 1) {
        unsigned int x = (t >= d) ? s[t - d] : 0u;
        __syncthreads();
        s[t] += x;
        __syncthreads();
    }
    offs[g] = s[t] - v;
    if (t == 255) part[blockIdx.x] = s[255];
}

__global__ __launch_bounds__(1024) void scan2_k(unsigned int* __restrict__ part) {
    int t = threadIdx.x;
    unsigned int v = part[t];
    __shared__ unsigned int s[1024];
    s[t] = v; __syncthreads();
    for (int d = 1; d < 1024; d <<= 1) {
        unsigned int x = (t >= d) ? s[t - d] : 0u;
        __syncthreads();
        s[t] += x;
        __syncthreads();
    }
    part[t] = s[t] - v;
}

__global__ __launch_bounds__(256) void scan3_k(unsigned int* __restrict__ offs,
                                               const unsigned int* __restrict__ part) {
    int g = blockIdx.x * 256 + threadIdx.x;
    offs[g] += part[blockIdx.x];
}

// ---------------- scatter global point id into CSR ----------------
__global__ __launch_bounds__(256) void scatter_pts_k(const int* __restrict__ vidx,
                                                     const int* __restrict__ slot,
                                                     const unsigned int* __restrict__ offs,
                                                     unsigned int* __restrict__ pidx2) {
    int g = blockIdx.x * 256 + threadIdx.x;
    int v = vidx[g];
    pidx2[offs[v] + slot[g]] = (unsigned int)g;
}

// ---------------- gather: CSR mean -> bf16 channel-last vox ----------------
__global__ __launch_bounds__(256) void gather_k(const float* __restrict__ featT,
                                                const unsigned int* __restrict__ cnts,
                                                const unsigned int* __restrict__ offs,
                                                const unsigned int* __restrict__ pidx2,
                                                bf16* __restrict__ voxCL) {
    int u = blockIdx.x * 256 + threadIdx.x;
    int v = u >> 3;
    int l8 = u & 7;
    unsigned int cnt = cnts[v];
    unsigned int off = offs[v];
    float acc[8] = {0.f, 0.f, 0.f, 0.f, 0.f, 0.f, 0.f, 0.f};
    for (unsigned int i = 0; i < cnt; ++i) {
        unsigned int g = pidx2[off + i];
        const float4* fp = (const float4*)(featT + (size_t)g * CIN + l8 * 8);
        float4 f0 = fp[0], f1 = fp[1];
        acc[0] += f0.x; acc[1] += f0.y; acc[2] += f0.z; acc[3] += f0.w;
        acc[4] += f1.x; acc[5] += f1.y; acc[6] += f1.z; acc[7] += f1.w;
    }
    float inv = 1.f / fmaxf((float)cnt, 1.f);
    ushort o[8];
#pragma unroll
    for (int j = 0; j < 8; ++j) o[j] = f2bu(acc[j] * inv);
    *(short8*)(voxCL + (size_t)v * CIN + l8 * 8) = *(short8*)o;
}

// ---------------- weight reorder: [co][ci][27] fp32 -> [t][c32][co][kb][8] bf16 ----------------
template <int CIN_T>
__global__ __launch_bounds__(256) void wreorder_k(const float* __restrict__ w,
                                                  bf16* __restrict__ wf) {
    const int NC = CIN_T / 32;
    int u = blockIdx.x * 256 + threadIdx.x;
    if (u >= 27 * NC * 128 * 4) return;
    int kb = u & 3;
    int co = (u >> 2) & 127;
    int c32 = (u >> 9) % NC;
    int t = u / (512 * NC);
    int cibase = c32 * 32 + kb * 8;
    ushort o[8];
#pragma unroll
    for (int j = 0; j < 8; ++j)
        o[j] = f2bu(w[((size_t)co * CIN_T + cibase + j) * 27 + t]);
    *(short8*)(wf + (size_t)u * 8) = *(short8*)o;
}

// ---------------- wp transpose: [co][ci] -> [ci][co] fp32 ----------------
__global__ __launch_bounds__(256) void wpt_k(const float* __restrict__ wp,
                                             float* __restrict__ wpT) {
    int u = blockIdx.x * 256 + threadIdx.x;  // 8192
    int co = u & 127, ci = u >> 7;
    wpT[ci * 128 + co] = wp[co * 64 + ci];
}

// ---------------- implicit-GEMM conv3d 3x3x3 via MFMA bf16 (R6-proven, EXACT) ----------------
// block 512 = 8 waves (4 cog x 2 sg); 80B pos stride; 49KB LDS -> 3 blocks/CU.
// Measured: conv2 272us @ MfmaUtil 38% / occ 60%. GNIN fusion REVERTED (R11: +45us,
// staging-volume 4.8x halo made per-element swish dominate). Mapping/bounds untouched.
template <int CIN_T>
__global__ __launch_bounds__(512, 2) void conv3d_mfma_k(const bf16* __restrict__ x,  // [b][p][CIN_T]
                                                        const bf16* __restrict__ wf, // [27][NC][128][4][8]
                                                        const float* __restrict__ bias,
                                                        bf16* __restrict__ y,        // [b][p][128]
                                                        float* __restrict__ gnacc) { // [64][2]
    constexpr int NC = CIN_T / 32;
    int blk = blockIdx.x;
    int hq = blk & 7;
    int d = (blk >> 3) & 31;
    int b = blk >> 8;
    int t = threadIdx.x;
    int lane = t & 63;
    int wid = t >> 6;
    int cog = wid >> 1;  // 0..3
    int sg = wid & 1;    // 0..1
    int lr = lane & 15;
    int kb = lane >> 4;

    __shared__ __align__(16) char xs[3 * 6 * 34 * 80];  // 48960 B
    __shared__ float gred[8][2];
    if (t < 16) gred[t >> 1][t & 1] = 0.f;

    f32x4 acc[2][4];
#pragma unroll
    for (int r = 0; r < 2; ++r)
#pragma unroll
        for (int j = 0; j < 4; ++j) acc[r][j] = (f32x4){0.f, 0.f, 0.f, 0.f};

    int bbase[4];
#pragma unroll
    for (int j = 0; j < 4; ++j) {
        int sp = sg * 64 + j * 16 + lr;
        int hl = sp >> 5, wl = sp & 31;
        bbase[j] = (hl * 34 + wl) * 80 + kb * 16;
    }

    for (int cc = 0; cc < NC; ++cc) {
        __syncthreads();
        for (int e = t; e < 612 * 4; e += 512) {
            int ekb = e & 3;
            int pos = e >> 2;
            int ww = pos % 34;
            int hh = (pos / 34) % 6;
            int dd = pos / 204;
            int dz = d + dd - 1;
            int hz = hq * 4 + hh - 1;
            int wz = ww - 1;
            short8 v = {0, 0, 0, 0, 0, 0, 0, 0};
            if (dz >= 0 && dz < RES && hz >= 0 && hz < RES && wz >= 0 && wz < RES)
                v = *(const short8*)(x + ((size_t)b * R3 + dz * 1024 + hz * 32 + wz) * CIN_T + cc * 32 + ekb * 8);
            *(short8*)(xs + pos * 80 + ekb * 16) = v;
        }
        __syncthreads();

        const short8* wfp = (const short8*)wf;
        size_t abase = ((size_t)cc * 128 + cog * 32 + lr) * 4 + kb;
#pragma unroll
        for (int dd = 0; dd < 3; ++dd)
#pragma unroll
            for (int dh = 0; dh < 3; ++dh)
#pragma unroll
                for (int dw = 0; dw < 3; ++dw) {
                    int tap = (dd * 3 + dh) * 3 + dw;
                    short8 a0 = wfp[abase + (size_t)tap * NC * 512];
                    short8 a1 = wfp[abase + (size_t)tap * NC * 512 + 64];
                    int toff = ((dd * 6 + dh) * 34 + dw) * 80;
                    short8 bb[4];
#pragma unroll
                    for (int j = 0; j < 4; ++j)
                        bb[j] = *(const short8*)(xs + bbase[j] + toff);
#pragma unroll
                    for (int j = 0; j < 4; ++j) {
                        acc[0][j] = __builtin_amdgcn_mfma_f32_16x16x32_bf16(a0, bb[j], acc[0][j], 0, 0, 0);
                        acc[1][j] = __builtin_amdgcn_mfma_f32_16x16x32_bf16(a1, bb[j], acc[1][j], 0, 0, 0);
                    }
                }
    }

    // epilogue: store bf16 + GN partial stats (group = cog*2 + r)
    float sred[2], ssred[2];
#pragma unroll
    for (int r = 0; r < 2; ++r) {
        int co = cog * 32 + r * 16 + kb * 4;
        float4 bv = *(const float4*)(bias + co);
        float s = 0.f, ss = 0.f;
#pragma unroll
        for (int j = 0; j < 4; ++j) {
            int sp = sg * 64 + j * 16 + lr;
            int p = d * 1024 + (hq * 4 + (sp >> 5)) * 32 + (sp & 31);
            float v0 = acc[r][j][0] + bv.x;
            float v1 = acc[r][j][1] + bv.y;
            float v2 = acc[r][j][2] + bv.z;
            float v3 = acc[r][j][3] + bv.w;
            ushort4 o;
            o.x = f2bu(v0); o.y = f2bu(v1); o.z = f2bu(v2); o.w = f2bu(v3);
            *(ushort4*)(y + ((size_t)b * R3 + p) * COUT + co) = o;
            s += v0 + v1 + v2 + v3;
            ss += v0 * v0 + v1 * v1 + v2 * v2 + v3 * v3;
        }
        sred[r] = s; ssred[r] = ss;
    }
#pragma unroll
    for (int m = 1; m < 64; m <<= 1) {
#pragma unroll
        for (int r = 0; r < 2; ++r) {
            sred[r] += __shfl_xor(sred[r], m, 64);
            ssred[r] += __shfl_xor(ssred[r], m, 64);
        }
    }
    if (lane == 0) {
#pragma unroll
        for (int r = 0; r < 2; ++r) {
            atomicAdd(&gred[cog * 2 + r][0], sred[r]);
            atomicAdd(&gred[cog * 2 + r][1], ssred[r]);
        }
    }
    __syncthreads();
    if (t < 16) atomicAdd(&gnacc[(b * 8 + (t >> 1)) * 2 + (t & 1)], gred[t >> 1][t & 1]);
}

// ---------------- GN apply + swish (act1, between convs) ----------------
__global__ __launch_bounds__(256) void gn_apply_cl_k(bf16* __restrict__ x,
                                                     const float* __restrict__ gnacc,
                                                     const float* __restrict__ gamma,
                                                     const float* __restrict__ beta) {
    int u = blockIdx.x * 256 + threadIdx.x;
    int ci8 = u & 15;
    int p = (u >> 4) & (R3 - 1);
    int b = u >> 19;
    int ci = ci8 * 8;
    int bg = b * 8 + (ci8 >> 1);
    const float M = (float)(GSIZE * R3);
    float s = gnacc[bg * 2], ss = gnacc[bg * 2 + 1];
    float mean = s / M;
    float istd = rsqrtf(fmaxf(ss / M - mean * mean, 0.f) + 1e-5f);
    bf16* ptr = x + ((size_t)b * R3 + p) * COUT + ci;
    short8 v = *(const short8*)ptr;
    ushort o[8];
#pragma unroll
    for (int j = 0; j < 8; ++j) {
        float f = b2f((ushort)v[j]);
        float yv = fmaf((f - mean) * istd, gamma[ci + j], beta[ci + j]);
        o[j] = f2bu(yv / (1.f + __expf(-yv)));
    }
    *(short8*)ptr = *(short8*)o;
}

// ---------------- point-branch: GEMM -> pf bf16 store + GN stats ----------------
__global__ __launch_bounds__(256) void pstats_cl_k(const float* __restrict__ featT, // [g][64]
                                                   const float* __restrict__ wpT,   // [64][128]
                                                   const float* __restrict__ bp,
                                                   bf16* __restrict__ pfb,          // [g][128]
                                                   float* __restrict__ gnacc) {     // [64][2]
    __shared__ float wls[64 * 128];  // 32 KB
    __shared__ float gred[8][2];
    int t = threadIdx.x;
    for (int e = t; e < 64 * 128 / 4; e += 256)
        ((float4*)wls)[e] = ((const float4*)wpT)[e];
    if (t < 16) gred[t >> 1][t & 1] = 0.f;
    __syncthreads();

    int u = blockIdx.x * 256 + t;
    int g = u >> 3;
    int l8 = u & 7;
    int b = g >> 14;
    int c0 = l8 * 16;

    float a[16];
#pragma unroll
    for (int k = 0; k < 16; ++k) a[k] = bp[c0 + k];
    const float* fg = featT + (size_t)g * CIN;
    for (int ci = 0; ci < CIN; ++ci) {
        float fv = fg[ci];
        const float* wrow = wls + ci * 128 + c0;
#pragma unroll
        for (int k = 0; k < 16; ++k) a[k] = fmaf(wrow[k], fv, a[k]);
    }
    ushort o_[16];
#pragma unroll
    for (int k = 0; k < 16; ++k) o_[k] = f2bu(a[k]);
    *(short8*)(pfb + (size_t)g * COUT + c0) = *(short8*)(o_);
    *(short8*)(pfb + (size_t)g * COUT + c0 + 8) = *(short8*)(o_ + 8);

    float s = 0.f, ss = 0.f;
#pragma unroll
    for (int k = 0; k < 16; ++k) { s += a[k]; ss = fmaf(a[k], a[k], ss); }
    s += __shfl_xor(s, 8, 64);  ss += __shfl_xor(ss, 8, 64);
    s += __shfl_xor(s, 16, 64); ss += __shfl_xor(ss, 16, 64);
    s += __shfl_xor(s, 32, 64); ss += __shfl_xor(ss, 32, 64);
    int lane = t & 63;
    if (lane < 8) {
        atomicAdd(&gred[lane][0], s);
        atomicAdd(&gred[lane][1], ss);
    }
    __syncthreads();
    if (t < 16) atomicAdd(&gnacc[(b * 8 + (t >> 1)) * 2 + (t & 1)], gred[t >> 1][t & 1]);
}

// ---------------- fuse2: 8 lanes/point; load pf + GN + swish + devox + add ----------------
__global__ __launch_bounds__(256) void fuse2_k(const bf16* __restrict__ vox,   // act2 [b][p][128]
                                               const bf16* __restrict__ pfb,   // [g][128]
                                               const float4* __restrict__ nc4,
                                               const unsigned int* __restrict__ pidx2,
                                               const float* __restrict__ gn2acc,
                                               const float* __restrict__ gnpacc,
                                               const float* __restrict__ g2g,
                                               const float* __restrict__ g2b,
                                               const float* __restrict__ gpg,
                                               const float* __restrict__ gpb,
                                               float* __restrict__ pfT) {      // [g][128]
    int t = threadIdx.x;
    int u = blockIdx.x * 256 + t;
    int s = u >> 3;
    int l8 = u & 7;
    unsigned int g = pidx2[s];
    int b = (int)(g >> 14);
    int c0 = l8 * 16;

    const short8* pfp = (const short8*)(pfb + (size_t)g * COUT + c0);
    short8 p0 = pfp[0], p1 = pfp[1];
    float a[16];
#pragma unroll
    for (int j = 0; j < 8; ++j) { a[j] = b2f((ushort)p0[j]); a[8 + j] = b2f((ushort)p1[j]); }

    int bg = b * 8 + l8;
    const float M2 = (float)(GSIZE * R3);
    const float Mp = (float)(GSIZE * NPTS);
    float s2 = gn2acc[bg * 2], ss2 = gn2acc[bg * 2 + 1];
    float mean2 = s2 / M2;
    float istd2 = rsqrtf(fmaxf(ss2 / M2 - mean2 * mean2, 0.f) + 1e-5f);
    float sp = gnpacc[bg * 2], ssp = gnpacc[bg * 2 + 1];
    float meanp = sp / Mp;
    float istdp = rsqrtf(fmaxf(ssp / Mp - meanp * meanp, 0.f) + 1e-5f);
    float ga[16], gb[16];
#pragma unroll
    for (int j = 0; j < 16; ++j) {
        float gm = g2g[c0 + j];
        ga[j] = istd2 * gm;
        gb[j] = g2b[c0 + j] - mean2 * istd2 * gm;
    }

    float4 c4 = nc4[g];
    const float CMAX = (float)(RES - 1) - 1e-6f;
    float cx = fminf(c4.x, CMAX), cy = fminf(c4.y, CMAX), cz = fminf(c4.z, CMAX);
    int ix0 = (int)cx, iy0 = (int)cy, iz0 = (int)cz;
    float fx = cx - ix0, fy = cy - iy0, fz = cz - iz0;
    int ix1 = min(ix0 + 1, RES - 1), iy1 = min(iy0 + 1, RES - 1), iz1 = min(iz0 + 1, RES - 1);
    float gx0 = 1.f - fx, gy0 = 1.f - fy, gz0 = 1.f - fz;
    float wc[8] = {gx0 * gy0 * gz0, gx0 * gy0 * fz, gx0 * fy * gz0, gx0 * fy * fz,
                   fx * gy0 * gz0,  fx * gy0 * fz,  fx * fy * gz0,  fx * fy * fz};
    int fi[8];
    fi[0] = (ix0 * RES + iy0) * RES + iz0; fi[1] = (ix0 * RES + iy0) * RES + iz1;
    fi[2] = (ix0 * RES + iy1) * RES + iz0; fi[3] = (ix0 * RES + iy1) * RES + iz1;
    fi[4] = (ix1 * RES + iy0) * RES + iz0; fi[5] = (ix1 * RES + iy0) * RES + iz1;
    fi[6] = (ix1 * RES + iy1) * RES + iz0; fi[7] = (ix1 * RES + iy1) * RES + iz1;

    const bf16* vb = vox + (size_t)b * R3 * COUT + c0;
    float accv[16] = {0.f, 0.f, 0.f, 0.f, 0.f, 0.f, 0.f, 0.f,
                      0.f, 0.f, 0.f, 0.f, 0.f, 0.f, 0.f, 0.f};
#pragma unroll
    for (int f = 0; f < 8; ++f) {
        const short8* vp = (const short8*)(vb + (size_t)fi[f] * COUT);
        short8 v0 = vp[0], v1 = vp[1];
        float wgt = wc[f];
#pragma unroll
        for (int j = 0; j < 8; ++j) {
            float yv = fmaf(b2f((ushort)v0[j]), ga[j], gb[j]);
            accv[j] = fmaf(wgt, yv / (1.f + __expf(-yv)), accv[j]);
        }
#pragma unroll
        for (int j = 0; j < 8; ++j) {
            float yv = fmaf(b2f((ushort)v1[j]), ga[8 + j], gb[8 + j]);
            accv[8 + j] = fmaf(wgt, yv / (1.f + __expf(-yv)), accv[8 + j]);
        }
    }

    float outv[16];
#pragma unroll
    for (int j = 0; j < 16; ++j) {
        float pm = gpg[c0 + j];
        float yv = fmaf((a[j] - meanp) * istdp, pm, gpb[c0 + j]);
        outv[j] = yv / (1.f + __expf(-yv)) + accv[j];
    }
    float* pp = pfT + (size_t)g * COUT + c0;
#pragma unroll
    for (int k = 0; k < 4; ++k)
        *(float4*)(pp + k * 4) = make_float4(outv[k*4], outv[k*4+1], outv[k*4+2], outv[k*4+3]);
}

// ---------------- transpose pfT [b][n][128] -> out [b][128][n] ----------------
__global__ __launch_bounds__(256) void transpose_out_k(const float* __restrict__ pfT,
                                                       float* __restrict__ out) {
    int blk = blockIdx.x;
    int b = blk >> 8, nt = blk & 255;
    int t = threadIdx.x;
    int n0 = nt * 64;
    __shared__ float lds[64][129];
#pragma unroll
    for (int k = 0; k < 8; ++k) {
        int e = t + k * 256;
        int row = e >> 5, c4 = e & 31;
        float4 v = ((const float4*)pfT)[(((size_t)b << 14) + n0 + row) * 32 + c4];
        lds[row][c4 * 4 + 0] = v.x;
        lds[row][c4 * 4 + 1] = v.y;
        lds[row][c4 * 4 + 2] = v.z;
        lds[row][c4 * 4 + 3] = v.w;
    }
    __syncthreads();
#pragma unroll
    for (int k = 0; k < 32; ++k) {
        int e = t + k * 256;
        int c = e >> 6, n = e & 63;
        out[((size_t)b * COUT + c) * NPTS + n0 + n] = lds[n][c];
    }
}

extern "C" void kernel_launch(void* const* d_in, const int* in_sizes, int n_in,
                              void* d_out, int out_size, void* d_ws, size_t ws_size,
                              hipStream_t stream) {
    const float* features = (const float*)d_in[0];
    const float* coords   = (const float*)d_in[1];
    const float* w1  = (const float*)d_in[3];
    const float* b1  = (const float*)d_in[4];
    const float* g1g = (const float*)d_in[5];
    const float* g1b = (const float*)d_in[6];
    const float* w2  = (const float*)d_in[7];
    const float* b2  = (const float*)d_in[8];
    const float* g2g = (const float*)d_in[9];
    const float* g2b = (const float*)d_in[10];
    const float* wp  = (const float*)d_in[11];
    const float* bp  = (const float*)d_in[12];
    const float* gpg = (const float*)d_in[13];
    const float* gpb = (const float*)d_in[14];
    float* out = (float*)d_out;

    // ws (~199 MB):
    //   [0,64MB)     act1 bf16 -> pfT fp32 (overlay; act1 dead after conv2)
    //   [64,128MB)   act2 bf16 (live until fuse2)
    //   [128,160MB)  voxCL bf16 -> pfb bf16 (overlay; voxCL dead after conv1)
    //   [160,192MB)  featT fp32
    //   tail: w1f, w2f, wpT, nc4, cnts, offs, vidx, slot, pidx2, part, stats
    char* ws = (char*)d_ws;
    size_t off = 0;
    bf16* act1 = (bf16*)(ws + off);
    float* pfT = (float*)(ws + off);         off += (size_t)BATCH * R3 * COUT * 2;  // 64MB
    bf16* act2 = (bf16*)(ws + off);          off += (size_t)BATCH * R3 * COUT * 2;  // 64MB
    bf16* voxCL = (bf16*)(ws + off);
    bf16* pfb = (bf16*)(ws + off);           off += (size_t)BATCH * R3 * CIN * 2;   // 32MB
    float* featT = (float*)(ws + off);       off += (size_t)BATCH * NPTS * CIN * 4; // 32MB
    bf16* w1f = (bf16*)(ws + off);           off += (size_t)27 * 2 * 128 * 32 * 2;
    bf16* w2f = (bf16*)(ws + off);           off += (size_t)27 * 4 * 128 * 32 * 2;
    float* wpT = (float*)(ws + off);         off += 64 * 128 * 4;
    float4* nc4 = (float4*)(ws + off);       off += (size_t)BATCH * NPTS * 16;
    unsigned int* cnts = (unsigned int*)(ws + off);  off += (size_t)BATCH * R3 * 4;
    unsigned int* offs = (unsigned int*)(ws + off);  off += (size_t)BATCH * R3 * 4;
    int* vidx = (int*)(ws + off);            off += (size_t)BATCH * NPTS * 4;
    int* slot = (int*)(ws + off);            off += (size_t)BATCH * NPTS * 4;
    unsigned int* pidx2 = (unsigned int*)(ws + off); off += (size_t)BATCH * NPTS * 4;
    unsigned int* part = (unsigned int*)(ws + off);  off += 4096;
    float* bstats = (float*)(ws + off);      off += 256;
    float* gn1acc = (float*)(ws + off);      off += 512;
    float* gn2acc = (float*)(ws + off);      off += 512;
    float* gnpacc = (float*)(ws + off);      off += 512;

    hipMemsetAsync(cnts, 0, (size_t)BATCH * R3 * 4, stream);
    hipMemsetAsync(gn1acc, 0, 3 * 512, stream);

    coord_stats_k<<<BATCH, 256, 0, stream>>>(coords, bstats);
    vox_idx_k<<<BATCH * NPTS / 256, 256, 0, stream>>>(coords, bstats, nc4, vidx, slot, cnts);
    transpose_feats_k<<<BATCH * 256, 256, 0, stream>>>(features, featT);
    scan1_k<<<BATCH * R3 / 256, 256, 0, stream>>>(cnts, offs, part);
    scan2_k<<<1, 1024, 0, stream>>>(part);
    scan3_k<<<BATCH * R3 / 256, 256, 0, stream>>>(offs, part);
    scatter_pts_k<<<BATCH * NPTS / 256, 256, 0, stream>>>(vidx, slot, offs, pidx2);
    gather_k<<<BATCH * R3 * 8 / 256, 256, 0, stream>>>(featT, cnts, offs, pidx2, voxCL);

    wreorder_k<CIN><<<(27 * 2 * 128 * 4 + 255) / 256, 256, 0, stream>>>(w1, w1f);
    wreorder_k<COUT><<<(27 * 4 * 128 * 4 + 255) / 256, 256, 0, stream>>>(w2, w2f);
    wpt_k<<<32, 256, 0, stream>>>(wp, wpT);

    conv3d_mfma_k<CIN><<<BATCH * 32 * 8, 512, 0, stream>>>(voxCL, w1f, b1, act1, gn1acc);
    gn_apply_cl_k<<<BATCH * R3 * 16 / 256, 256, 0, stream>>>(act1, gn1acc, g1g, g1b);

    conv3d_mfma_k<COUT><<<BATCH * 32 * 8, 512, 0, stream>>>(act1, w2f, b2, act2, gn2acc);

    // pfb overlays voxCL (dead after conv1); launched after conv2 for safety
    pstats_cl_k<<<BATCH * NPTS * 8 / 256, 256, 0, stream>>>(featT, wpT, bp, pfb, gnpacc);

    fuse2_k<<<BATCH * NPTS * 8 / 256, 256, 0, stream>>>(act2, pfb, nc4, pidx2,
                                                        gn2acc, gnpacc, g2g, g2b, gpg, gpb, pfT);

    transpose_out_k<<<BATCH * 256, 256, 0, stream>>>(pfT, out);
}

// Round 13
// 644.238 us; speedup vs baseline: 2.3575x; 1.0767x over previous
//
#include <hip/hip_runtime.h>
#include <hip/hip_bf16.h>
#include <cmath>

#define BATCH 8
#define CIN 64
#define COUT 128
#define NPTS 16384
#define RES 32
#define R3 32768
#define NGROUP 8
#define GSIZE 16

typedef __hip_bfloat16 bf16;
typedef __attribute__((ext_vector_type(8))) short short8;
typedef __attribute__((ext_vector_type(4))) float f32x4;

__device__ inline float b2f(ushort u) { union { float f; uint v; } x; x.v = ((uint)u) << 16; return x.f; }
__device__ inline ushort f2bu(float f) { __hip_bfloat16 h = __float2bfloat16(f); return *reinterpret_cast<ushort*>(&h); }

// ---------------- coord stats ----------------
__global__ __launch_bounds__(256) void coord_stats_k(const float* __restrict__ coords,
                                                     float* __restrict__ bstats) {
    int b = blockIdx.x;
    int t = threadIdx.x;
    __shared__ float red[256];
    __shared__ float means[3];
    for (int c = 0; c < 3; ++c) {
        float acc = 0.f;
        const float* p = coords + ((size_t)b * 3 + c) * NPTS;
        for (int n = t; n < NPTS; n += 256) acc += p[n];
        red[t] = acc; __syncthreads();
        for (int s = 128; s > 0; s >>= 1) { if (t < s) red[t] += red[t + s]; __syncthreads(); }
        if (t == 0) means[c] = red[0] * (1.f / NPTS);
        __syncthreads();
    }
    float m0 = means[0], m1 = means[1], m2 = means[2];
    const float* px = coords + ((size_t)b * 3 + 0) * NPTS;
    const float* py = coords + ((size_t)b * 3 + 1) * NPTS;
    const float* pz = coords + ((size_t)b * 3 + 2) * NPTS;
    float mx = 0.f;
    for (int n = t; n < NPTS; n += 256) {
        float dx = px[n] - m0, dy = py[n] - m1, dz = pz[n] - m2;
        mx = fmaxf(mx, sqrtf(dx * dx + dy * dy + dz * dz));
    }
    red[t] = mx; __syncthreads();
    for (int s = 128; s > 0; s >>= 1) { if (t < s) red[t] = fmaxf(red[t], red[t + s]); __syncthreads(); }
    if (t == 0) {
        bstats[b * 4 + 0] = m0; bstats[b * 4 + 1] = m1; bstats[b * 4 + 2] = m2;
        bstats[b * 4 + 3] = 1.f / (2.f * red[0]);
    }
}

// ---------------- per-point voxel index + nc4 + count ----------------
__global__ __launch_bounds__(256) void vox_idx_k(const float* __restrict__ coords,
                                                 const float* __restrict__ bstats,
                                                 float4* __restrict__ nc4,
                                                 int* __restrict__ vidx,
                                                 int* __restrict__ slot,
                                                 unsigned int* __restrict__ cnts) {
    int g = blockIdx.x * 256 + threadIdx.x;
    int b = g >> 14, n = g & (NPTS - 1);
    float m0 = bstats[b * 4 + 0], m1 = bstats[b * 4 + 1], m2 = bstats[b * 4 + 2];
    float sc = bstats[b * 4 + 3];
    float x = coords[((size_t)b * 3 + 0) * NPTS + n];
    float y = coords[((size_t)b * 3 + 1) * NPTS + n];
    float z = coords[((size_t)b * 3 + 2) * NPTS + n];
    float ncx = fminf(fmaxf(((x - m0) * sc + 0.5f) * (float)RES, 0.f), RES - 1.f);
    float ncy = fminf(fmaxf(((y - m1) * sc + 0.5f) * (float)RES, 0.f), RES - 1.f);
    float ncz = fminf(fmaxf(((z - m2) * sc + 0.5f) * (float)RES, 0.f), RES - 1.f);
    nc4[g] = make_float4(ncx, ncy, ncz, 0.f);
    int ix = min(max((int)rintf(ncx), 0), RES - 1);  // rintf = half-even = jnp.round
    int iy = min(max((int)rintf(ncy), 0), RES - 1);
    int iz = min(max((int)rintf(ncz), 0), RES - 1);
    int v = b * R3 + (ix * RES + iy) * RES + iz;
    vidx[g] = v;
    slot[g] = (int)atomicAdd(&cnts[v], 1u);
}

// ---------------- feature transpose: [b][64][N] fp32 -> [g][64] bf16 ----------------
__global__ __launch_bounds__(256) void transpose_feats_k(const float* __restrict__ feats,
                                                         bf16* __restrict__ featTb) {
    int blk = blockIdx.x;
    int b = blk >> 8, ntile = blk & 255;
    int t = threadIdx.x;
    __shared__ float lds[64][65];
    for (int e = t; e < 64 * 64; e += 256) {
        int c = e >> 6, n = e & 63;
        lds[c][n] = feats[((size_t)b * CIN + c) * NPTS + ntile * 64 + n];
    }
    __syncthreads();
    for (int e = t; e < 64 * 8; e += 256) {   // 512: (n, ci-octet)
        int n = e >> 3, oct = e & 7;
        ushort o[8];
#pragma unroll
        for (int j = 0; j < 8; ++j) o[j] = f2bu(lds[oct * 8 + j][n]);
        *(short8*)(featTb + ((((size_t)b << 14) + ntile * 64 + n) * CIN) + oct * 8) = *(short8*)o;
    }
}

// ---------------- scan ----------------
__global__ __launch_bounds__(256) void scan1_k(const unsigned int* __restrict__ cnts,
                                               unsigned int* __restrict__ offs,
                                               unsigned int* __restrict__ part) {
    int t = threadIdx.x;
    int g = blockIdx.x * 256 + t;
    unsigned int v = cnts[g];
    __shared__ unsigned int s[256];
    s[t] = v; __syncthreads();
    for (int d = 1; d < 256; d <<= 1) {
        unsigned int x = (t >= d) ? s[t - d] : 0u;
        __syncthreads();
        s[t] += x;
        __syncthreads();
    }
    offs[g] = s[t] - v;
    if (t == 255) part[blockIdx.x] = s[255];
}

__global__ __launch_bounds__(1024) void scan2_k(unsigned int* __restrict__ part) {
    int t = threadIdx.x;
    unsigned int v = part[t];
    __shared__ unsigned int s[1024];
    s[t] = v; __syncthreads();
    for (int d = 1; d < 1024; d <<= 1) {
        unsigned int x = (t >= d) ? s[t - d] : 0u;
        __syncthreads();
        s[t] += x;
        __syncthreads();
    }
    part[t] = s[t] - v;
}

__global__ __launch_bounds__(256) void scan3_k(unsigned int* __restrict__ offs,
                                               const unsigned int* __restrict__ part) {
    int g = blockIdx.x * 256 + threadIdx.x;
    offs[g] += part[blockIdx.x];
}

// ---------------- scatter global point id into CSR ----------------
__global__ __launch_bounds__(256) void scatter_pts_k(const int* __restrict__ vidx,
                                                     const int* __restrict__ slot,
                                                     const unsigned int* __restrict__ offs,
                                                     unsigned int* __restrict__ pidx2) {
    int g = blockIdx.x * 256 + threadIdx.x;
    int v = vidx[g];
    pidx2[offs[v] + slot[g]] = (unsigned int)g;
}

// ---------------- gather: CSR mean -> bf16 channel-last vox ----------------
__global__ __launch_bounds__(256) void gather_k(const bf16* __restrict__ featTb,
                                                const unsigned int* __restrict__ cnts,
                                                const unsigned int* __restrict__ offs,
                                                const unsigned int* __restrict__ pidx2,
                                                bf16* __restrict__ voxCL) {
    int u = blockIdx.x * 256 + threadIdx.x;
    int v = u >> 3;
    int l8 = u & 7;
    unsigned int cnt = cnts[v];
    unsigned int off = offs[v];
    float acc[8] = {0.f, 0.f, 0.f, 0.f, 0.f, 0.f, 0.f, 0.f};
    for (unsigned int i = 0; i < cnt; ++i) {
        unsigned int g = pidx2[off + i];
        short8 f = *(const short8*)(featTb + (size_t)g * CIN + l8 * 8);
#pragma unroll
        for (int j = 0; j < 8; ++j) acc[j] += b2f((ushort)f[j]);
    }
    float inv = 1.f / fmaxf((float)cnt, 1.f);
    ushort o[8];
#pragma unroll
    for (int j = 0; j < 8; ++j) o[j] = f2bu(acc[j] * inv);
    *(short8*)(voxCL + (size_t)v * CIN + l8 * 8) = *(short8*)o;
}

// ---------------- weight reorder: [co][ci][27] fp32 -> [t][c32][co][kb][8] bf16 ----------------
template <int CIN_T>
__global__ __launch_bounds__(256) void wreorder_k(const float* __restrict__ w,
                                                  bf16* __restrict__ wf) {
    const int NC = CIN_T / 32;
    int u = blockIdx.x * 256 + threadIdx.x;
    if (u >= 27 * NC * 128 * 4) return;
    int kb = u & 3;
    int co = (u >> 2) & 127;
    int c32 = (u >> 9) % NC;
    int t = u / (512 * NC);
    int cibase = c32 * 32 + kb * 8;
    ushort o[8];
#pragma unroll
    for (int j = 0; j < 8; ++j)
        o[j] = f2bu(w[((size_t)co * CIN_T + cibase + j) * 27 + t]);
    *(short8*)(wf + (size_t)u * 8) = *(short8*)o;
}

// ---------------- wp reorder: [co][64] fp32 -> [c32][co][kb][8] bf16 (MFMA A-frag order) ----------------
__global__ __launch_bounds__(256) void wpreorder_k(const float* __restrict__ wp,
                                                   bf16* __restrict__ wpb) {
    int u = blockIdx.x * 256 + threadIdx.x;  // 2*128*4 = 1024
    if (u >= 1024) return;
    int kb = u & 3;
    int co = (u >> 2) & 127;
    int c32 = u >> 9;
    ushort o[8];
#pragma unroll
    for (int j = 0; j < 8; ++j)
        o[j] = f2bu(wp[(size_t)co * CIN + c32 * 32 + kb * 8 + j]);
    *(short8*)(wpb + (size_t)u * 8) = *(short8*)o;
}

// ---------------- implicit-GEMM conv3d 3x3x3 via MFMA bf16 (R6-proven, EXACT) ----------------
// block 512 = 8 waves (4 cog x 2 sg); 80B pos stride; 49KB LDS -> 3 blocks/CU.
// Measured: conv2 272us @ MfmaUtil 38% / occ 60%. Mapping/bounds untouched.
template <int CIN_T>
__global__ __launch_bounds__(512, 2) void conv3d_mfma_k(const bf16* __restrict__ x,  // [b][p][CIN_T]
                                                        const bf16* __restrict__ wf, // [27][NC][128][4][8]
                                                        const float* __restrict__ bias,
                                                        bf16* __restrict__ y,        // [b][p][128]
                                                        float* __restrict__ gnacc) { // [64][2]
    constexpr int NC = CIN_T / 32;
    int blk = blockIdx.x;
    int hq = blk & 7;
    int d = (blk >> 3) & 31;
    int b = blk >> 8;
    int t = threadIdx.x;
    int lane = t & 63;
    int wid = t >> 6;
    int cog = wid >> 1;  // 0..3
    int sg = wid & 1;    // 0..1
    int lr = lane & 15;
    int kb = lane >> 4;

    __shared__ __align__(16) char xs[3 * 6 * 34 * 80];  // 48960 B
    __shared__ float gred[8][2];
    if (t < 16) gred[t >> 1][t & 1] = 0.f;

    f32x4 acc[2][4];
#pragma unroll
    for (int r = 0; r < 2; ++r)
#pragma unroll
        for (int j = 0; j < 4; ++j) acc[r][j] = (f32x4){0.f, 0.f, 0.f, 0.f};

    int bbase[4];
#pragma unroll
    for (int j = 0; j < 4; ++j) {
        int sp = sg * 64 + j * 16 + lr;
        int hl = sp >> 5, wl = sp & 31;
        bbase[j] = (hl * 34 + wl) * 80 + kb * 16;
    }

    for (int cc = 0; cc < NC; ++cc) {
        __syncthreads();
        for (int e = t; e < 612 * 4; e += 512) {
            int ekb = e & 3;
            int pos = e >> 2;
            int ww = pos % 34;
            int hh = (pos / 34) % 6;
            int dd = pos / 204;
            int dz = d + dd - 1;
            int hz = hq * 4 + hh - 1;
            int wz = ww - 1;
            short8 v = {0, 0, 0, 0, 0, 0, 0, 0};
            if (dz >= 0 && dz < RES && hz >= 0 && hz < RES && wz >= 0 && wz < RES)
                v = *(const short8*)(x + ((size_t)b * R3 + dz * 1024 + hz * 32 + wz) * CIN_T + cc * 32 + ekb * 8);
            *(short8*)(xs + pos * 80 + ekb * 16) = v;
        }
        __syncthreads();

        const short8* wfp = (const short8*)wf;
        size_t abase = ((size_t)cc * 128 + cog * 32 + lr) * 4 + kb;
#pragma unroll
        for (int dd = 0; dd < 3; ++dd)
#pragma unroll
            for (int dh = 0; dh < 3; ++dh)
#pragma unroll
                for (int dw = 0; dw < 3; ++dw) {
                    int tap = (dd * 3 + dh) * 3 + dw;
                    short8 a0 = wfp[abase + (size_t)tap * NC * 512];
                    short8 a1 = wfp[abase + (size_t)tap * NC * 512 + 64];
                    int toff = ((dd * 6 + dh) * 34 + dw) * 80;
                    short8 bb[4];
#pragma unroll
                    for (int j = 0; j < 4; ++j)
                        bb[j] = *(const short8*)(xs + bbase[j] + toff);
#pragma unroll
                    for (int j = 0; j < 4; ++j) {
                        acc[0][j] = __builtin_amdgcn_mfma_f32_16x16x32_bf16(a0, bb[j], acc[0][j], 0, 0, 0);
                        acc[1][j] = __builtin_amdgcn_mfma_f32_16x16x32_bf16(a1, bb[j], acc[1][j], 0, 0, 0);
                    }
                }
    }

    // epilogue: store bf16 + GN partial stats (group = cog*2 + r)
    float sred[2], ssred[2];
#pragma unroll
    for (int r = 0; r < 2; ++r) {
        int co = cog * 32 + r * 16 + kb * 4;
        float4 bv = *(const float4*)(bias + co);
        float s = 0.f, ss = 0.f;
#pragma unroll
        for (int j = 0; j < 4; ++j) {
            int sp = sg * 64 + j * 16 + lr;
            int p = d * 1024 + (hq * 4 + (sp >> 5)) * 32 + (sp & 31);
            float v0 = acc[r][j][0] + bv.x;
            float v1 = acc[r][j][1] + bv.y;
            float v2 = acc[r][j][2] + bv.z;
            float v3 = acc[r][j][3] + bv.w;
            ushort4 o;
            o.x = f2bu(v0); o.y = f2bu(v1); o.z = f2bu(v2); o.w = f2bu(v3);
            *(ushort4*)(y + ((size_t)b * R3 + p) * COUT + co) = o;
            s += v0 + v1 + v2 + v3;
            ss += v0 * v0 + v1 * v1 + v2 * v2 + v3 * v3;
        }
        sred[r] = s; ssred[r] = ss;
    }
#pragma unroll
    for (int m = 1; m < 64; m <<= 1) {
#pragma unroll
        for (int r = 0; r < 2; ++r) {
            sred[r] += __shfl_xor(sred[r], m, 64);
            ssred[r] += __shfl_xor(ssred[r], m, 64);
        }
    }
    if (lane == 0) {
#pragma unroll
        for (int r = 0; r < 2; ++r) {
            atomicAdd(&gred[cog * 2 + r][0], sred[r]);
            atomicAdd(&gred[cog * 2 + r][1], ssred[r]);
        }
    }
    __syncthreads();
    if (t < 16) atomicAdd(&gnacc[(b * 8 + (t >> 1)) * 2 + (t & 1)], gred[t >> 1][t & 1]);
}

// ---------------- GN apply + swish (act1, between convs) ----------------
__global__ __launch_bounds__(256) void gn_apply_cl_k(bf16* __restrict__ x,
                                                     const float* __restrict__ gnacc,
                                                     const float* __restrict__ gamma,
                                                     const float* __restrict__ beta) {
    int u = blockIdx.x * 256 + threadIdx.x;
    int ci8 = u & 15;
    int p = (u >> 4) & (R3 - 1);
    int b = u >> 19;
    int ci = ci8 * 8;
    int bg = b * 8 + (ci8 >> 1);
    const float M = (float)(GSIZE * R3);
    float s = gnacc[bg * 2], ss = gnacc[bg * 2 + 1];
    float mean = s / M;
    float istd = rsqrtf(fmaxf(ss / M - mean * mean, 0.f) + 1e-5f);
    bf16* ptr = x + ((size_t)b * R3 + p) * COUT + ci;
    short8 v = *(const short8*)ptr;
    ushort o[8];
#pragma unroll
    for (int j = 0; j < 8; ++j) {
        float f = b2f((ushort)v[j]);
        float yv = fmaf((f - mean) * istd, gamma[ci + j], beta[ci + j]);
        o[j] = f2bu(yv / (1.f + __expf(-yv)));
    }
    *(short8*)ptr = *(short8*)o;
}

// ---------------- point-branch GEMM via MFMA: pf bf16 + GN stats ----------------
// block 256 = 4 waves; block computes 64 points x 128 co. Wave cog: co in [cog*32, +32).
// A = wpb (conv-proven fragment order), B = featTb 16B/lane channel-contiguous.
// Epilogue identical in structure to conv's (group = cog*2 + r, kb/q-invariant).
__global__ __launch_bounds__(256) void pgemm_mfma_k(const bf16* __restrict__ featTb, // [g][64]
                                                    const bf16* __restrict__ wpb,    // [2][128][4][8]
                                                    const float* __restrict__ bp,
                                                    bf16* __restrict__ pfb,          // [g][128]
                                                    float* __restrict__ gnacc) {     // [64][2]
    int t = threadIdx.x;
    int lane = t & 63;
    int cog = t >> 6;       // 0..3
    int lr = lane & 15;
    int kb = lane >> 4;
    int g0 = blockIdx.x * 64;
    int b = g0 >> 14;

    __shared__ float gred[8][2];
    if (t < 16) gred[t >> 1][t & 1] = 0.f;

    f32x4 acc[2][4];
#pragma unroll
    for (int r = 0; r < 2; ++r)
#pragma unroll
        for (int j = 0; j < 4; ++j) acc[r][j] = (f32x4){0.f, 0.f, 0.f, 0.f};

    const short8* wfp = (const short8*)wpb;
    const short8* ftp = (const short8*)featTb;  // [g][8 octets]
#pragma unroll
    for (int cc = 0; cc < 2; ++cc) {
        size_t abase = ((size_t)cc * 128 + cog * 32 + lr) * 4 + kb;
        short8 a0 = wfp[abase];
        short8 a1 = wfp[abase + 64];
#pragma unroll
        for (int j = 0; j < 4; ++j) {
            short8 bb = ftp[(size_t)(g0 + j * 16 + lr) * 8 + cc * 4 + kb];
            acc[0][j] = __builtin_amdgcn_mfma_f32_16x16x32_bf16(a0, bb, acc[0][j], 0, 0, 0);
            acc[1][j] = __builtin_amdgcn_mfma_f32_16x16x32_bf16(a1, bb, acc[1][j], 0, 0, 0);
        }
    }

    float sred[2], ssred[2];
#pragma unroll
    for (int r = 0; r < 2; ++r) {
        int co = cog * 32 + r * 16 + kb * 4;
        float4 bv = *(const float4*)(bp + co);
        float s = 0.f, ss = 0.f;
#pragma unroll
        for (int j = 0; j < 4; ++j) {
            int g = g0 + j * 16 + lr;
            float v0 = acc[r][j][0] + bv.x;
            float v1 = acc[r][j][1] + bv.y;
            float v2 = acc[r][j][2] + bv.z;
            float v3 = acc[r][j][3] + bv.w;
            ushort4 o;
            o.x = f2bu(v0); o.y = f2bu(v1); o.z = f2bu(v2); o.w = f2bu(v3);
            *(ushort4*)(pfb + (size_t)g * COUT + co) = o;
            s += v0 + v1 + v2 + v3;
            ss += v0 * v0 + v1 * v1 + v2 * v2 + v3 * v3;
        }
        sred[r] = s; ssred[r] = ss;
    }
#pragma unroll
    for (int m = 1; m < 64; m <<= 1) {
#pragma unroll
        for (int r = 0; r < 2; ++r) {
            sred[r] += __shfl_xor(sred[r], m, 64);
            ssred[r] += __shfl_xor(ssred[r], m, 64);
        }
    }
    if (lane == 0) {
#pragma unroll
        for (int r = 0; r < 2; ++r) {
            atomicAdd(&gred[cog * 2 + r][0], sred[r]);
            atomicAdd(&gred[cog * 2 + r][1], ssred[r]);
        }
    }
    __syncthreads();
    if (t < 16) atomicAdd(&gnacc[(b * 8 + (t >> 1)) * 2 + (t & 1)], gred[t >> 1][t & 1]);
}

// ---------------- fuse2: 8 lanes/point; load pf + GN + swish + devox + add ----------------
__global__ __launch_bounds__(256) void fuse2_k(const bf16* __restrict__ vox,   // act2 [b][p][128]
                                               const bf16* __restrict__ pfb,   // [g][128]
                                               const float4* __restrict__ nc4,
                                               const unsigned int* __restrict__ pidx2,
                                               const float* __restrict__ gn2acc,
                                               const float* __restrict__ gnpacc,
                                               const float* __restrict__ g2g,
                                               const float* __restrict__ g2b,
                                               const float* __restrict__ gpg,
                                               const float* __restrict__ gpb,
                                               float* __restrict__ pfT) {      // [g][128]
    int t = threadIdx.x;
    int u = blockIdx.x * 256 + t;
    int s = u >> 3;
    int l8 = u & 7;
    unsigned int g = pidx2[s];
    int b = (int)(g >> 14);
    int c0 = l8 * 16;

    const short8* pfp = (const short8*)(pfb + (size_t)g * COUT + c0);
    short8 p0 = pfp[0], p1 = pfp[1];
    float a[16];
#pragma unroll
    for (int j = 0; j < 8; ++j) { a[j] = b2f((ushort)p0[j]); a[8 + j] = b2f((ushort)p1[j]); }

    int bg = b * 8 + l8;
    const float M2 = (float)(GSIZE * R3);
    const float Mp = (float)(GSIZE * NPTS);
    float s2 = gn2acc[bg * 2], ss2 = gn2acc[bg * 2 + 1];
    float mean2 = s2 / M2;
    float istd2 = rsqrtf(fmaxf(ss2 / M2 - mean2 * mean2, 0.f) + 1e-5f);
    float sp = gnpacc[bg * 2], ssp = gnpacc[bg * 2 + 1];
    float meanp = sp / Mp;
    float istdp = rsqrtf(fmaxf(ssp / Mp - meanp * meanp, 0.f) + 1e-5f);
    float ga[16], gb[16];
#pragma unroll
    for (int j = 0; j < 16; ++j) {
        float gm = g2g[c0 + j];
        ga[j] = istd2 * gm;
        gb[j] = g2b[c0 + j] - mean2 * istd2 * gm;
    }

    float4 c4 = nc4[g];
    const float CMAX = (float)(RES - 1) - 1e-6f;
    float cx = fminf(c4.x, CMAX), cy = fminf(c4.y, CMAX), cz = fminf(c4.z, CMAX);
    int ix0 = (int)cx, iy0 = (int)cy, iz0 = (int)cz;
    float fx = cx - ix0, fy = cy - iy0, fz = cz - iz0;
    int ix1 = min(ix0 + 1, RES - 1), iy1 = min(iy0 + 1, RES - 1), iz1 = min(iz0 + 1, RES - 1);
    float gx0 = 1.f - fx, gy0 = 1.f - fy, gz0 = 1.f - fz;
    float wc[8] = {gx0 * gy0 * gz0, gx0 * gy0 * fz, gx0 * fy * gz0, gx0 * fy * fz,
                   fx * gy0 * gz0,  fx * gy0 * fz,  fx * fy * gz0,  fx * fy * fz};
    int fi[8];
    fi[0] = (ix0 * RES + iy0) * RES + iz0; fi[1] = (ix0 * RES + iy0) * RES + iz1;
    fi[2] = (ix0 * RES + iy1) * RES + iz0; fi[3] = (ix0 * RES + iy1) * RES + iz1;
    fi[4] = (ix1 * RES + iy0) * RES + iz0; fi[5] = (ix1 * RES + iy0) * RES + iz1;
    fi[6] = (ix1 * RES + iy1) * RES + iz0; fi[7] = (ix1 * RES + iy1) * RES + iz1;

    const bf16* vb = vox + (size_t)b * R3 * COUT + c0;
    float accv[16] = {0.f, 0.f, 0.f, 0.f, 0.f, 0.f, 0.f, 0.f,
                      0.f, 0.f, 0.f, 0.f, 0.f, 0.f, 0.f, 0.f};
#pragma unroll
    for (int f = 0; f < 8; ++f) {
        const short8* vp = (const short8*)(vb + (size_t)fi[f] * COUT);
        short8 v0 = vp[0], v1 = vp[1];
        float wgt = wc[f];
#pragma unroll
        for (int j = 0; j < 8; ++j) {
            float yv = fmaf(b2f((ushort)v0[j]), ga[j], gb[j]);
            accv[j] = fmaf(wgt, yv / (1.f + __expf(-yv)), accv[j]);
        }
#pragma unroll
        for (int j = 0; j < 8; ++j) {
            float yv = fmaf(b2f((ushort)v1[j]), ga[8 + j], gb[8 + j]);
            accv[8 + j] = fmaf(wgt, yv / (1.f + __expf(-yv)), accv[8 + j]);
        }
    }

    float outv[16];
#pragma unroll
    for (int j = 0; j < 16; ++j) {
        float pm = gpg[c0 + j];
        float yv = fmaf((a[j] - meanp) * istdp, pm, gpb[c0 + j]);
        outv[j] = yv / (1.f + __expf(-yv)) + accv[j];
    }
    float* pp = pfT + (size_t)g * COUT + c0;
#pragma unroll
    for (int k = 0; k < 4; ++k)
        *(float4*)(pp + k * 4) = make_float4(outv[k*4], outv[k*4+1], outv[k*4+2], outv[k*4+3]);
}

// ---------------- transpose pfT [b][n][128] -> out [b][128][n] ----------------
__global__ __launch_bounds__(256) void transpose_out_k(const float* __restrict__ pfT,
                                                       float* __restrict__ out) {
    int blk = blockIdx.x;
    int b = blk >> 8, nt = blk & 255;
    int t = threadIdx.x;
    int n0 = nt * 64;
    __shared__ float lds[64][129];
#pragma unroll
    for (int k = 0; k < 8; ++k) {
        int e = t + k * 256;
        int row = e >> 5, c4 = e & 31;
        float4 v = ((const float4*)pfT)[(((size_t)b << 14) + n0 + row) * 32 + c4];
        lds[row][c4 * 4 + 0] = v.x;
        lds[row][c4 * 4 + 1] = v.y;
        lds[row][c4 * 4 + 2] = v.z;
        lds[row][c4 * 4 + 3] = v.w;
    }
    __syncthreads();
#pragma unroll
    for (int k = 0; k < 32; ++k) {
        int e = t + k * 256;
        int c = e >> 6, n = e & 63;
        out[((size_t)b * COUT + c) * NPTS + n0 + n] = lds[n][c];
    }
}

extern "C" void kernel_launch(void* const* d_in, const int* in_sizes, int n_in,
                              void* d_out, int out_size, void* d_ws, size_t ws_size,
                              hipStream_t stream) {
    const float* features = (const float*)d_in[0];
    const float* coords   = (const float*)d_in[1];
    const float* w1  = (const float*)d_in[3];
    const float* b1  = (const float*)d_in[4];
    const float* g1g = (const float*)d_in[5];
    const float* g1b = (const float*)d_in[6];
    const float* w2  = (const float*)d_in[7];
    const float* b2  = (const float*)d_in[8];
    const float* g2g = (const float*)d_in[9];
    const float* g2b = (const float*)d_in[10];
    const float* wp  = (const float*)d_in[11];
    const float* bp  = (const float*)d_in[12];
    const float* gpg = (const float*)d_in[13];
    const float* gpb = (const float*)d_in[14];
    float* out = (float*)d_out;

    // ws (~183 MB):
    //   [0,64MB)     act1 bf16 -> pfT fp32 (overlay; act1 dead after conv2)
    //   [64,128MB)   act2 bf16 (live until fuse2)
    //   [128,160MB)  voxCL bf16 -> pfb bf16 (overlay; voxCL dead after conv1)
    //   [160,176MB)  featTb bf16 (live until pgemm)
    //   tail: w1f, w2f, wpb, nc4, cnts, offs, vidx, slot, pidx2, part, stats
    char* ws = (char*)d_ws;
    size_t off = 0;
    bf16* act1 = (bf16*)(ws + off);
    float* pfT = (float*)(ws + off);         off += (size_t)BATCH * R3 * COUT * 2;  // 64MB
    bf16* act2 = (bf16*)(ws + off);          off += (size_t)BATCH * R3 * COUT * 2;  // 64MB
    bf16* voxCL = (bf16*)(ws + off);
    bf16* pfb = (bf16*)(ws + off);           off += (size_t)BATCH * R3 * CIN * 2;   // 32MB
    bf16* featTb = (bf16*)(ws + off);        off += (size_t)BATCH * NPTS * CIN * 2; // 16MB
    bf16* w1f = (bf16*)(ws + off);           off += (size_t)27 * 2 * 128 * 32 * 2;
    bf16* w2f = (bf16*)(ws + off);           off += (size_t)27 * 4 * 128 * 32 * 2;
    bf16* wpb = (bf16*)(ws + off);           off += (size_t)2 * 128 * 32 * 2;       // 16KB
    float4* nc4 = (float4*)(ws + off);       off += (size_t)BATCH * NPTS * 16;
    unsigned int* cnts = (unsigned int*)(ws + off);  off += (size_t)BATCH * R3 * 4;
    unsigned int* offs = (unsigned int*)(ws + off);  off += (size_t)BATCH * R3 * 4;
    int* vidx = (int*)(ws + off);            off += (size_t)BATCH * NPTS * 4;
    int* slot = (int*)(ws + off);            off += (size_t)BATCH * NPTS * 4;
    unsigned int* pidx2 = (unsigned int*)(ws + off); off += (size_t)BATCH * NPTS * 4;
    unsigned int* part = (unsigned int*)(ws + off);  off += 4096;
    float* bstats = (float*)(ws + off);      off += 256;
    float* gn1acc = (float*)(ws + off);      off += 512;
    float* gn2acc = (float*)(ws + off);      off += 512;
    float* gnpacc = (float*)(ws + off);      off += 512;

    hipMemsetAsync(cnts, 0, (size_t)BATCH * R3 * 4, stream);
    hipMemsetAsync(gn1acc, 0, 3 * 512, stream);

    coord_stats_k<<<BATCH, 256, 0, stream>>>(coords, bstats);
    vox_idx_k<<<BATCH * NPTS / 256, 256, 0, stream>>>(coords, bstats, nc4, vidx, slot, cnts);
    transpose_feats_k<<<BATCH * 256, 256, 0, stream>>>(features, featTb);
    scan1_k<<<BATCH * R3 / 256, 256, 0, stream>>>(cnts, offs, part);
    scan2_k<<<1, 1024, 0, stream>>>(part);
    scan3_k<<<BATCH * R3 / 256, 256, 0, stream>>>(offs, part);
    scatter_pts_k<<<BATCH * NPTS / 256, 256, 0, stream>>>(vidx, slot, offs, pidx2);
    gather_k<<<BATCH * R3 * 8 / 256, 256, 0, stream>>>(featTb, cnts, offs, pidx2, voxCL);

    wreorder_k<CIN><<<(27 * 2 * 128 * 4 + 255) / 256, 256, 0, stream>>>(w1, w1f);
    wreorder_k<COUT><<<(27 * 4 * 128 * 4 + 255) / 256, 256, 0, stream>>>(w2, w2f);
    wpreorder_k<<<4, 256, 0, stream>>>(wp, wpb);

    conv3d_mfma_k<CIN><<<BATCH * 32 * 8, 512, 0, stream>>>(voxCL, w1f, b1, act1, gn1acc);
    gn_apply_cl_k<<<BATCH * R3 * 16 / 256, 256, 0, stream>>>(act1, gn1acc, g1g, g1b);

    conv3d_mfma_k<COUT><<<BATCH * 32 * 8, 512, 0, stream>>>(act1, w2f, b2, act2, gn2acc);

    // pfb overlays voxCL (dead after conv1); launched after conv2 for safety
    pgemm_mfma_k<<<BATCH * NPTS / 64, 256, 0, stream>>>(featTb, wpb, bp, pfb, gnpacc);

    fuse2_k<<<BATCH * NPTS * 8 / 256, 256, 0, stream>>>(act2, pfb, nc4, pidx2,
                                                        gn2acc, gnpacc, g2g, g2b, gpg, gpb, pfT);

    transpose_out_k<<<BATCH * 256, 256, 0, stream>>>(pfT, out);
}

// Round 16
// 633.541 us; speedup vs baseline: 2.3973x; 1.0169x over previous
//
#include <hip/hip_runtime.h>
#include <hip/hip_bf16.h>
#include <cmath>

#define BATCH 8
#define CIN 64
#define COUT 128
#define NPTS 16384
#define RES 32
#define R3 32768
#define NGROUP 8
#define GSIZE 16

typedef __hip_bfloat16 bf16;
typedef __attribute__((ext_vector_type(8))) short short8;
typedef __attribute__((ext_vector_type(4))) float f32x4;

__device__ inline float b2f(ushort u) { union { float f; uint v; } x; x.v = ((uint)u) << 16; return x.f; }
__device__ inline ushort f2bu(float f) { __hip_bfloat16 h = __float2bfloat16(f); return *reinterpret_cast<ushort*>(&h); }

// ---------------- coord stats ----------------
__global__ __launch_bounds__(256) void coord_stats_k(const float* __restrict__ coords,
                                                     float* __restrict__ bstats) {
    int b = blockIdx.x;
    int t = threadIdx.x;
    __shared__ float red[256];
    __shared__ float means[3];
    for (int c = 0; c < 3; ++c) {
        float acc = 0.f;
        const float* p = coords + ((size_t)b * 3 + c) * NPTS;
        for (int n = t; n < NPTS; n += 256) acc += p[n];
        red[t] = acc; __syncthreads();
        for (int s = 128; s > 0; s >>= 1) { if (t < s) red[t] += red[t + s]; __syncthreads(); }
        if (t == 0) means[c] = red[0] * (1.f / NPTS);
        __syncthreads();
    }
    float m0 = means[0], m1 = means[1], m2 = means[2];
    const float* px = coords + ((size_t)b * 3 + 0) * NPTS;
    const float* py = coords + ((size_t)b * 3 + 1) * NPTS;
    const float* pz = coords + ((size_t)b * 3 + 2) * NPTS;
    float mx = 0.f;
    for (int n = t; n < NPTS; n += 256) {
        float dx = px[n] - m0, dy = py[n] - m1, dz = pz[n] - m2;
        mx = fmaxf(mx, sqrtf(dx * dx + dy * dy + dz * dz));
    }
    red[t] = mx; __syncthreads();
    for (int s = 128; s > 0; s >>= 1) { if (t < s) red[t] = fmaxf(red[t], red[t + s]); __syncthreads(); }
    if (t == 0) {
        bstats[b * 4 + 0] = m0; bstats[b * 4 + 1] = m1; bstats[b * 4 + 2] = m2;
        bstats[b * 4 + 3] = 1.f / (2.f * red[0]);
    }
}

// ---------------- per-point voxel index + nc4 + count ----------------
__global__ __launch_bounds__(256) void vox_idx_k(const float* __restrict__ coords,
                                                 const float* __restrict__ bstats,
                                                 float4* __restrict__ nc4,
                                                 int* __restrict__ vidx,
                                                 int* __restrict__ slot,
                                                 unsigned int* __restrict__ cnts) {
    int g = blockIdx.x * 256 + threadIdx.x;
    int b = g >> 14, n = g & (NPTS - 1);
    float m0 = bstats[b * 4 + 0], m1 = bstats[b * 4 + 1], m2 = bstats[b * 4 + 2];
    float sc = bstats[b * 4 + 3];
    float x = coords[((size_t)b * 3 + 0) * NPTS + n];
    float y = coords[((size_t)b * 3 + 1) * NPTS + n];
    float z = coords[((size_t)b * 3 + 2) * NPTS + n];
    float ncx = fminf(fmaxf(((x - m0) * sc + 0.5f) * (float)RES, 0.f), RES - 1.f);
    float ncy = fminf(fmaxf(((y - m1) * sc + 0.5f) * (float)RES, 0.f), RES - 1.f);
    float ncz = fminf(fmaxf(((z - m2) * sc + 0.5f) * (float)RES, 0.f), RES - 1.f);
    nc4[g] = make_float4(ncx, ncy, ncz, 0.f);
    int ix = min(max((int)rintf(ncx), 0), RES - 1);  // rintf = half-even = jnp.round
    int iy = min(max((int)rintf(ncy), 0), RES - 1);
    int iz = min(max((int)rintf(ncz), 0), RES - 1);
    int v = b * R3 + (ix * RES + iy) * RES + iz;
    vidx[g] = v;
    slot[g] = (int)atomicAdd(&cnts[v], 1u);
}

// ---------------- feature transpose: [b][64][N] fp32 -> [g][64] bf16 ----------------
__global__ __launch_bounds__(256) void transpose_feats_k(const float* __restrict__ feats,
                                                         bf16* __restrict__ featTb) {
    int blk = blockIdx.x;
    int b = blk >> 8, ntile = blk & 255;
    int t = threadIdx.x;
    __shared__ float lds[64][65];
    for (int e = t; e < 64 * 64; e += 256) {
        int c = e >> 6, n = e & 63;
        lds[c][n] = feats[((size_t)b * CIN + c) * NPTS + ntile * 64 + n];
    }
    __syncthreads();
    for (int e = t; e < 64 * 8; e += 256) {   // 512: (n, ci-octet)
        int n = e >> 3, oct = e & 7;
        ushort o[8];
#pragma unroll
        for (int j = 0; j < 8; ++j) o[j] = f2bu(lds[oct * 8 + j][n]);
        *(short8*)(featTb + ((((size_t)b << 14) + ntile * 64 + n) * CIN) + oct * 8) = *(short8*)o;
    }
}

// ---------------- scan ----------------
__global__ __launch_bounds__(256) void scan1_k(const unsigned int* __restrict__ cnts,
                                               unsigned int* __restrict__ offs,
                                               unsigned int* __restrict__ part) {
    int t = threadIdx.x;
    int g = blockIdx.x * 256 + t;
    unsigned int v = cnts[g];
    __shared__ unsigned int s[256];
    s[t] = v; __syncthreads();
    for (int d = 1; d < 256; d <<= 1) {
        unsigned int x = (t >= d) ? s[t - d] : 0u;
        __syncthreads();
        s[t] += x;
        __syncthreads();
    }
    offs[g] = s[t] - v;
    if (t == 255) part[blockIdx.x] = s[255];
}

__global__ __launch_bounds__(1024) void scan2_k(unsigned int* __restrict__ part) {
    int t = threadIdx.x;
    unsigned int v = part[t];
    __shared__ unsigned int s[1024];
    s[t] = v; __syncthreads();
    for (int d = 1; d < 1024; d <<= 1) {
        unsigned int x = (t >= d) ? s[t - d] : 0u;
        __syncthreads();
        s[t] += x;
        __syncthreads();
    }
    part[t] = s[t] - v;
}

__global__ __launch_bounds__(256) void scan3_k(unsigned int* __restrict__ offs,
                                               const unsigned int* __restrict__ part) {
    int g = blockIdx.x * 256 + threadIdx.x;
    offs[g] += part[blockIdx.x];
}

// ---------------- scatter global point id into CSR ----------------
__global__ __launch_bounds__(256) void scatter_pts_k(const int* __restrict__ vidx,
                                                     const int* __restrict__ slot,
                                                     const unsigned int* __restrict__ offs,
                                                     unsigned int* __restrict__ pidx2) {
    int g = blockIdx.x * 256 + threadIdx.x;
    int v = vidx[g];
    pidx2[offs[v] + slot[g]] = (unsigned int)g;
}

// ---------------- gather: CSR mean -> bf16 channel-last vox ----------------
__global__ __launch_bounds__(256) void gather_k(const bf16* __restrict__ featTb,
                                                const unsigned int* __restrict__ cnts,
                                                const unsigned int* __restrict__ offs,
                                                const unsigned int* __restrict__ pidx2,
                                                bf16* __restrict__ voxCL) {
    int u = blockIdx.x * 256 + threadIdx.x;
    int v = u >> 3;
    int l8 = u & 7;
    unsigned int cnt = cnts[v];
    unsigned int off = offs[v];
    float acc[8] = {0.f, 0.f, 0.f, 0.f, 0.f, 0.f, 0.f, 0.f};
    for (unsigned int i = 0; i < cnt; ++i) {
        unsigned int g = pidx2[off + i];
        short8 f = *(const short8*)(featTb + (size_t)g * CIN + l8 * 8);
#pragma unroll
        for (int j = 0; j < 8; ++j) acc[j] += b2f((ushort)f[j]);
    }
    float inv = 1.f / fmaxf((float)cnt, 1.f);
    ushort o[8];
#pragma unroll
    for (int j = 0; j < 8; ++j) o[j] = f2bu(acc[j] * inv);
    *(short8*)(voxCL + (size_t)v * CIN + l8 * 8) = *(short8*)o;
}

// ---------------- weight reorder: [co][ci][27] fp32 -> [t][c32][co][kb][8] bf16 ----------------
template <int CIN_T>
__global__ __launch_bounds__(256) void wreorder_k(const float* __restrict__ w,
                                                  bf16* __restrict__ wf) {
    const int NC = CIN_T / 32;
    int u = blockIdx.x * 256 + threadIdx.x;
    if (u >= 27 * NC * 128 * 4) return;
    int kb = u & 3;
    int co = (u >> 2) & 127;
    int c32 = (u >> 9) % NC;
    int t = u / (512 * NC);
    int cibase = c32 * 32 + kb * 8;
    ushort o[8];
#pragma unroll
    for (int j = 0; j < 8; ++j)
        o[j] = f2bu(w[((size_t)co * CIN_T + cibase + j) * 27 + t]);
    *(short8*)(wf + (size_t)u * 8) = *(short8*)o;
}

// ---------------- wp reorder: [co][64] fp32 -> [c32][co][kb][8] bf16 (MFMA A-frag order) ----------------
__global__ __launch_bounds__(256) void wpreorder_k(const float* __restrict__ wp,
                                                   bf16* __restrict__ wpb) {
    int u = blockIdx.x * 256 + threadIdx.x;  // 2*128*4 = 1024
    if (u >= 1024) return;
    int kb = u & 3;
    int co = (u >> 2) & 127;
    int c32 = u >> 9;
    ushort o[8];
#pragma unroll
    for (int j = 0; j < 8; ++j)
        o[j] = f2bu(wp[(size_t)co * CIN + c32 * 32 + kb * 8 + j]);
    *(short8*)(wpb + (size_t)u * 8) = *(short8*)o;
}

// ---------------- implicit-GEMM conv3d 3x3x3 via MFMA bf16 (R6/R13-proven, EXACT) ----------------
// block 512 = 8 waves (4 cog x 2 sg); 80B pos stride; 49KB LDS -> 3 blocks/CU.
// Measured: conv2 272us @ MfmaUtil 38% / occ 60%. Mapping/bounds/staging untouched.
template <int CIN_T>
__global__ __launch_bounds__(512, 2) void conv3d_mfma_k(const bf16* __restrict__ x,  // [b][p][CIN_T]
                                                        const bf16* __restrict__ wf, // [27][NC][128][4][8]
                                                        const float* __restrict__ bias,
                                                        bf16* __restrict__ y,        // [b][p][128]
                                                        float* __restrict__ gnacc) { // [64][2]
    constexpr int NC = CIN_T / 32;
    int blk = blockIdx.x;
    int hq = blk & 7;
    int d = (blk >> 3) & 31;
    int b = blk >> 8;
    int t = threadIdx.x;
    int lane = t & 63;
    int wid = t >> 6;
    int cog = wid >> 1;  // 0..3
    int sg = wid & 1;    // 0..1
    int lr = lane & 15;
    int kb = lane >> 4;

    __shared__ __align__(16) char xs[3 * 6 * 34 * 80];  // 48960 B
    __shared__ float gred[8][2];
    if (t < 16) gred[t >> 1][t & 1] = 0.f;

    f32x4 acc[2][4];
#pragma unroll
    for (int r = 0; r < 2; ++r)
#pragma unroll
        for (int j = 0; j < 4; ++j) acc[r][j] = (f32x4){0.f, 0.f, 0.f, 0.f};

    int bbase[4];
#pragma unroll
    for (int j = 0; j < 4; ++j) {
        int sp = sg * 64 + j * 16 + lr;
        int hl = sp >> 5, wl = sp & 31;
        bbase[j] = (hl * 34 + wl) * 80 + kb * 16;
    }

    for (int cc = 0; cc < NC; ++cc) {
        __syncthreads();
        for (int e = t; e < 612 * 4; e += 512) {
            int ekb = e & 3;
            int pos = e >> 2;
            int ww = pos % 34;
            int hh = (pos / 34) % 6;
            int dd = pos / 204;
            int dz = d + dd - 1;
            int hz = hq * 4 + hh - 1;
            int wz = ww - 1;
            short8 v = {0, 0, 0, 0, 0, 0, 0, 0};
            if (dz >= 0 && dz < RES && hz >= 0 && hz < RES && wz >= 0 && wz < RES)
                v = *(const short8*)(x + ((size_t)b * R3 + dz * 1024 + hz * 32 + wz) * CIN_T + cc * 32 + ekb * 8);
            *(short8*)(xs + pos * 80 + ekb * 16) = v;
        }
        __syncthreads();

        const short8* wfp = (const short8*)wf;
        size_t abase = ((size_t)cc * 128 + cog * 32 + lr) * 4 + kb;
#pragma unroll
        for (int dd = 0; dd < 3; ++dd)
#pragma unroll
            for (int dh = 0; dh < 3; ++dh)
#pragma unroll
                for (int dw = 0; dw < 3; ++dw) {
                    int tap = (dd * 3 + dh) * 3 + dw;
                    short8 a0 = wfp[abase + (size_t)tap * NC * 512];
                    short8 a1 = wfp[abase + (size_t)tap * NC * 512 + 64];
                    int toff = ((dd * 6 + dh) * 34 + dw) * 80;
                    short8 bb[4];
#pragma unroll
                    for (int j = 0; j < 4; ++j)
                        bb[j] = *(const short8*)(xs + bbase[j] + toff);
#pragma unroll
                    for (int j = 0; j < 4; ++j) {
                        acc[0][j] = __builtin_amdgcn_mfma_f32_16x16x32_bf16(a0, bb[j], acc[0][j], 0, 0, 0);
                        acc[1][j] = __builtin_amdgcn_mfma_f32_16x16x32_bf16(a1, bb[j], acc[1][j], 0, 0, 0);
                    }
                }
    }

    // epilogue: store bf16 + GN partial stats (group = cog*2 + r)
    float sred[2], ssred[2];
#pragma unroll
    for (int r = 0; r < 2; ++r) {
        int co = cog * 32 + r * 16 + kb * 4;
        float4 bv = *(const float4*)(bias + co);
        float s = 0.f, ss = 0.f;
#pragma unroll
        for (int j = 0; j < 4; ++j) {
            int sp = sg * 64 + j * 16 + lr;
            int p = d * 1024 + (hq * 4 + (sp >> 5)) * 32 + (sp & 31);
            float v0 = acc[r][j][0] + bv.x;
            float v1 = acc[r][j][1] + bv.y;
            float v2 = acc[r][j][2] + bv.z;
            float v3 = acc[r][j][3] + bv.w;
            ushort4 o;
            o.x = f2bu(v0); o.y = f2bu(v1); o.z = f2bu(v2); o.w = f2bu(v3);
            *(ushort4*)(y + ((size_t)b * R3 + p) * COUT + co) = o;
            s += v0 + v1 + v2 + v3;
            ss += v0 * v0 + v1 * v1 + v2 * v2 + v3 * v3;
        }
        sred[r] = s; ssred[r] = ss;
    }
#pragma unroll
    for (int m = 1; m < 64; m <<= 1) {
#pragma unroll
        for (int r = 0; r < 2; ++r) {
            sred[r] += __shfl_xor(sred[r], m, 64);
            ssred[r] += __shfl_xor(ssred[r], m, 64);
        }
    }
    if (lane == 0) {
#pragma unroll
        for (int r = 0; r < 2; ++r) {
            atomicAdd(&gred[cog * 2 + r][0], sred[r]);
            atomicAdd(&gred[cog * 2 + r][1], ssred[r]);
        }
    }
    __syncthreads();
    if (t < 16) atomicAdd(&gnacc[(b * 8 + (t >> 1)) * 2 + (t & 1)], gred[t >> 1][t & 1]);
}

// ---------------- GN apply + swish (act1, between convs) ----------------
__global__ __launch_bounds__(256) void gn_apply_cl_k(bf16* __restrict__ x,
                                                     const float* __restrict__ gnacc,
                                                     const float* __restrict__ gamma,
                                                     const float* __restrict__ beta) {
    int u = blockIdx.x * 256 + threadIdx.x;
    int ci8 = u & 15;
    int p = (u >> 4) & (R3 - 1);
    int b = u >> 19;
    int ci = ci8 * 8;
    int bg = b * 8 + (ci8 >> 1);
    const float M = (float)(GSIZE * R3);
    float s = gnacc[bg * 2], ss = gnacc[bg * 2 + 1];
    float mean = s / M;
    float istd = rsqrtf(fmaxf(ss / M - mean * mean, 0.f) + 1e-5f);
    bf16* ptr = x + ((size_t)b * R3 + p) * COUT + ci;
    short8 v = *(const short8*)ptr;
    ushort o[8];
#pragma unroll
    for (int j = 0; j < 8; ++j) {
        float f = b2f((ushort)v[j]);
        float yv = fmaf((f - mean) * istd, gamma[ci + j], beta[ci + j]);
        o[j] = f2bu(yv / (1.f + __expf(-yv)));
    }
    *(short8*)ptr = *(short8*)o;
}

// ---------------- point-branch GEMM via MFMA: pf bf16 + GN stats ----------------
__global__ __launch_bounds__(256) void pgemm_mfma_k(const bf16* __restrict__ featTb, // [g][64]
                                                    const bf16* __restrict__ wpb,    // [2][128][4][8]
                                                    const float* __restrict__ bp,
                                                    bf16* __restrict__ pfb,          // [g][128]
                                                    float* __restrict__ gnacc) {     // [64][2]
    int t = threadIdx.x;
    int lane = t & 63;
    int cog = t >> 6;       // 0..3
    int lr = lane & 15;
    int kb = lane >> 4;
    int g0 = blockIdx.x * 64;
    int b = g0 >> 14;

    __shared__ float gred[8][2];
    if (t < 16) gred[t >> 1][t & 1] = 0.f;
    __syncthreads();   // ensure gred init visible before any wave's atomicAdd

    f32x4 acc[2][4];
#pragma unroll
    for (int r = 0; r < 2; ++r)
#pragma unroll
        for (int j = 0; j < 4; ++j) acc[r][j] = (f32x4){0.f, 0.f, 0.f, 0.f};

    const short8* wfp = (const short8*)wpb;
    const short8* ftp = (const short8*)featTb;  // [g][8 octets]
#pragma unroll
    for (int cc = 0; cc < 2; ++cc) {
        size_t abase = ((size_t)cc * 128 + cog * 32 + lr) * 4 + kb;
        short8 a0 = wfp[abase];
        short8 a1 = wfp[abase + 64];
#pragma unroll
        for (int j = 0; j < 4; ++j) {
            short8 bb = ftp[(size_t)(g0 + j * 16 + lr) * 8 + cc * 4 + kb];
            acc[0][j] = __builtin_amdgcn_mfma_f32_16x16x32_bf16(a0, bb, acc[0][j], 0, 0, 0);
            acc[1][j] = __builtin_amdgcn_mfma_f32_16x16x32_bf16(a1, bb, acc[1][j], 0, 0, 0);
        }
    }

    float sred[2], ssred[2];
#pragma unroll
    for (int r = 0; r < 2; ++r) {
        int co = cog * 32 + r * 16 + kb * 4;
        float4 bv = *(const float4*)(bp + co);
        float s = 0.f, ss = 0.f;
#pragma unroll
        for (int j = 0; j < 4; ++j) {
            int g = g0 + j * 16 + lr;
            float v0 = acc[r][j][0] + bv.x;
            float v1 = acc[r][j][1] + bv.y;
            float v2 = acc[r][j][2] + bv.z;
            float v3 = acc[r][j][3] + bv.w;
            ushort4 o;
            o.x = f2bu(v0); o.y = f2bu(v1); o.z = f2bu(v2); o.w = f2bu(v3);
            *(ushort4*)(pfb + (size_t)g * COUT + co) = o;
            s += v0 + v1 + v2 + v3;
            ss += v0 * v0 + v1 * v1 + v2 * v2 + v3 * v3;
        }
        sred[r] = s; ssred[r] = ss;
    }
#pragma unroll
    for (int m = 1; m < 64; m <<= 1) {
#pragma unroll
        for (int r = 0; r < 2; ++r) {
            sred[r] += __shfl_xor(sred[r], m, 64);
            ssred[r] += __shfl_xor(ssred[r], m, 64);
        }
    }
    if (lane == 0) {
#pragma unroll
        for (int r = 0; r < 2; ++r) {
            atomicAdd(&gred[cog * 2 + r][0], sred[r]);
            atomicAdd(&gred[cog * 2 + r][1], ssred[r]);
        }
    }
    __syncthreads();
    if (t < 16) atomicAdd(&gnacc[(b * 8 + (t >> 1)) * 2 + (t & 1)], gred[t >> 1][t & 1]);
}

// ---------------- fuse2: 8 lanes/point; load pf + GN + swish + devox + add; bf16 IN PLACE ----------------
// Safe in place: pidx2 is a bijection over g; each (g, 16-ch slice) is read+written
// by exactly one thread; pgemm fully rewrites pfb each call (replay-deterministic).
__global__ __launch_bounds__(256) void fuse2_k(const bf16* __restrict__ vox,   // act2 [b][p][128]
                                               bf16* __restrict__ pfb,         // [g][128] in/out
                                               const float4* __restrict__ nc4,
                                               const unsigned int* __restrict__ pidx2,
                                               const float* __restrict__ gn2acc,
                                               const float* __restrict__ gnpacc,
                                               const float* __restrict__ g2g,
                                               const float* __restrict__ g2b,
                                               const float* __restrict__ gpg,
                                               const float* __restrict__ gpb) {
    int t = threadIdx.x;
    int u = blockIdx.x * 256 + t;
    int s = u >> 3;
    int l8 = u & 7;
    unsigned int g = pidx2[s];
    int b = (int)(g >> 14);
    int c0 = l8 * 16;

    const short8* pfp = (const short8*)(pfb + (size_t)g * COUT + c0);
    short8 p0 = pfp[0], p1 = pfp[1];
    float a[16];
#pragma unroll
    for (int j = 0; j < 8; ++j) { a[j] = b2f((ushort)p0[j]); a[8 + j] = b2f((ushort)p1[j]); }

    int bg = b * 8 + l8;
    const float M2 = (float)(GSIZE * R3);
    const float Mp = (float)(GSIZE * NPTS);
    float s2 = gn2acc[bg * 2], ss2 = gn2acc[bg * 2 + 1];
    float mean2 = s2 / M2;
    float istd2 = rsqrtf(fmaxf(ss2 / M2 - mean2 * mean2, 0.f) + 1e-5f);
    float sp = gnpacc[bg * 2], ssp = gnpacc[bg * 2 + 1];
    float meanp = sp / Mp;
    float istdp = rsqrtf(fmaxf(ssp / Mp - meanp * meanp, 0.f) + 1e-5f);
    float ga[16], gb[16];
#pragma unroll
    for (int j = 0; j < 16; ++j) {
        float gm = g2g[c0 + j];
        ga[j] = istd2 * gm;
        gb[j] = g2b[c0 + j] - mean2 * istd2 * gm;
    }

    float4 c4 = nc4[g];
    const float CMAX = (float)(RES - 1) - 1e-6f;
    float cx = fminf(c4.x, CMAX), cy = fminf(c4.y, CMAX), cz = fminf(c4.z, CMAX);
    int ix0 = (int)cx, iy0 = (int)cy, iz0 = (int)cz;
    float fx = cx - ix0, fy = cy - iy0, fz = cz - iz0;
    int ix1 = min(ix0 + 1, RES - 1), iy1 = min(iy0 + 1, RES - 1), iz1 = min(iz0 + 1, RES - 1);
    float gx0 = 1.f - fx, gy0 = 1.f - fy, gz0 = 1.f - fz;
    float wc[8] = {gx0 * gy0 * gz0, gx0 * gy0 * fz, gx0 * fy * gz0, gx0 * fy * fz,
                   fx * gy0 * gz0,  fx * gy0 * fz,  fx * fy * gz0,  fx * fy * fz};
    int fi[8];
    fi[0] = (ix0 * RES + iy0) * RES + iz0; fi[1] = (ix0 * RES + iy0) * RES + iz1;
    fi[2] = (ix0 * RES + iy1) * RES + iz0; fi[3] = (ix0 * RES + iy1) * RES + iz1;
    fi[4] = (ix1 * RES + iy0) * RES + iz0; fi[5] = (ix1 * RES + iy0) * RES + iz1;
    fi[6] = (ix1 * RES + iy1) * RES + iz0; fi[7] = (ix1 * RES + iy1) * RES + iz1;

    const bf16* vb = vox + (size_t)b * R3 * COUT + c0;
    float accv[16] = {0.f, 0.f, 0.f, 0.f, 0.f, 0.f, 0.f, 0.f,
                      0.f, 0.f, 0.f, 0.f, 0.f, 0.f, 0.f, 0.f};
#pragma unroll
    for (int f = 0; f < 8; ++f) {
        const short8* vp = (const short8*)(vb + (size_t)fi[f] * COUT);
        short8 v0 = vp[0], v1 = vp[1];
        float wgt = wc[f];
#pragma unroll
        for (int j = 0; j < 8; ++j) {
            float yv = fmaf(b2f((ushort)v0[j]), ga[j], gb[j]);
            accv[j] = fmaf(wgt, yv / (1.f + __expf(-yv)), accv[j]);
        }
#pragma unroll
        for (int j = 0; j < 8; ++j) {
            float yv = fmaf(b2f((ushort)v1[j]), ga[8 + j], gb[8 + j]);
            accv[8 + j] = fmaf(wgt, yv / (1.f + __expf(-yv)), accv[8 + j]);
        }
    }

    ushort outv[16];
#pragma unroll
    for (int j = 0; j < 16; ++j) {
        float pm = gpg[c0 + j];
        float yv = fmaf((a[j] - meanp) * istdp, pm, gpb[c0 + j]);
        outv[j] = f2bu(yv / (1.f + __expf(-yv)) + accv[j]);
    }
    bf16* pp = pfb + (size_t)g * COUT + c0;
    *(short8*)(pp) = *(short8*)(outv);
    *(short8*)(pp + 8) = *(short8*)(outv + 8);
}

// ---------------- transpose pfb bf16 [b][n][128] -> out fp32 [b][128][n] ----------------
__global__ __launch_bounds__(256) void transpose_out_k(const bf16* __restrict__ pfb,
                                                       float* __restrict__ out) {
    int blk = blockIdx.x;
    int b = blk >> 8, nt = blk & 255;
    int t = threadIdx.x;
    int n0 = nt * 64;
    __shared__ float lds[64][129];
#pragma unroll
    for (int k = 0; k < 4; ++k) {
        int e = t + k * 256;          // 1024 short8 loads: 64 rows x 16 octets (full 128 ch)
        int row = e >> 4, oct = e & 15;
        short8 v = *(const short8*)(pfb + (((size_t)b << 14) + n0 + row) * COUT + oct * 8);
#pragma unroll
        for (int j = 0; j < 8; ++j) lds[row][oct * 8 + j] = b2f((ushort)v[j]);
    }
    __syncthreads();
#pragma unroll
    for (int k = 0; k < 32; ++k) {
        int e = t + k * 256;
        int c = e >> 6, n = e & 63;
        out[((size_t)b * COUT + c) * NPTS + n0 + n] = lds[n][c];
    }
}

extern "C" void kernel_launch(void* const* d_in, const int* in_sizes, int n_in,
                              void* d_out, int out_size, void* d_ws, size_t ws_size,
                              hipStream_t stream) {
    const float* features = (const float*)d_in[0];
    const float* coords   = (const float*)d_in[1];
    const float* w1  = (const float*)d_in[3];
    const float* b1  = (const float*)d_in[4];
    const float* g1g = (const float*)d_in[5];
    const float* g1b = (const float*)d_in[6];
    const float* w2  = (const float*)d_in[7];
    const float* b2  = (const float*)d_in[8];
    const float* g2g = (const float*)d_in[9];
    const float* g2b = (const float*)d_in[10];
    const float* wp  = (const float*)d_in[11];
    const float* bp  = (const float*)d_in[12];
    const float* gpg = (const float*)d_in[13];
    const float* gpb = (const float*)d_in[14];
    float* out = (float*)d_out;

    // ws (~183 MB):
    //   [0,64MB)     act1 bf16 (dead after conv2)
    //   [64,128MB)   act2 bf16 (live until fuse2)
    //   [128,160MB)  voxCL bf16 -> pfb bf16 (overlay; voxCL dead after conv1)
    //   [160,176MB)  featTb bf16 (live until pgemm)
    //   tail: w1f, w2f, wpb, nc4, cnts, offs, vidx, slot, pidx2, part, stats
    char* ws = (char*)d_ws;
    size_t off = 0;
    bf16* act1 = (bf16*)(ws + off);          off += (size_t)BATCH * R3 * COUT * 2;  // 64MB
    bf16* act2 = (bf16*)(ws + off);          off += (size_t)BATCH * R3 * COUT * 2;  // 64MB
    bf16* voxCL = (bf16*)(ws + off);
    bf16* pfb = (bf16*)(ws + off);           off += (size_t)BATCH * R3 * CIN * 2;   // 32MB
    bf16* featTb = (bf16*)(ws + off);        off += (size_t)BATCH * NPTS * CIN * 2; // 16MB
    bf16* w1f = (bf16*)(ws + off);           off += (size_t)27 * 2 * 128 * 32 * 2;
    bf16* w2f = (bf16*)(ws + off);           off += (size_t)27 * 4 * 128 * 32 * 2;
    bf16* wpb = (bf16*)(ws + off);           off += (size_t)2 * 128 * 32 * 2;       // 16KB
    float4* nc4 = (float4*)(ws + off);       off += (size_t)BATCH * NPTS * 16;
    unsigned int* cnts = (unsigned int*)(ws + off);  off += (size_t)BATCH * R3 * 4;
    unsigned int* offs = (unsigned int*)(ws + off);  off += (size_t)BATCH * R3 * 4;
    int* vidx = (int*)(ws + off);            off += (size_t)BATCH * NPTS * 4;
    int* slot = (int*)(ws + off);            off += (size_t)BATCH * NPTS * 4;
    unsigned int* pidx2 = (unsigned int*)(ws + off); off += (size_t)BATCH * NPTS * 4;
    unsigned int* part = (unsigned int*)(ws + off);  off += 4096;
    float* bstats = (float*)(ws + off);      off += 256;
    float* gn1acc = (float*)(ws + off);      off += 512;
    float* gn2acc = (float*)(ws + off);      off += 512;
    float* gnpacc = (float*)(ws + off);      off += 512;

    hipMemsetAsync(cnts, 0, (size_t)BATCH * R3 * 4, stream);
    hipMemsetAsync(gn1acc, 0, 3 * 512, stream);

    coord_stats_k<<<BATCH, 256, 0, stream>>>(coords, bstats);
    vox_idx_k<<<BATCH * NPTS / 256, 256, 0, stream>>>(coords, bstats, nc4, vidx, slot, cnts);
    transpose_feats_k<<<BATCH * 256, 256, 0, stream>>>(features, featTb);
    scan1_k<<<BATCH * R3 / 256, 256, 0, stream>>>(cnts, offs, part);
    scan2_k<<<1, 1024, 0, stream>>>(part);
    scan3_k<<<BATCH * R3 / 256, 256, 0, stream>>>(offs, part);
    scatter_pts_k<<<BATCH * NPTS / 256, 256, 0, stream>>>(vidx, slot, offs, pidx2);
    gather_k<<<BATCH * R3 * 8 / 256, 256, 0, stream>>>(featTb, cnts, offs, pidx2, voxCL);

    wreorder_k<CIN><<<(27 * 2 * 128 * 4 + 255) / 256, 256, 0, stream>>>(w1, w1f);
    wreorder_k<COUT><<<(27 * 4 * 128 * 4 + 255) / 256, 256, 0, stream>>>(w2, w2f);
    wpreorder_k<<<4, 256, 0, stream>>>(wp, wpb);

    conv3d_mfma_k<CIN><<<BATCH * 32 * 8, 512, 0, stream>>>(voxCL, w1f, b1, act1, gn1acc);
    gn_apply_cl_k<<<BATCH * R3 * 16 / 256, 256, 0, stream>>>(act1, gn1acc, g1g, g1b);

    conv3d_mfma_k<COUT><<<BATCH * 32 * 8, 512, 0, stream>>>(act1, w2f, b2, act2, gn2acc);

    // pfb overlays voxCL (dead after conv1); launched after conv2 for safety
    pgemm_mfma_k<<<BATCH * NPTS / 64, 256, 0, stream>>>(featTb, wpb, bp, pfb, gnpacc);

    fuse2_k<<<BATCH * NPTS * 8 / 256, 256, 0, stream>>>(act2, pfb, nc4, pidx2,
                                                        gn2acc, gnpacc, g2g, g2b, gpg, gpb);

    transpose_out_k<<<BATCH * 256, 256, 0, stream>>>(pfb, out);
}